// Round 2
// baseline (295.678 us; speedup 1.0000x reference)
//
#include <hip/hip_runtime.h>
#include <math.h>

#define NN 50000
#define EE 800000
#define ET (EE + NN)      // edges + self loops
#define F_IN 128
#define HEADS 8
#define HID 16
#define C1 (HEADS * HID)  // 128
#define CLASSES 40
#define NEG_SLOPE 0.2f
#define LOG2E 1.4426950408889634f

#define GB1 ((NN + 31) / 32)        // 1563 gemm1 blocks
#define CB1 ((EE / 4 + 255) / 256)  // 782 count blocks
#define NCHUNKS ((NN + 1023) / 1024)  // 49

typedef __attribute__((ext_vector_type(8))) short bf16x8;
typedef __attribute__((ext_vector_type(4))) float f32x4;

__device__ __forceinline__ unsigned cvtpk(float a, float b) {
    unsigned r;
    asm("v_cvt_pk_bf16_f32 %0, %1, %2" : "=v"(r) : "v"(a), "v"(b));
    return r;
}
__device__ __forceinline__ float fexp2(float x) {
    float r;
    asm("v_exp_f32 %0, %1\n\ts_nop 0" : "=v"(r) : "v"(x));
    return r;
}
__device__ __forceinline__ float bflo(unsigned u) { return __uint_as_float(u << 16); }
__device__ __forceinline__ float bfhi(unsigned u) { return __uint_as_float(u & 0xffff0000u); }
__device__ __forceinline__ float lrelu(float a) { return fmaxf(a, NEG_SLOPE * a); }
__device__ __forceinline__ bf16x8 pack8(float f0, float f1, float f2, float f3,
                                        float f4, float f5, float f6, float f7) {
    union { unsigned u[4]; bf16x8 v; } U;
    U.u[0] = cvtpk(f0, f1);
    U.u[1] = cvtpk(f2, f3);
    U.u[2] = cvtpk(f4, f5);
    U.u[3] = cvtpk(f6, f7);
    return U.v;
}
// split 8 consecutive f32 into hi/lo bf16 fragments (hi + lo == f32 within 2^-18 rel)
__device__ __forceinline__ void hilo8(const float* p, bf16x8* hi, bf16x8* lo) {
    union { unsigned u[4]; bf16x8 v; } H, L;
    #pragma unroll
    for (int j = 0; j < 4; ++j) {
        float a = p[2 * j], b = p[2 * j + 1];
        unsigned h = cvtpk(a, b);
        L.u[j] = cvtpk(a - bflo(h), b - bfhi(h));
        H.u[j] = h;
    }
    *hi = H.v;
    *lo = L.v;
}

// ---------------- GEMM1 + MFMA-based elogit1 + fused count ----------------
// e_src1[n,h] = sum_k x[n,k] * va[k,h],  va[k,h] = sum_t W1[k,h*16+t]*a_src[h,t]
// va computed cooperatively into LDS; e done as one extra 16-col MFMA tile (hi/lo bf16).
__global__ void gemm1_count_kernel(const float* __restrict__ x, const float* __restrict__ W1,
                                   const float* __restrict__ a_src, const float* __restrict__ a_dst,
                                   const int* __restrict__ ei,
                                   unsigned short* __restrict__ h1b,
                                   float* __restrict__ e_src, float* __restrict__ e_dst,
                                   int* __restrict__ deg) {
    const int bid = blockIdx.x;
    const int tid = threadIdx.x;
    if (bid >= GB1) {  // -------- count part (independent of gemm; overlaps it) --------
        int base = ((bid - GB1) * 256 + tid) * 4;
        if (base < EE) {
            int4 d4 = *(const int4*)(ei + EE + base);
            atomicAdd(&deg[d4.x], 1);
            atomicAdd(&deg[d4.y], 1);
            atomicAdd(&deg[d4.z], 1);
            atomicAdd(&deg[d4.w], 1);
        }
        return;
    }

    // --- cooperative va precompute: vaT[h][k] (h<8: src, h>=8: dst), LOG2E pre-scaled ---
    __shared__ float vaT[16][132];  // +4 pad: 2-way-max bank aliasing, rows stay 16B aligned
    {
        const int k = tid >> 1, half = tid & 1;
        const float* wrow = W1 + (size_t)k * C1 + half * 64;
        #pragma unroll
        for (int hh = 0; hh < 4; ++hh) {
            const int h = half * 4 + hh;
            float s = 0.f, d2 = 0.f;
            #pragma unroll
            for (int t = 0; t < 16; ++t) {
                float wv = wrow[hh * 16 + t];
                s  += wv * a_src[h * HID + t];
                d2 += wv * a_dst[h * HID + t];
            }
            vaT[h][k]     = s * LOG2E;
            vaT[h + 8][k] = d2 * LOG2E;
        }
    }

    const int w = tid >> 6, lane = tid & 63;
    const int q = lane >> 4, c = lane & 15;

    bf16x8 bfrag[2][4];
    #pragma unroll
    for (int nt = 0; nt < 2; ++nt) {
        const int col = w * 32 + nt * 16 + c;
        #pragma unroll
        for (int kc = 0; kc < 4; ++kc) {
            const int k0 = kc * 32 + q * 8;
            const float* wp = W1 + (size_t)k0 * C1 + col;
            bfrag[nt][kc] = pack8(wp[0], wp[C1], wp[2 * C1], wp[3 * C1],
                                  wp[4 * C1], wp[5 * C1], wp[6 * C1], wp[7 * C1]);
        }
    }

    __syncthreads();
    // e-operand fragments (only waves 0/1 consume them)
    bf16x8 beh[4], bel[4];
    if (w < 2) {
        #pragma unroll
        for (int kc = 0; kc < 4; ++kc)
            hilo8(&vaT[c][kc * 32 + q * 8], &beh[kc], &bel[kc]);
    }

    #pragma unroll
    for (int mt = 0; mt < 2; ++mt) {
        const int m0 = (bid * 2 + mt) * 16;
        if (m0 >= NN) break;
        int row = m0 + c;
        if (row > NN - 1) row = NN - 1;
        bf16x8 afrag[4];
        #pragma unroll
        for (int kc = 0; kc < 4; ++kc) {
            const float* xp = x + (size_t)row * F_IN + kc * 32 + q * 8;
            float4 p0 = *(const float4*)xp;
            float4 p1 = *(const float4*)(xp + 4);
            afrag[kc] = pack8(p0.x, p0.y, p0.z, p0.w, p1.x, p1.y, p1.z, p1.w);
        }
        f32x4 acc0 = {0.f, 0.f, 0.f, 0.f};
        f32x4 acc1 = {0.f, 0.f, 0.f, 0.f};
        #pragma unroll
        for (int kc = 0; kc < 4; ++kc) {
            acc0 = __builtin_amdgcn_mfma_f32_16x16x32_bf16(afrag[kc], bfrag[0][kc], acc0, 0, 0, 0);
            acc1 = __builtin_amdgcn_mfma_f32_16x16x32_bf16(afrag[kc], bfrag[1][kc], acc1, 0, 0, 0);
        }
        // e-MFMA: wave `mt` computes e_src/e_dst for this m-tile (all waves share rows)
        if (w == mt) {
            f32x4 acce = {0.f, 0.f, 0.f, 0.f};
            #pragma unroll
            for (int kc = 0; kc < 4; ++kc) {
                acce = __builtin_amdgcn_mfma_f32_16x16x32_bf16(afrag[kc], beh[kc], acce, 0, 0, 0);
                acce = __builtin_amdgcn_mfma_f32_16x16x32_bf16(afrag[kc], bel[kc], acce, 0, 0, 0);
            }
            float* ep = (c < 8) ? e_src : e_dst;
            const int cc = c & 7;
            #pragma unroll
            for (int r = 0; r < 4; ++r) {
                const int ro = m0 + q * 4 + r;
                if (ro < NN) ep[(size_t)ro * HEADS + cc] = acce[r];
            }
        }
        #pragma unroll
        for (int r = 0; r < 4; ++r) {
            const int ro = m0 + q * 4 + r;
            if (ro < NN) {
                h1b[(size_t)ro * C1 + w * 32 + c]      = (unsigned short)cvtpk(acc0[r], acc0[r]);
                h1b[(size_t)ro * C1 + w * 32 + 16 + c] = (unsigned short)cvtpk(acc1[r], acc1[r]);
            }
        }
    }
}

// ---------------- CSR scan ----------------
// exclusive scan over (deg[i] + 1)  [+1 = self-loop]
__global__ void scan1_kernel(const int* __restrict__ deg, int* __restrict__ rowptr,
                             int* __restrict__ bsum) {
    __shared__ int sh[256];
    const int tid = threadIdx.x;
    const int base = blockIdx.x * 1024 + tid * 4;
    int v[4], s[4];
    #pragma unroll
    for (int j = 0; j < 4; ++j) v[j] = (base + j < NN) ? (deg[base + j] + 1) : 0;
    s[0] = v[0]; s[1] = s[0] + v[1]; s[2] = s[1] + v[2]; s[3] = s[2] + v[3];
    int T = s[3];
    sh[tid] = T;
    __syncthreads();
    for (int off = 1; off < 256; off <<= 1) {
        int xv = (tid >= off) ? sh[tid - off] : 0;
        __syncthreads();
        sh[tid] += xv;
        __syncthreads();
    }
    int excl = sh[tid] - T;
    #pragma unroll
    for (int j = 0; j < 4; ++j)
        if (base + j < NN) rowptr[base + j] = excl + s[j] - v[j];
    if (tid == 255) bsum[blockIdx.x] = sh[255];
}

// finalize rowptr (scan2 fused: wave-0 shfl_up scan of the 49 block sums);
// self-loop at slot rowptr[i]; cursor starts past it; deg -> total cnt
__global__ void scan3_kernel(int* __restrict__ rowptr, const int* __restrict__ bsum,
                             int* __restrict__ cursor, unsigned short* __restrict__ csr,
                             int* __restrict__ deg) {
    __shared__ int ex[64];
    const int tid = threadIdx.x;
    if (tid < 64) {
        int v = (tid < NCHUNKS) ? bsum[tid] : 0;
        int s = v;
        #pragma unroll
        for (int off = 1; off < 64; off <<= 1) {
            int xv = __shfl_up(s, off);
            if (tid >= off) s += xv;
        }
        ex[tid] = s - v;  // exclusive prefix
    }
    __syncthreads();
    int i = blockIdx.x * blockDim.x + tid;
    if (i >= NN) return;
    int rp = rowptr[i] + ex[i >> 10];
    rowptr[i] = rp;
    cursor[i] = rp + 1;
    csr[rp] = (unsigned short)i;  // self-loop first
    deg[i] += 1;                  // total incoming count incl. self-loop
}

// scatter real edges: 4 per thread, int4 loads, ushort payloads (L2-merged stores)
__global__ void fill_kernel(const int* __restrict__ ei, int* __restrict__ cursor,
                            unsigned short* __restrict__ csr) {
    int base = (blockIdx.x * blockDim.x + threadIdx.x) * 4;
    if (base >= EE) return;
    int4 s4 = *(const int4*)(ei + base);
    int4 d4 = *(const int4*)(ei + EE + base);
    int p0 = atomicAdd(&cursor[d4.x], 1);
    int p1 = atomicAdd(&cursor[d4.y], 1);
    int p2 = atomicAdd(&cursor[d4.z], 1);
    int p3 = atomicAdd(&cursor[d4.w], 1);
    csr[p0] = (unsigned short)s4.x;
    csr[p1] = (unsigned short)s4.y;
    csr[p2] = (unsigned short)s4.z;
    csr[p3] = (unsigned short)s4.w;
}

// ---------------- layer-1 aggregation (bf16 hmid out) ----------------
// block = 256 = 4 waves; wave per dst node. Wave = 4 edge-groups x 16 lanes.
// Lane l (0..15) owns channels 8l..8l+7; head = l>>1. Group g: edges i = g, g+4, ...
__global__ void agg1_kernel(const unsigned short* __restrict__ h1b,
                            const float* __restrict__ e_src, const float* __restrict__ e_dst,
                            const int* __restrict__ rowptr, const int* __restrict__ deg,
                            const unsigned short* __restrict__ csr,
                            const float* __restrict__ b1, unsigned short* __restrict__ hmid) {
    const int d = blockIdx.x * 4 + (threadIdx.x >> 6);
    const int lane = threadIdx.x & 63;
    const int g = lane >> 4;       // edge-group 0..3
    const int l = lane & 15;       // channel-lane: channels 8l..8l+7
    const int hd = l >> 1;
    const float ed = e_dst[(size_t)d * HEADS + hd];  // pre-scaled by log2e
    const int start = rowptr[d];
    const int cnt = deg[d];

    float denom = 0.f;
    float acc[8] = {0.f, 0.f, 0.f, 0.f, 0.f, 0.f, 0.f, 0.f};

    for (int i = g; i < cnt; i += 8) {
        const int i1 = i + 4;
        const bool v1 = i1 < cnt;
        const int j1 = v1 ? i1 : i;
        int s0 = csr[start + i];
        int s1 = csr[start + j1];
        float es0 = e_src[(size_t)s0 * HEADS + hd];
        float es1 = e_src[(size_t)s1 * HEADS + hd];
        uint4 g0 = *(const uint4*)(h1b + (size_t)s0 * C1 + 8 * l);
        uint4 g1 = *(const uint4*)(h1b + (size_t)s1 * C1 + 8 * l);
        float w0 = fexp2(lrelu(es0 + ed));
        float w1 = v1 ? fexp2(lrelu(es1 + ed)) : 0.f;
        denom += w0 + w1;
        acc[0] += w0 * bflo(g0.x) + w1 * bflo(g1.x);
        acc[1] += w0 * bfhi(g0.x) + w1 * bfhi(g1.x);
        acc[2] += w0 * bflo(g0.y) + w1 * bflo(g1.y);
        acc[3] += w0 * bfhi(g0.y) + w1 * bfhi(g1.y);
        acc[4] += w0 * bflo(g0.z) + w1 * bflo(g1.z);
        acc[5] += w0 * bfhi(g0.z) + w1 * bfhi(g1.z);
        acc[6] += w0 * bflo(g0.w) + w1 * bflo(g1.w);
        acc[7] += w0 * bfhi(g0.w) + w1 * bfhi(g1.w);
    }
    // combine the 4 edge-groups (lanes l, l+16, l+32, l+48)
    denom += __shfl_xor(denom, 16);
    denom += __shfl_xor(denom, 32);
    #pragma unroll
    for (int k = 0; k < 8; ++k) {
        acc[k] += __shfl_xor(acc[k], 16);
        acc[k] += __shfl_xor(acc[k], 32);
    }
    if (g == 0) {
        const float inv = 1.f / (denom + 1e-16f);
        float o[8];
        #pragma unroll
        for (int k = 0; k < 8; ++k) {
            float t = acc[k] * inv + b1[8 * l + k];
            o[k] = (t > 0.f) ? t : expm1f(t);
        }
        uint4 st;
        st.x = cvtpk(o[0], o[1]);
        st.y = cvtpk(o[2], o[3]);
        st.z = cvtpk(o[4], o[5]);
        st.w = cvtpk(o[6], o[7]);
        *(uint4*)(hmid + (size_t)d * C1 + 8 * l) = st;  // bf16 row, 16B/lane
    }
}

// ---------------- GEMM2 (bf16 A direct) + MFMA-based elogit2 ----------------
// e2 = hmid @ (W2 @ a)  (associativity); va2 in LDS, hi/lo bf16 in cols 0..3 of one tile.
__global__ void gemm2_kernel(const unsigned short* __restrict__ hmid, const float* __restrict__ W2,
                             const float* __restrict__ a_src, const float* __restrict__ a_dst,
                             unsigned short* __restrict__ h2b,
                             float* __restrict__ e_src, float* __restrict__ e_dst) {
    const int tid = threadIdx.x;

    __shared__ float vaT2[2][132];
    if (tid < C1) {
        const float* wrow = W2 + (size_t)tid * CLASSES;
        float s = 0.f, d2 = 0.f;
        #pragma unroll
        for (int c2 = 0; c2 < CLASSES; ++c2) {
            float wv = wrow[c2];
            s  += wv * a_src[c2];
            d2 += wv * a_dst[c2];
        }
        vaT2[0][tid] = s * LOG2E;
        vaT2[1][tid] = d2 * LOG2E;
    }

    const int w = tid >> 6, lane = tid & 63;
    const int q = lane >> 4, c = lane & 15;

    bf16x8 bfrag[3][4];
    #pragma unroll
    for (int nt = 0; nt < 3; ++nt) {
        const int col = nt * 16 + c;
        const bool cv = col < CLASSES;
        #pragma unroll
        for (int kc = 0; kc < 4; ++kc) {
            const int k0 = kc * 32 + q * 8;
            bf16x8 bb = 0;
            if (cv) {
                const float* wp = W2 + (size_t)k0 * CLASSES + col;
                bb = pack8(wp[0], wp[CLASSES], wp[2 * CLASSES], wp[3 * CLASSES],
                           wp[4 * CLASSES], wp[5 * CLASSES], wp[6 * CLASSES], wp[7 * CLASSES]);
            }
            bfrag[nt][kc] = bb;
        }
    }

    __syncthreads();
    // e-tile: col 0 = src_hi, 1 = src_lo, 2 = dst_hi, 3 = dst_lo
    bf16x8 bfe[4];
    #pragma unroll
    for (int kc = 0; kc < 4; ++kc) {
        bf16x8 h8 = 0, l8 = 0;
        if (c < 4) hilo8(&vaT2[c >> 1][kc * 32 + q * 8], &h8, &l8);
        bfe[kc] = (c & 1) ? l8 : h8;
    }

    const int m0 = (blockIdx.x * 4 + w) * 16;
    if (m0 >= NN) return;
    int row = m0 + c;
    if (row > NN - 1) row = NN - 1;
    bf16x8 afrag[4];
    #pragma unroll
    for (int kc = 0; kc < 4; ++kc)
        afrag[kc] = *(const bf16x8*)(hmid + (size_t)row * C1 + kc * 32 + q * 8);  // no converts

    f32x4 acc[3] = {{0.f,0.f,0.f,0.f},{0.f,0.f,0.f,0.f},{0.f,0.f,0.f,0.f}};
    f32x4 acce = {0.f, 0.f, 0.f, 0.f};
    #pragma unroll
    for (int kc = 0; kc < 4; ++kc) {
        acc[0] = __builtin_amdgcn_mfma_f32_16x16x32_bf16(afrag[kc], bfrag[0][kc], acc[0], 0, 0, 0);
        acc[1] = __builtin_amdgcn_mfma_f32_16x16x32_bf16(afrag[kc], bfrag[1][kc], acc[1], 0, 0, 0);
        acc[2] = __builtin_amdgcn_mfma_f32_16x16x32_bf16(afrag[kc], bfrag[2][kc], acc[2], 0, 0, 0);
        acce   = __builtin_amdgcn_mfma_f32_16x16x32_bf16(afrag[kc], bfe[kc],      acce,   0, 0, 0);
    }
    #pragma unroll
    for (int r = 0; r < 4; ++r) {
        const int ro = m0 + q * 4 + r;
        // combine hi+lo columns: cols (0,1) -> e_src, cols (2,3) -> e_dst
        float v = acce[r] + __shfl_xor(acce[r], 1);
        if (ro < NN) {
            #pragma unroll
            for (int nt = 0; nt < 3; ++nt) {
                const int col = nt * 16 + c;
                if (col < CLASSES)
                    h2b[(size_t)ro * CLASSES + col] = (unsigned short)cvtpk(acc[nt][r], acc[nt][r]);
            }
            if (c == 0) e_src[ro] = v;
            if (c == 2) e_dst[ro] = v;
        }
    }
}

// ---------------- layer-2 aggregation -> output ----------------
// block = 256 = 4 waves; wave per dst node. Wave = 3 edge-groups x 20 lanes (60 active).
__global__ void agg2_kernel(const unsigned short* __restrict__ h2b,
                            const float* __restrict__ e_src, const float* __restrict__ e_dst,
                            const int* __restrict__ rowptr, const int* __restrict__ deg,
                            const unsigned short* __restrict__ csr,
                            const float* __restrict__ b2, float* __restrict__ out) {
    const int d = blockIdx.x * 4 + (threadIdx.x >> 6);
    const int lane = threadIdx.x & 63;
    const int eg = lane / 20;      // 0..2 active, 3 = idle lanes 60..63
    const int c  = lane % 20;
    const bool act = lane < 60;
    const float ed = e_dst[d];     // pre-scaled by log2e
    const int start = rowptr[d];
    const int cnt = deg[d];

    float denom = 0.f, acc0 = 0.f, acc1 = 0.f;
    for (int i = act ? eg : cnt; i < cnt; i += 6) {
        const int i1 = i + 3;
        const bool v1 = i1 < cnt;
        const int j1 = v1 ? i1 : i;
        int s0 = csr[start + i];
        int s1 = csr[start + j1];
        float es0 = e_src[s0], es1 = e_src[s1];
        unsigned g0 = *(const unsigned*)(h2b + (size_t)s0 * CLASSES + 2 * c);
        unsigned g1 = *(const unsigned*)(h2b + (size_t)s1 * CLASSES + 2 * c);
        float w0 = fexp2(lrelu(es0 + ed));
        float w1 = v1 ? fexp2(lrelu(es1 + ed)) : 0.f;
        denom += w0 + w1;
        acc0 += w0 * bflo(g0) + w1 * bflo(g1);
        acc1 += w0 * bfhi(g0) + w1 * bfhi(g1);
    }
    // combine 3 edge-groups: lanes c, c+20, c+40
    float dA = __shfl(denom, c + 20), dB = __shfl(denom, c + 40);
    float aA = __shfl(acc0,  c + 20), aB = __shfl(acc0,  c + 40);
    float bA = __shfl(acc1,  c + 20), bB = __shfl(acc1,  c + 40);
    if (lane < 20) {
        denom += dA + dB;
        acc0  += aA + aB;
        acc1  += bA + bB;
        const float inv = 1.f / (denom + 1e-16f);
        float2 o;
        o.x = acc0 * inv + b2[2 * c];
        o.y = acc1 * inv + b2[2 * c + 1];
        *(float2*)(out + (size_t)d * CLASSES + 2 * c) = o;
    }
}

extern "C" void kernel_launch(void* const* d_in, const int* in_sizes, int n_in,
                              void* d_out, int out_size, void* d_ws, size_t ws_size,
                              hipStream_t stream) {
    const float* x      = (const float*)d_in[0];
    const int*   ei     = (const int*)d_in[1];
    const float* W1     = (const float*)d_in[2];
    const float* a_src1 = (const float*)d_in[3];
    const float* a_dst1 = (const float*)d_in[4];
    const float* b1     = (const float*)d_in[5];
    const float* W2     = (const float*)d_in[6];
    const float* a_src2 = (const float*)d_in[7];
    const float* a_dst2 = (const float*)d_in[8];
    const float* b2     = (const float*)d_in[9];
    float* out = (float*)d_out;

    char* ws = (char*)d_ws;
    size_t off = 0;
    auto alloc = [&](size_t bytes) { char* p = ws + off; off += (bytes + 255) & ~(size_t)255; return p; };
    unsigned short* h1b   = (unsigned short*)alloc((size_t)NN * C1 * 2);
    unsigned short* h2b   = (unsigned short*)alloc((size_t)NN * CLASSES * 2);
    unsigned short* hmidb = (unsigned short*)alloc((size_t)NN * C1 * 2);
    float* e_src1 = (float*)alloc((size_t)NN * HEADS * 4);
    float* e_dst1 = (float*)alloc((size_t)NN * HEADS * 4);
    float* e_src2 = (float*)alloc((size_t)NN * 4);
    float* e_dst2 = (float*)alloc((size_t)NN * 4);
    int*   deg    = (int*)alloc((size_t)NN * 4);
    int*   rowptr = (int*)alloc((size_t)NN * 4);
    int*   cursor = (int*)alloc((size_t)NN * 4);
    unsigned short* csr = (unsigned short*)alloc((size_t)ET * 2);
    int*   bsum   = (int*)alloc(256 * 4);

    hipMemsetAsync(deg, 0, (size_t)NN * 4, stream);

    gemm1_count_kernel<<<GB1 + CB1, 256, 0, stream>>>(x, W1, a_src1, a_dst1, ei,
                                                      h1b, e_src1, e_dst1, deg);
    scan1_kernel<<<NCHUNKS, 256, 0, stream>>>(deg, rowptr, bsum);
    scan3_kernel<<<(NN + 255) / 256, 256, 0, stream>>>(rowptr, bsum, cursor, csr, deg);
    fill_kernel<<<(EE / 4 + 255) / 256, 256, 0, stream>>>(ei, cursor, csr);

    agg1_kernel<<<NN / 4, 256, 0, stream>>>(h1b, e_src1, e_dst1, rowptr, deg, csr, b1, hmidb);

    gemm2_kernel<<<(NN + 63) / 64, 256, 0, stream>>>(hmidb, W2, a_src2, a_dst2,
                                                     h2b, e_src2, e_dst2);
    agg2_kernel<<<NN / 4, 256, 0, stream>>>(h2b, e_src2, e_dst2, rowptr, deg, csr, b2, out);
}

// Round 3
// 285.417 us; speedup vs baseline: 1.0360x; 1.0360x over previous
//
#include <hip/hip_runtime.h>
#include <math.h>

#define NN 50000
#define EE 800000
#define ET (EE + NN)      // edges + self loops
#define F_IN 128
#define HEADS 8
#define HID 16
#define C1 (HEADS * HID)  // 128
#define CLASSES 40
#define NEG_SLOPE 0.2f
#define LOG2E 1.4426950408889634f

#define GB1 ((NN + 31) / 32)        // 1563 gemm1 blocks
#define CB1 ((EE / 4 + 255) / 256)  // 782 count blocks
#define NCHUNKS ((NN + 1023) / 1024)  // 49

typedef __attribute__((ext_vector_type(8))) short bf16x8;
typedef __attribute__((ext_vector_type(4))) float f32x4;

__device__ __forceinline__ unsigned cvtpk(float a, float b) {
    unsigned r;
    asm("v_cvt_pk_bf16_f32 %0, %1, %2" : "=v"(r) : "v"(a), "v"(b));
    return r;
}
__device__ __forceinline__ float fexp2(float x) {
    float r;
    asm("v_exp_f32 %0, %1\n\ts_nop 0" : "=v"(r) : "v"(x));
    return r;
}
__device__ __forceinline__ float bflo(unsigned u) { return __uint_as_float(u << 16); }
__device__ __forceinline__ float bfhi(unsigned u) { return __uint_as_float(u & 0xffff0000u); }
__device__ __forceinline__ float lrelu(float a) { return fmaxf(a, NEG_SLOPE * a); }
__device__ __forceinline__ unsigned short bf1(float a) { return (unsigned short)cvtpk(a, a); }
__device__ __forceinline__ float bf1f(float a) { return bflo(cvtpk(a, a)); }
__device__ __forceinline__ bf16x8 pack8(float f0, float f1, float f2, float f3,
                                        float f4, float f5, float f6, float f7) {
    union { unsigned u[4]; bf16x8 v; } U;
    U.u[0] = cvtpk(f0, f1);
    U.u[1] = cvtpk(f2, f3);
    U.u[2] = cvtpk(f4, f5);
    U.u[3] = cvtpk(f6, f7);
    return U.v;
}

// ---------------- prep: va1/va2 (once, fragment layout, hi/lo bf16) + deg zero ----------------
// va1[k,h] = sum_t W1[k,h*16+t]*a[h,t]  (h<8: src, h>=8: dst), LOG2E pre-scaled.
// Stored transposed: va1h/va1l[h][k] bf16 (16 rows x 128). va2b rows: src_hi,src_lo,dst_hi,dst_lo.
__global__ void prep_kernel(const float* __restrict__ W1,
                            const float* __restrict__ as1, const float* __restrict__ ad1,
                            const float* __restrict__ W2,
                            const float* __restrict__ as2, const float* __restrict__ ad2,
                            unsigned short* __restrict__ va1h, unsigned short* __restrict__ va1l,
                            unsigned short* __restrict__ va2b, int* __restrict__ deg) {
    const int tid = threadIdx.x;
    if (blockIdx.x > 0) {  // deg zeroing (replaces hipMemsetAsync)
        int base = ((blockIdx.x - 1) * 256 + tid) * 4;
        if (base < NN) *(int4*)(deg + base) = make_int4(0, 0, 0, 0);
        return;
    }
    {   // va1: thread (k, half) computes 4 heads x {src,dst}
        const int k = tid >> 1, half = tid & 1;
        const float* wrow = W1 + (size_t)k * C1 + half * 64;
        #pragma unroll
        for (int hh = 0; hh < 4; ++hh) {
            const int h = half * 4 + hh;
            float s = 0.f, d = 0.f;
            #pragma unroll
            for (int t = 0; t < 16; ++t) {
                float wv = wrow[hh * 16 + t];
                s += wv * as1[h * HID + t];
                d += wv * ad1[h * HID + t];
            }
            s *= LOG2E; d *= LOG2E;
            va1h[h * 128 + k]       = bf1(s);
            va1l[h * 128 + k]       = bf1(s - bf1f(s));
            va1h[(h + 8) * 128 + k] = bf1(d);
            va1l[(h + 8) * 128 + k] = bf1(d - bf1f(d));
        }
    }
    if (tid < C1) {  // va2: thread k dots W2 row k with a2 vectors
        const float* wrow = W2 + (size_t)tid * CLASSES;
        float s = 0.f, d = 0.f;
        #pragma unroll
        for (int c2 = 0; c2 < CLASSES; ++c2) {
            float wv = wrow[c2];
            s += wv * as2[c2];
            d += wv * ad2[c2];
        }
        s *= LOG2E; d *= LOG2E;
        va2b[0 * 128 + tid] = bf1(s);
        va2b[1 * 128 + tid] = bf1(s - bf1f(s));
        va2b[2 * 128 + tid] = bf1(d);
        va2b[3 * 128 + tid] = bf1(d - bf1f(d));
    }
}

// ---------------- GEMM1 + MFMA elogit1 + interleaved count ----------------
__global__ void gemm1_count_kernel(const float* __restrict__ x, const float* __restrict__ W1,
                                   const unsigned short* __restrict__ va1h,
                                   const unsigned short* __restrict__ va1l,
                                   const int* __restrict__ ei,
                                   unsigned short* __restrict__ h1b,
                                   float* __restrict__ e_src, float* __restrict__ e_dst,
                                   int* __restrict__ deg) {
    const int bid = blockIdx.x;
    const int tid = threadIdx.x;
    // interleave: bid<2*CB1: odd = count, even = gemm; bid>=2*CB1: gemm
    int gemmb;
    if (bid < 2 * CB1) {
        if (bid & 1) {  // -------- count (overlapped with gemm throughout) --------
            int base = ((bid >> 1) * 256 + tid) * 4;
            if (base < EE) {
                int4 d4 = *(const int4*)(ei + EE + base);
                atomicAdd(&deg[d4.x], 1);
                atomicAdd(&deg[d4.y], 1);
                atomicAdd(&deg[d4.z], 1);
                atomicAdd(&deg[d4.w], 1);
            }
            return;
        }
        gemmb = bid >> 1;
    } else {
        gemmb = bid - CB1;
    }

    const int w = tid >> 6, lane = tid & 63;
    const int q = lane >> 4, c = lane & 15;

    bf16x8 bfrag[2][4];
    #pragma unroll
    for (int nt = 0; nt < 2; ++nt) {
        const int col = w * 32 + nt * 16 + c;
        #pragma unroll
        for (int kc = 0; kc < 4; ++kc) {
            const int k0 = kc * 32 + q * 8;
            const float* wp = W1 + (size_t)k0 * C1 + col;
            bfrag[nt][kc] = pack8(wp[0], wp[C1], wp[2 * C1], wp[3 * C1],
                                  wp[4 * C1], wp[5 * C1], wp[6 * C1], wp[7 * C1]);
        }
    }
    // e-operand fragments from prep (L2-hot 8KB)
    bf16x8 beh[4], bel[4];
    #pragma unroll
    for (int kc = 0; kc < 4; ++kc) {
        const int coloff = kc * 32 + q * 8;
        beh[kc] = *(const bf16x8*)(va1h + c * 128 + coloff);
        bel[kc] = *(const bf16x8*)(va1l + c * 128 + coloff);
    }

    // hoisted A-loads for both m-tiles (16 independent 16B loads -> MLP)
    bf16x8 afrag[2][4];
    #pragma unroll
    for (int mt = 0; mt < 2; ++mt) {
        const int m0 = (gemmb * 2 + mt) * 16;
        int row = m0 + c;
        if (row > NN - 1) row = NN - 1;
        #pragma unroll
        for (int kc = 0; kc < 4; ++kc) {
            const float* xp = x + (size_t)row * F_IN + kc * 32 + q * 8;
            float4 p0 = *(const float4*)xp;
            float4 p1 = *(const float4*)(xp + 4);
            afrag[mt][kc] = pack8(p0.x, p0.y, p0.z, p0.w, p1.x, p1.y, p1.z, p1.w);
        }
    }

    #pragma unroll
    for (int mt = 0; mt < 2; ++mt) {
        const int m0 = (gemmb * 2 + mt) * 16;
        f32x4 acc0 = {0.f, 0.f, 0.f, 0.f};
        f32x4 acc1 = {0.f, 0.f, 0.f, 0.f};
        #pragma unroll
        for (int kc = 0; kc < 4; ++kc) {
            acc0 = __builtin_amdgcn_mfma_f32_16x16x32_bf16(afrag[mt][kc], bfrag[0][kc], acc0, 0, 0, 0);
            acc1 = __builtin_amdgcn_mfma_f32_16x16x32_bf16(afrag[mt][kc], bfrag[1][kc], acc1, 0, 0, 0);
        }
        // e-MFMA: wave `mt` computes e_src/e_dst for this m-tile
        if (w == mt) {
            f32x4 acce = {0.f, 0.f, 0.f, 0.f};
            #pragma unroll
            for (int kc = 0; kc < 4; ++kc) {
                acce = __builtin_amdgcn_mfma_f32_16x16x32_bf16(afrag[mt][kc], beh[kc], acce, 0, 0, 0);
                acce = __builtin_amdgcn_mfma_f32_16x16x32_bf16(afrag[mt][kc], bel[kc], acce, 0, 0, 0);
            }
            float* ep = (c < 8) ? e_src : e_dst;
            const int cc = c & 7;
            #pragma unroll
            for (int r = 0; r < 4; ++r) {
                const int ro = m0 + q * 4 + r;
                if (ro < NN) ep[(size_t)ro * HEADS + cc] = acce[r];
            }
        }
        #pragma unroll
        for (int r = 0; r < 4; ++r) {
            const int ro = m0 + q * 4 + r;
            if (ro < NN) {
                h1b[(size_t)ro * C1 + w * 32 + c]      = (unsigned short)cvtpk(acc0[r], acc0[r]);
                h1b[(size_t)ro * C1 + w * 32 + 16 + c] = (unsigned short)cvtpk(acc1[r], acc1[r]);
            }
        }
    }
}

// ---------------- CSR scan ----------------
// exclusive scan over (deg[i] + 1)  [+1 = self-loop]
__global__ void scan1_kernel(const int* __restrict__ deg, int* __restrict__ rowptr,
                             int* __restrict__ bsum) {
    __shared__ int sh[256];
    const int tid = threadIdx.x;
    const int base = blockIdx.x * 1024 + tid * 4;
    int v[4], s[4];
    #pragma unroll
    for (int j = 0; j < 4; ++j) v[j] = (base + j < NN) ? (deg[base + j] + 1) : 0;
    s[0] = v[0]; s[1] = s[0] + v[1]; s[2] = s[1] + v[2]; s[3] = s[2] + v[3];
    int T = s[3];
    sh[tid] = T;
    __syncthreads();
    for (int off = 1; off < 256; off <<= 1) {
        int xv = (tid >= off) ? sh[tid - off] : 0;
        __syncthreads();
        sh[tid] += xv;
        __syncthreads();
    }
    int excl = sh[tid] - T;
    #pragma unroll
    for (int j = 0; j < 4; ++j)
        if (base + j < NN) rowptr[base + j] = excl + s[j] - v[j];
    if (tid == 255) bsum[blockIdx.x] = sh[255];
}

// finalize rowptr (scan2 fused); self-loop at slot rowptr[i]; cursor past it; deg -> total cnt
__global__ void scan3_kernel(int* __restrict__ rowptr, const int* __restrict__ bsum,
                             int* __restrict__ cursor, unsigned short* __restrict__ csr,
                             int* __restrict__ deg) {
    __shared__ int ex[64];
    const int tid = threadIdx.x;
    if (tid < 64) {
        int v = (tid < NCHUNKS) ? bsum[tid] : 0;
        int s = v;
        #pragma unroll
        for (int off = 1; off < 64; off <<= 1) {
            int xv = __shfl_up(s, off);
            if (tid >= off) s += xv;
        }
        ex[tid] = s - v;  // exclusive prefix
    }
    __syncthreads();
    int i = blockIdx.x * blockDim.x + tid;
    if (i >= NN) return;
    int rp = rowptr[i] + ex[i >> 10];
    rowptr[i] = rp;
    cursor[i] = rp + 1;
    csr[rp] = (unsigned short)i;  // self-loop first
    deg[i] += 1;                  // total incoming count incl. self-loop
}

// scatter real edges: 4 per thread, int4 loads, ushort payloads (L2-merged stores)
__global__ void fill_kernel(const int* __restrict__ ei, int* __restrict__ cursor,
                            unsigned short* __restrict__ csr) {
    int base = (blockIdx.x * blockDim.x + threadIdx.x) * 4;
    if (base >= EE) return;
    int4 s4 = *(const int4*)(ei + base);
    int4 d4 = *(const int4*)(ei + EE + base);
    int p0 = atomicAdd(&cursor[d4.x], 1);
    int p1 = atomicAdd(&cursor[d4.y], 1);
    int p2 = atomicAdd(&cursor[d4.z], 1);
    int p3 = atomicAdd(&cursor[d4.w], 1);
    csr[p0] = (unsigned short)s4.x;
    csr[p1] = (unsigned short)s4.y;
    csr[p2] = (unsigned short)s4.z;
    csr[p3] = (unsigned short)s4.w;
}

// ---------------- layer-1 aggregation (bf16 hmid out) ----------------
__global__ void agg1_kernel(const unsigned short* __restrict__ h1b,
                            const float* __restrict__ e_src, const float* __restrict__ e_dst,
                            const int* __restrict__ rowptr, const int* __restrict__ deg,
                            const unsigned short* __restrict__ csr,
                            const float* __restrict__ b1, unsigned short* __restrict__ hmid) {
    const int d = blockIdx.x * 4 + (threadIdx.x >> 6);
    const int lane = threadIdx.x & 63;
    const int g = lane >> 4;       // edge-group 0..3
    const int l = lane & 15;       // channel-lane: channels 8l..8l+7
    const int hd = l >> 1;
    const float ed = e_dst[(size_t)d * HEADS + hd];  // pre-scaled by log2e
    const int start = rowptr[d];
    const int cnt = deg[d];

    float denom = 0.f;
    float acc[8] = {0.f, 0.f, 0.f, 0.f, 0.f, 0.f, 0.f, 0.f};

    for (int i = g; i < cnt; i += 8) {
        const int i1 = i + 4;
        const bool v1 = i1 < cnt;
        const int j1 = v1 ? i1 : i;
        int s0 = csr[start + i];
        int s1 = csr[start + j1];
        float es0 = e_src[(size_t)s0 * HEADS + hd];
        float es1 = e_src[(size_t)s1 * HEADS + hd];
        uint4 g0 = *(const uint4*)(h1b + (size_t)s0 * C1 + 8 * l);
        uint4 g1 = *(const uint4*)(h1b + (size_t)s1 * C1 + 8 * l);
        float w0 = fexp2(lrelu(es0 + ed));
        float w1 = v1 ? fexp2(lrelu(es1 + ed)) : 0.f;
        denom += w0 + w1;
        acc[0] += w0 * bflo(g0.x) + w1 * bflo(g1.x);
        acc[1] += w0 * bfhi(g0.x) + w1 * bfhi(g1.x);
        acc[2] += w0 * bflo(g0.y) + w1 * bflo(g1.y);
        acc[3] += w0 * bfhi(g0.y) + w1 * bfhi(g1.y);
        acc[4] += w0 * bflo(g0.z) + w1 * bflo(g1.z);
        acc[5] += w0 * bfhi(g0.z) + w1 * bfhi(g1.z);
        acc[6] += w0 * bflo(g0.w) + w1 * bflo(g1.w);
        acc[7] += w0 * bfhi(g0.w) + w1 * bfhi(g1.w);
    }
    // combine the 4 edge-groups (lanes l, l+16, l+32, l+48)
    denom += __shfl_xor(denom, 16);
    denom += __shfl_xor(denom, 32);
    #pragma unroll
    for (int k = 0; k < 8; ++k) {
        acc[k] += __shfl_xor(acc[k], 16);
        acc[k] += __shfl_xor(acc[k], 32);
    }
    if (g == 0) {
        const float inv = 1.f / (denom + 1e-16f);
        float o[8];
        #pragma unroll
        for (int k = 0; k < 8; ++k) {
            float t = acc[k] * inv + b1[8 * l + k];
            o[k] = (t > 0.f) ? t : expm1f(t);
        }
        uint4 st;
        st.x = cvtpk(o[0], o[1]);
        st.y = cvtpk(o[2], o[3]);
        st.z = cvtpk(o[4], o[5]);
        st.w = cvtpk(o[6], o[7]);
        *(uint4*)(hmid + (size_t)d * C1 + 8 * l) = st;  // bf16 row, 16B/lane
    }
}

// ---------------- GEMM2 (bf16 A direct) + MFMA elogit2 (va2 from prep) ----------------
__global__ void gemm2_kernel(const unsigned short* __restrict__ hmid, const float* __restrict__ W2,
                             const unsigned short* __restrict__ va2b,
                             unsigned short* __restrict__ h2b,
                             float* __restrict__ e_src, float* __restrict__ e_dst) {
    const int tid = threadIdx.x;
    const int w = tid >> 6, lane = tid & 63;
    const int q = lane >> 4, c = lane & 15;

    bf16x8 bfrag[3][4];
    #pragma unroll
    for (int nt = 0; nt < 3; ++nt) {
        const int col = nt * 16 + c;
        const bool cv = col < CLASSES;
        #pragma unroll
        for (int kc = 0; kc < 4; ++kc) {
            const int k0 = kc * 32 + q * 8;
            bf16x8 bb = 0;
            if (cv) {
                const float* wp = W2 + (size_t)k0 * CLASSES + col;
                bb = pack8(wp[0], wp[CLASSES], wp[2 * CLASSES], wp[3 * CLASSES],
                           wp[4 * CLASSES], wp[5 * CLASSES], wp[6 * CLASSES], wp[7 * CLASSES]);
            }
            bfrag[nt][kc] = bb;
        }
    }
    // e-tile cols: 0=src_hi, 1=src_lo, 2=dst_hi, 3=dst_lo (from prep, 1KB L2-hot)
    bf16x8 bfe[4];
    #pragma unroll
    for (int kc = 0; kc < 4; ++kc) {
        bf16x8 bb = 0;
        if (c < 4) bb = *(const bf16x8*)(va2b + c * 128 + kc * 32 + q * 8);
        bfe[kc] = bb;
    }

    const int m0 = (blockIdx.x * 4 + w) * 16;
    if (m0 >= NN) return;
    int row = m0 + c;
    if (row > NN - 1) row = NN - 1;
    bf16x8 afrag[4];
    #pragma unroll
    for (int kc = 0; kc < 4; ++kc)
        afrag[kc] = *(const bf16x8*)(hmid + (size_t)row * C1 + kc * 32 + q * 8);  // no converts

    f32x4 acc[3] = {{0.f,0.f,0.f,0.f},{0.f,0.f,0.f,0.f},{0.f,0.f,0.f,0.f}};
    f32x4 acce = {0.f, 0.f, 0.f, 0.f};
    #pragma unroll
    for (int kc = 0; kc < 4; ++kc) {
        acc[0] = __builtin_amdgcn_mfma_f32_16x16x32_bf16(afrag[kc], bfrag[0][kc], acc[0], 0, 0, 0);
        acc[1] = __builtin_amdgcn_mfma_f32_16x16x32_bf16(afrag[kc], bfrag[1][kc], acc[1], 0, 0, 0);
        acc[2] = __builtin_amdgcn_mfma_f32_16x16x32_bf16(afrag[kc], bfrag[2][kc], acc[2], 0, 0, 0);
        acce   = __builtin_amdgcn_mfma_f32_16x16x32_bf16(afrag[kc], bfe[kc],      acce,   0, 0, 0);
    }
    #pragma unroll
    for (int r = 0; r < 4; ++r) {
        const int ro = m0 + q * 4 + r;
        // combine hi+lo columns: cols (0,1) -> e_src, cols (2,3) -> e_dst
        float v = acce[r] + __shfl_xor(acce[r], 1);
        if (ro < NN) {
            #pragma unroll
            for (int nt = 0; nt < 3; ++nt) {
                const int col = nt * 16 + c;
                if (col < CLASSES)
                    h2b[(size_t)ro * CLASSES + col] = (unsigned short)cvtpk(acc[nt][r], acc[nt][r]);
            }
            if (c == 0) e_src[ro] = v;
            if (c == 2) e_dst[ro] = v;
        }
    }
}

// ---------------- layer-2 aggregation -> output ----------------
__global__ void agg2_kernel(const unsigned short* __restrict__ h2b,
                            const float* __restrict__ e_src, const float* __restrict__ e_dst,
                            const int* __restrict__ rowptr, const int* __restrict__ deg,
                            const unsigned short* __restrict__ csr,
                            const float* __restrict__ b2, float* __restrict__ out) {
    const int d = blockIdx.x * 4 + (threadIdx.x >> 6);
    const int lane = threadIdx.x & 63;
    const int eg = lane / 20;      // 0..2 active, 3 = idle lanes 60..63
    const int c  = lane % 20;
    const bool act = lane < 60;
    const float ed = e_dst[d];     // pre-scaled by log2e
    const int start = rowptr[d];
    const int cnt = deg[d];

    float denom = 0.f, acc0 = 0.f, acc1 = 0.f;
    for (int i = act ? eg : cnt; i < cnt; i += 6) {
        const int i1 = i + 3;
        const bool v1 = i1 < cnt;
        const int j1 = v1 ? i1 : i;
        int s0 = csr[start + i];
        int s1 = csr[start + j1];
        float es0 = e_src[s0], es1 = e_src[s1];
        unsigned g0 = *(const unsigned*)(h2b + (size_t)s0 * CLASSES + 2 * c);
        unsigned g1 = *(const unsigned*)(h2b + (size_t)s1 * CLASSES + 2 * c);
        float w0 = fexp2(lrelu(es0 + ed));
        float w1 = v1 ? fexp2(lrelu(es1 + ed)) : 0.f;
        denom += w0 + w1;
        acc0 += w0 * bflo(g0) + w1 * bflo(g1);
        acc1 += w0 * bfhi(g0) + w1 * bfhi(g1);
    }
    // combine 3 edge-groups: lanes c, c+20, c+40
    float dA = __shfl(denom, c + 20), dB = __shfl(denom, c + 40);
    float aA = __shfl(acc0,  c + 20), aB = __shfl(acc0,  c + 40);
    float bA = __shfl(acc1,  c + 20), bB = __shfl(acc1,  c + 40);
    if (lane < 20) {
        denom += dA + dB;
        acc0  += aA + aB;
        acc1  += bA + bB;
        const float inv = 1.f / (denom + 1e-16f);
        float2 o;
        o.x = acc0 * inv + b2[2 * c];
        o.y = acc1 * inv + b2[2 * c + 1];
        *(float2*)(out + (size_t)d * CLASSES + 2 * c) = o;
    }
}

extern "C" void kernel_launch(void* const* d_in, const int* in_sizes, int n_in,
                              void* d_out, int out_size, void* d_ws, size_t ws_size,
                              hipStream_t stream) {
    const float* x      = (const float*)d_in[0];
    const int*   ei     = (const int*)d_in[1];
    const float* W1     = (const float*)d_in[2];
    const float* a_src1 = (const float*)d_in[3];
    const float* a_dst1 = (const float*)d_in[4];
    const float* b1     = (const float*)d_in[5];
    const float* W2     = (const float*)d_in[6];
    const float* a_src2 = (const float*)d_in[7];
    const float* a_dst2 = (const float*)d_in[8];
    const float* b2     = (const float*)d_in[9];
    float* out = (float*)d_out;

    char* ws = (char*)d_ws;
    size_t off = 0;
    auto alloc = [&](size_t bytes) { char* p = ws + off; off += (bytes + 255) & ~(size_t)255; return p; };
    unsigned short* h1b   = (unsigned short*)alloc((size_t)NN * C1 * 2);
    unsigned short* h2b   = (unsigned short*)alloc((size_t)NN * CLASSES * 2);
    unsigned short* hmidb = (unsigned short*)alloc((size_t)NN * C1 * 2);
    float* e_src1 = (float*)alloc((size_t)NN * HEADS * 4);
    float* e_dst1 = (float*)alloc((size_t)NN * HEADS * 4);
    float* e_src2 = (float*)alloc((size_t)NN * 4);
    float* e_dst2 = (float*)alloc((size_t)NN * 4);
    int*   deg    = (int*)alloc((size_t)NN * 4);
    int*   rowptr = (int*)alloc((size_t)NN * 4);
    int*   cursor = (int*)alloc((size_t)NN * 4);
    unsigned short* csr  = (unsigned short*)alloc((size_t)ET * 2);
    int*   bsum   = (int*)alloc(256 * 4);
    unsigned short* va1h = (unsigned short*)alloc(16 * 128 * 2);
    unsigned short* va1l = (unsigned short*)alloc(16 * 128 * 2);
    unsigned short* va2b = (unsigned short*)alloc(4 * 128 * 2);

    prep_kernel<<<1 + NCHUNKS, 256, 0, stream>>>(W1, a_src1, a_dst1, W2, a_src2, a_dst2,
                                                 va1h, va1l, va2b, deg);
    gemm1_count_kernel<<<GB1 + CB1, 256, 0, stream>>>(x, W1, va1h, va1l, ei,
                                                      h1b, e_src1, e_dst1, deg);
    scan1_kernel<<<NCHUNKS, 256, 0, stream>>>(deg, rowptr, bsum);
    scan3_kernel<<<(NN + 255) / 256, 256, 0, stream>>>(rowptr, bsum, cursor, csr, deg);
    fill_kernel<<<(EE / 4 + 255) / 256, 256, 0, stream>>>(ei, cursor, csr);

    agg1_kernel<<<NN / 4, 256, 0, stream>>>(h1b, e_src1, e_dst1, rowptr, deg, csr, b1, hmidb);

    gemm2_kernel<<<(NN + 63) / 64, 256, 0, stream>>>(hmidb, W2, va2b, h2b, e_src2, e_dst2);
    agg2_kernel<<<NN / 4, 256, 0, stream>>>(h2b, e_src2, e_dst2, rowptr, deg, csr, b2, out);
}

// Round 4
// 277.631 us; speedup vs baseline: 1.0650x; 1.0280x over previous
//
#include <hip/hip_runtime.h>
#include <math.h>

#define NN 50000
#define EE 800000
#define ET (EE + NN)      // edges + self loops
#define F_IN 128
#define HEADS 8
#define HID 16
#define C1 (HEADS * HID)  // 128
#define CLASSES 40
#define NEG_SLOPE 0.2f
#define LOG2E 1.4426950408889634f

#define GB1 ((NN + 31) / 32)        // 1563 gemm1 blocks
#define CB1 ((EE / 4 + 255) / 256)  // 782 count blocks
#define NCHUNKS ((NN + 1023) / 1024)  // 49

typedef __attribute__((ext_vector_type(8))) short bf16x8;
typedef __attribute__((ext_vector_type(4))) float f32x4;

__device__ __forceinline__ unsigned cvtpk(float a, float b) {
    unsigned r;
    asm("v_cvt_pk_bf16_f32 %0, %1, %2" : "=v"(r) : "v"(a), "v"(b));
    return r;
}
__device__ __forceinline__ float fexp2(float x) {
    float r;
    asm("v_exp_f32 %0, %1\n\ts_nop 0" : "=v"(r) : "v"(x));
    return r;
}
__device__ __forceinline__ float bflo(unsigned u) { return __uint_as_float(u << 16); }
__device__ __forceinline__ float bfhi(unsigned u) { return __uint_as_float(u & 0xffff0000u); }
__device__ __forceinline__ float lrelu(float a) { return fmaxf(a, NEG_SLOPE * a); }
__device__ __forceinline__ unsigned short bf1(float a) { return (unsigned short)cvtpk(a, a); }
__device__ __forceinline__ float bf1f(float a) { return bflo(cvtpk(a, a)); }
__device__ __forceinline__ bf16x8 pack8(float f0, float f1, float f2, float f3,
                                        float f4, float f5, float f6, float f7) {
    union { unsigned u[4]; bf16x8 v; } U;
    U.u[0] = cvtpk(f0, f1);
    U.u[1] = cvtpk(f2, f3);
    U.u[2] = cvtpk(f4, f5);
    U.u[3] = cvtpk(f6, f7);
    return U.v;
}

// ---------------- prep ----------------
// block 0: va1 (16x128 hi/lo bf16, frag layout) + va2 (4x128 bf16)
// block 1: W1b — W1 as bf16 MFMA fragments: frag f = (ntw*4+kc)*64+lane,
//          elem j = bf16(W1[kc*32+(lane>>4)*8+j][ (ntw>>1)*32+(ntw&1)*16+(lane&15) ])
// block 2: W2b — W2 fragments (nt*4+kc)*64+lane, cols >= CLASSES zeroed
// blocks 3+: zero deg
__global__ void prep_kernel(const float* __restrict__ W1,
                            const float* __restrict__ as1, const float* __restrict__ ad1,
                            const float* __restrict__ W2,
                            const float* __restrict__ as2, const float* __restrict__ ad2,
                            unsigned short* __restrict__ va1h, unsigned short* __restrict__ va1l,
                            unsigned short* __restrict__ va2b,
                            unsigned short* __restrict__ W1b, unsigned short* __restrict__ W2b,
                            int* __restrict__ deg) {
    const int tid = threadIdx.x;
    const int b = blockIdx.x;
    if (b >= 3) {  // deg zeroing (replaces hipMemsetAsync)
        int base = ((b - 3) * 256 + tid) * 4;
        if (base < NN) *(int4*)(deg + base) = make_int4(0, 0, 0, 0);
        return;
    }
    if (b == 1) {  // W1b fragments: 2048 frags, 8 per thread
        for (int f = tid; f < 2048; f += 256) {
            const int lane = f & 63, kc = (f >> 6) & 3, ntw = f >> 8;
            const int q = lane >> 4, c = lane & 15;
            const int col = (ntw >> 1) * 32 + (ntw & 1) * 16 + c;
            const int k0 = kc * 32 + q * 8;
            const float* wp = W1 + (size_t)k0 * C1 + col;
            *(bf16x8*)(W1b + (size_t)f * 8) =
                pack8(wp[0], wp[C1], wp[2 * C1], wp[3 * C1],
                      wp[4 * C1], wp[5 * C1], wp[6 * C1], wp[7 * C1]);
        }
        return;
    }
    if (b == 2) {  // W2b fragments: 768 frags
        for (int f = tid; f < 768; f += 256) {
            const int lane = f & 63, kc = (f >> 6) & 3, nt = f >> 8;
            const int q = lane >> 4, c = lane & 15;
            const int col = nt * 16 + c;
            const int k0 = kc * 32 + q * 8;
            bf16x8 v = 0;
            if (col < CLASSES) {
                const float* wp = W2 + (size_t)k0 * CLASSES + col;
                v = pack8(wp[0], wp[CLASSES], wp[2 * CLASSES], wp[3 * CLASSES],
                          wp[4 * CLASSES], wp[5 * CLASSES], wp[6 * CLASSES], wp[7 * CLASSES]);
            }
            *(bf16x8*)(W2b + (size_t)f * 8) = v;
        }
        return;
    }
    {   // va1: thread (k, half) computes 4 heads x {src,dst}
        const int k = tid >> 1, half = tid & 1;
        const float* wrow = W1 + (size_t)k * C1 + half * 64;
        #pragma unroll
        for (int hh = 0; hh < 4; ++hh) {
            const int h = half * 4 + hh;
            float s = 0.f, d = 0.f;
            #pragma unroll
            for (int t = 0; t < 16; ++t) {
                float wv = wrow[hh * 16 + t];
                s += wv * as1[h * HID + t];
                d += wv * ad1[h * HID + t];
            }
            s *= LOG2E; d *= LOG2E;
            va1h[h * 128 + k]       = bf1(s);
            va1l[h * 128 + k]       = bf1(s - bf1f(s));
            va1h[(h + 8) * 128 + k] = bf1(d);
            va1l[(h + 8) * 128 + k] = bf1(d - bf1f(d));
        }
    }
    if (tid < C1) {  // va2: thread k dots W2 row k with a2 vectors
        const float* wrow = W2 + (size_t)tid * CLASSES;
        float s = 0.f, d = 0.f;
        #pragma unroll
        for (int c2 = 0; c2 < CLASSES; ++c2) {
            float wv = wrow[c2];
            s += wv * as2[c2];
            d += wv * ad2[c2];
        }
        s *= LOG2E; d *= LOG2E;
        va2b[0 * 128 + tid] = bf1(s);
        va2b[1 * 128 + tid] = bf1(s - bf1f(s));
        va2b[2 * 128 + tid] = bf1(d);
        va2b[3 * 128 + tid] = bf1(d - bf1f(d));
    }
}

// ---------------- GEMM1 + MFMA elogit1 + interleaved count ----------------
__global__ __launch_bounds__(256, 4)
void gemm1_count_kernel(const float* __restrict__ x,
                        const unsigned short* __restrict__ W1b,
                        const unsigned short* __restrict__ va1h,
                        const unsigned short* __restrict__ va1l,
                        const int* __restrict__ ei,
                        unsigned short* __restrict__ h1b,
                        float* __restrict__ e_src, float* __restrict__ e_dst,
                        int* __restrict__ deg) {
    const int bid = blockIdx.x;
    const int tid = threadIdx.x;
    // interleave: bid<2*CB1: odd = count, even = gemm; bid>=2*CB1: gemm
    int gemmb;
    if (bid < 2 * CB1) {
        if (bid & 1) {  // -------- count (overlapped with gemm throughout) --------
            int base = ((bid >> 1) * 256 + tid) * 4;
            if (base < EE) {
                int4 d4 = *(const int4*)(ei + EE + base);
                atomicAdd(&deg[d4.x], 1);
                atomicAdd(&deg[d4.y], 1);
                atomicAdd(&deg[d4.z], 1);
                atomicAdd(&deg[d4.w], 1);
            }
            return;
        }
        gemmb = bid >> 1;
    } else {
        gemmb = bid - CB1;
    }

    const int w = tid >> 6, lane = tid & 63;
    const int q = lane >> 4, c = lane & 15;

    // hoisted A-loads for both m-tiles (16 independent 16B loads -> MLP)
    bf16x8 afrag[2][4];
    #pragma unroll
    for (int mt = 0; mt < 2; ++mt) {
        const int m0 = (gemmb * 2 + mt) * 16;
        int row = m0 + c;
        if (row > NN - 1) row = NN - 1;
        #pragma unroll
        for (int kc = 0; kc < 4; ++kc) {
            const float* xp = x + (size_t)row * F_IN + kc * 32 + q * 8;
            float4 p0 = *(const float4*)xp;
            float4 p1 = *(const float4*)(xp + 4);
            afrag[mt][kc] = pack8(p0.x, p0.y, p0.z, p0.w, p1.x, p1.y, p1.z, p1.w);
        }
    }

    // B fragments: preconverted, fully-coalesced 16B loads (L2-hot 32KB)
    bf16x8 bfrag[2][4];
    #pragma unroll
    for (int nt = 0; nt < 2; ++nt)
        #pragma unroll
        for (int kc = 0; kc < 4; ++kc)
            bfrag[nt][kc] = *(const bf16x8*)(W1b + ((size_t)(((w * 2 + nt) * 4 + kc) * 64 + lane)) * 8);
    // e-operand fragments from prep (L2-hot 8KB)
    bf16x8 beh[4], bel[4];
    #pragma unroll
    for (int kc = 0; kc < 4; ++kc) {
        const int coloff = kc * 32 + q * 8;
        beh[kc] = *(const bf16x8*)(va1h + c * 128 + coloff);
        bel[kc] = *(const bf16x8*)(va1l + c * 128 + coloff);
    }

    #pragma unroll
    for (int mt = 0; mt < 2; ++mt) {
        const int m0 = (gemmb * 2 + mt) * 16;
        f32x4 acc0 = {0.f, 0.f, 0.f, 0.f};
        f32x4 acc1 = {0.f, 0.f, 0.f, 0.f};
        #pragma unroll
        for (int kc = 0; kc < 4; ++kc) {
            acc0 = __builtin_amdgcn_mfma_f32_16x16x32_bf16(afrag[mt][kc], bfrag[0][kc], acc0, 0, 0, 0);
            acc1 = __builtin_amdgcn_mfma_f32_16x16x32_bf16(afrag[mt][kc], bfrag[1][kc], acc1, 0, 0, 0);
        }
        // e-MFMA: wave `mt` computes e_src/e_dst for this m-tile
        if (w == mt) {
            f32x4 acce = {0.f, 0.f, 0.f, 0.f};
            #pragma unroll
            for (int kc = 0; kc < 4; ++kc) {
                acce = __builtin_amdgcn_mfma_f32_16x16x32_bf16(afrag[mt][kc], beh[kc], acce, 0, 0, 0);
                acce = __builtin_amdgcn_mfma_f32_16x16x32_bf16(afrag[mt][kc], bel[kc], acce, 0, 0, 0);
            }
            float* ep = (c < 8) ? e_src : e_dst;
            const int cc = c & 7;
            #pragma unroll
            for (int r = 0; r < 4; ++r) {
                const int ro = m0 + q * 4 + r;
                if (ro < NN) ep[(size_t)ro * HEADS + cc] = acce[r];
            }
        }
        #pragma unroll
        for (int r = 0; r < 4; ++r) {
            const int ro = m0 + q * 4 + r;
            if (ro < NN) {
                h1b[(size_t)ro * C1 + w * 32 + c]      = (unsigned short)cvtpk(acc0[r], acc0[r]);
                h1b[(size_t)ro * C1 + w * 32 + 16 + c] = (unsigned short)cvtpk(acc1[r], acc1[r]);
            }
        }
    }
}

// ---------------- CSR scan ----------------
// exclusive scan over (deg[i] + 1)  [+1 = self-loop]
__global__ void scan1_kernel(const int* __restrict__ deg, int* __restrict__ rowptr,
                             int* __restrict__ bsum) {
    __shared__ int sh[256];
    const int tid = threadIdx.x;
    const int base = blockIdx.x * 1024 + tid * 4;
    int v[4], s[4];
    #pragma unroll
    for (int j = 0; j < 4; ++j) v[j] = (base + j < NN) ? (deg[base + j] + 1) : 0;
    s[0] = v[0]; s[1] = s[0] + v[1]; s[2] = s[1] + v[2]; s[3] = s[2] + v[3];
    int T = s[3];
    sh[tid] = T;
    __syncthreads();
    for (int off = 1; off < 256; off <<= 1) {
        int xv = (tid >= off) ? sh[tid - off] : 0;
        __syncthreads();
        sh[tid] += xv;
        __syncthreads();
    }
    int excl = sh[tid] - T;
    #pragma unroll
    for (int j = 0; j < 4; ++j)
        if (base + j < NN) rowptr[base + j] = excl + s[j] - v[j];
    if (tid == 255) bsum[blockIdx.x] = sh[255];
}

// finalize rowptr (scan2 fused); self-loop at slot rowptr[i]; cursor past it; deg -> total cnt
__global__ void scan3_kernel(int* __restrict__ rowptr, const int* __restrict__ bsum,
                             int* __restrict__ cursor, unsigned short* __restrict__ csr,
                             int* __restrict__ deg) {
    __shared__ int ex[64];
    const int tid = threadIdx.x;
    if (tid < 64) {
        int v = (tid < NCHUNKS) ? bsum[tid] : 0;
        int s = v;
        #pragma unroll
        for (int off = 1; off < 64; off <<= 1) {
            int xv = __shfl_up(s, off);
            if (tid >= off) s += xv;
        }
        ex[tid] = s - v;  // exclusive prefix
    }
    __syncthreads();
    int i = blockIdx.x * blockDim.x + tid;
    if (i >= NN) return;
    int rp = rowptr[i] + ex[i >> 10];
    rowptr[i] = rp;
    cursor[i] = rp + 1;
    csr[rp] = (unsigned short)i;  // self-loop first
    deg[i] += 1;                  // total incoming count incl. self-loop
}

// scatter real edges: 4 per thread, int4 loads, ushort payloads (L2-merged stores)
__global__ void fill_kernel(const int* __restrict__ ei, int* __restrict__ cursor,
                            unsigned short* __restrict__ csr) {
    int base = (blockIdx.x * blockDim.x + threadIdx.x) * 4;
    if (base >= EE) return;
    int4 s4 = *(const int4*)(ei + base);
    int4 d4 = *(const int4*)(ei + EE + base);
    int p0 = atomicAdd(&cursor[d4.x], 1);
    int p1 = atomicAdd(&cursor[d4.y], 1);
    int p2 = atomicAdd(&cursor[d4.z], 1);
    int p3 = atomicAdd(&cursor[d4.w], 1);
    csr[p0] = (unsigned short)s4.x;
    csr[p1] = (unsigned short)s4.y;
    csr[p2] = (unsigned short)s4.z;
    csr[p3] = (unsigned short)s4.w;
}

// ---------------- layer-1 aggregation (bf16 hmid out) ----------------
__global__ void agg1_kernel(const unsigned short* __restrict__ h1b,
                            const float* __restrict__ e_src, const float* __restrict__ e_dst,
                            const int* __restrict__ rowptr, const int* __restrict__ deg,
                            const unsigned short* __restrict__ csr,
                            const float* __restrict__ b1, unsigned short* __restrict__ hmid) {
    const int d = blockIdx.x * 4 + (threadIdx.x >> 6);
    const int lane = threadIdx.x & 63;
    const int g = lane >> 4;       // edge-group 0..3
    const int l = lane & 15;       // channel-lane: channels 8l..8l+7
    const int hd = l >> 1;
    const float ed = e_dst[(size_t)d * HEADS + hd];  // pre-scaled by log2e
    const int start = rowptr[d];
    const int cnt = deg[d];

    float denom = 0.f;
    float acc[8] = {0.f, 0.f, 0.f, 0.f, 0.f, 0.f, 0.f, 0.f};

    for (int i = g; i < cnt; i += 8) {
        const int i1 = i + 4;
        const bool v1 = i1 < cnt;
        const int j1 = v1 ? i1 : i;
        int s0 = csr[start + i];
        int s1 = csr[start + j1];
        float es0 = e_src[(size_t)s0 * HEADS + hd];
        float es1 = e_src[(size_t)s1 * HEADS + hd];
        uint4 g0 = *(const uint4*)(h1b + (size_t)s0 * C1 + 8 * l);
        uint4 g1 = *(const uint4*)(h1b + (size_t)s1 * C1 + 8 * l);
        float w0 = fexp2(lrelu(es0 + ed));
        float w1 = v1 ? fexp2(lrelu(es1 + ed)) : 0.f;
        denom += w0 + w1;
        acc[0] += w0 * bflo(g0.x) + w1 * bflo(g1.x);
        acc[1] += w0 * bfhi(g0.x) + w1 * bfhi(g1.x);
        acc[2] += w0 * bflo(g0.y) + w1 * bflo(g1.y);
        acc[3] += w0 * bfhi(g0.y) + w1 * bfhi(g1.y);
        acc[4] += w0 * bflo(g0.z) + w1 * bflo(g1.z);
        acc[5] += w0 * bfhi(g0.z) + w1 * bfhi(g1.z);
        acc[6] += w0 * bflo(g0.w) + w1 * bflo(g1.w);
        acc[7] += w0 * bfhi(g0.w) + w1 * bfhi(g1.w);
    }
    // combine the 4 edge-groups (lanes l, l+16, l+32, l+48)
    denom += __shfl_xor(denom, 16);
    denom += __shfl_xor(denom, 32);
    #pragma unroll
    for (int k = 0; k < 8; ++k) {
        acc[k] += __shfl_xor(acc[k], 16);
        acc[k] += __shfl_xor(acc[k], 32);
    }
    if (g == 0) {
        const float inv = 1.f / (denom + 1e-16f);
        float o[8];
        #pragma unroll
        for (int k = 0; k < 8; ++k) {
            float t = acc[k] * inv + b1[8 * l + k];
            o[k] = (t > 0.f) ? t : expm1f(t);
        }
        uint4 st;
        st.x = cvtpk(o[0], o[1]);
        st.y = cvtpk(o[2], o[3]);
        st.z = cvtpk(o[4], o[5]);
        st.w = cvtpk(o[6], o[7]);
        *(uint4*)(hmid + (size_t)d * C1 + 8 * l) = st;  // bf16 row, 16B/lane
    }
}

// ---------------- GEMM2 (bf16 A direct, preconverted W2b) + MFMA elogit2 ----------------
__global__ __launch_bounds__(256, 4)
void gemm2_kernel(const unsigned short* __restrict__ hmid,
                  const unsigned short* __restrict__ W2b,
                  const unsigned short* __restrict__ va2b,
                  unsigned short* __restrict__ h2b,
                  float* __restrict__ e_src, float* __restrict__ e_dst) {
    const int tid = threadIdx.x;
    const int w = tid >> 6, lane = tid & 63;
    const int q = lane >> 4, c = lane & 15;

    const int m0 = (blockIdx.x * 4 + w) * 16;
    if (m0 >= NN) return;
    int row = m0 + c;
    if (row > NN - 1) row = NN - 1;
    bf16x8 afrag[4];
    #pragma unroll
    for (int kc = 0; kc < 4; ++kc)
        afrag[kc] = *(const bf16x8*)(hmid + (size_t)row * C1 + kc * 32 + q * 8);  // no converts

    bf16x8 bfrag[3][4];
    #pragma unroll
    for (int nt = 0; nt < 3; ++nt)
        #pragma unroll
        for (int kc = 0; kc < 4; ++kc)
            bfrag[nt][kc] = *(const bf16x8*)(W2b + (size_t)((nt * 4 + kc) * 64 + lane) * 8);
    // e-tile cols: 0=src_hi, 1=src_lo, 2=dst_hi, 3=dst_lo (from prep, 1KB L2-hot)
    bf16x8 bfe[4];
    #pragma unroll
    for (int kc = 0; kc < 4; ++kc) {
        bf16x8 bb = 0;
        if (c < 4) bb = *(const bf16x8*)(va2b + c * 128 + kc * 32 + q * 8);
        bfe[kc] = bb;
    }

    f32x4 acc[3] = {{0.f,0.f,0.f,0.f},{0.f,0.f,0.f,0.f},{0.f,0.f,0.f,0.f}};
    f32x4 acce = {0.f, 0.f, 0.f, 0.f};
    #pragma unroll
    for (int kc = 0; kc < 4; ++kc) {
        acc[0] = __builtin_amdgcn_mfma_f32_16x16x32_bf16(afrag[kc], bfrag[0][kc], acc[0], 0, 0, 0);
        acc[1] = __builtin_amdgcn_mfma_f32_16x16x32_bf16(afrag[kc], bfrag[1][kc], acc[1], 0, 0, 0);
        acc[2] = __builtin_amdgcn_mfma_f32_16x16x32_bf16(afrag[kc], bfrag[2][kc], acc[2], 0, 0, 0);
        acce   = __builtin_amdgcn_mfma_f32_16x16x32_bf16(afrag[kc], bfe[kc],      acce,   0, 0, 0);
    }
    #pragma unroll
    for (int r = 0; r < 4; ++r) {
        const int ro = m0 + q * 4 + r;
        // combine hi+lo columns: cols (0,1) -> e_src, cols (2,3) -> e_dst
        float v = acce[r] + __shfl_xor(acce[r], 1);
        if (ro < NN) {
            #pragma unroll
            for (int nt = 0; nt < 3; ++nt) {
                const int col = nt * 16 + c;
                if (col < CLASSES)
                    h2b[(size_t)ro * CLASSES + col] = (unsigned short)cvtpk(acc[nt][r], acc[nt][r]);
            }
            if (c == 0) e_src[ro] = v;
            if (c == 2) e_dst[ro] = v;
        }
    }
}

// ---------------- layer-2 aggregation -> output ----------------
__global__ void agg2_kernel(const unsigned short* __restrict__ h2b,
                            const float* __restrict__ e_src, const float* __restrict__ e_dst,
                            const int* __restrict__ rowptr, const int* __restrict__ deg,
                            const unsigned short* __restrict__ csr,
                            const float* __restrict__ b2, float* __restrict__ out) {
    const int d = blockIdx.x * 4 + (threadIdx.x >> 6);
    const int lane = threadIdx.x & 63;
    const int eg = lane / 20;      // 0..2 active, 3 = idle lanes 60..63
    const int c  = lane % 20;
    const bool act = lane < 60;
    const float ed = e_dst[d];     // pre-scaled by log2e
    const int start = rowptr[d];
    const int cnt = deg[d];

    float denom = 0.f, acc0 = 0.f, acc1 = 0.f;
    for (int i = act ? eg : cnt; i < cnt; i += 6) {
        const int i1 = i + 3;
        const bool v1 = i1 < cnt;
        const int j1 = v1 ? i1 : i;
        int s0 = csr[start + i];
        int s1 = csr[start + j1];
        float es0 = e_src[s0], es1 = e_src[s1];
        unsigned g0 = *(const unsigned*)(h2b + (size_t)s0 * CLASSES + 2 * c);
        unsigned g1 = *(const unsigned*)(h2b + (size_t)s1 * CLASSES + 2 * c);
        float w0 = fexp2(lrelu(es0 + ed));
        float w1 = v1 ? fexp2(lrelu(es1 + ed)) : 0.f;
        denom += w0 + w1;
        acc0 += w0 * bflo(g0) + w1 * bflo(g1);
        acc1 += w0 * bfhi(g0) + w1 * bfhi(g1);
    }
    // combine 3 edge-groups: lanes c, c+20, c+40
    float dA = __shfl(denom, c + 20), dB = __shfl(denom, c + 40);
    float aA = __shfl(acc0,  c + 20), aB = __shfl(acc0,  c + 40);
    float bA = __shfl(acc1,  c + 20), bB = __shfl(acc1,  c + 40);
    if (lane < 20) {
        denom += dA + dB;
        acc0  += aA + aB;
        acc1  += bA + bB;
        const float inv = 1.f / (denom + 1e-16f);
        float2 o;
        o.x = acc0 * inv + b2[2 * c];
        o.y = acc1 * inv + b2[2 * c + 1];
        *(float2*)(out + (size_t)d * CLASSES + 2 * c) = o;
    }
}

extern "C" void kernel_launch(void* const* d_in, const int* in_sizes, int n_in,
                              void* d_out, int out_size, void* d_ws, size_t ws_size,
                              hipStream_t stream) {
    const float* x      = (const float*)d_in[0];
    const int*   ei     = (const int*)d_in[1];
    const float* W1     = (const float*)d_in[2];
    const float* a_src1 = (const float*)d_in[3];
    const float* a_dst1 = (const float*)d_in[4];
    const float* b1     = (const float*)d_in[5];
    const float* W2     = (const float*)d_in[6];
    const float* a_src2 = (const float*)d_in[7];
    const float* a_dst2 = (const float*)d_in[8];
    const float* b2     = (const float*)d_in[9];
    float* out = (float*)d_out;

    char* ws = (char*)d_ws;
    size_t off = 0;
    auto alloc = [&](size_t bytes) { char* p = ws + off; off += (bytes + 255) & ~(size_t)255; return p; };
    unsigned short* h1b   = (unsigned short*)alloc((size_t)NN * C1 * 2);
    unsigned short* h2b   = (unsigned short*)alloc((size_t)NN * CLASSES * 2);
    unsigned short* hmidb = (unsigned short*)alloc((size_t)NN * C1 * 2);
    float* e_src1 = (float*)alloc((size_t)NN * HEADS * 4);
    float* e_dst1 = (float*)alloc((size_t)NN * HEADS * 4);
    float* e_src2 = (float*)alloc((size_t)NN * 4);
    float* e_dst2 = (float*)alloc((size_t)NN * 4);
    int*   deg    = (int*)alloc((size_t)NN * 4);
    int*   rowptr = (int*)alloc((size_t)NN * 4);
    int*   cursor = (int*)alloc((size_t)NN * 4);
    unsigned short* csr  = (unsigned short*)alloc((size_t)ET * 2);
    int*   bsum   = (int*)alloc(256 * 4);
    unsigned short* va1h = (unsigned short*)alloc(16 * 128 * 2);
    unsigned short* va1l = (unsigned short*)alloc(16 * 128 * 2);
    unsigned short* va2b = (unsigned short*)alloc(4 * 128 * 2);
    unsigned short* W1b  = (unsigned short*)alloc(2048 * 8 * 2);
    unsigned short* W2b  = (unsigned short*)alloc(768 * 8 * 2);

    prep_kernel<<<3 + NCHUNKS, 256, 0, stream>>>(W1, a_src1, a_dst1, W2, a_src2, a_dst2,
                                                 va1h, va1l, va2b, W1b, W2b, deg);
    gemm1_count_kernel<<<GB1 + CB1, 256, 0, stream>>>(x, W1b, va1h, va1l, ei,
                                                      h1b, e_src1, e_dst1, deg);
    scan1_kernel<<<NCHUNKS, 256, 0, stream>>>(deg, rowptr, bsum);
    scan3_kernel<<<(NN + 255) / 256, 256, 0, stream>>>(rowptr, bsum, cursor, csr, deg);
    fill_kernel<<<(EE / 4 + 255) / 256, 256, 0, stream>>>(ei, cursor, csr);

    agg1_kernel<<<NN / 4, 256, 0, stream>>>(h1b, e_src1, e_dst1, rowptr, deg, csr, b1, hmidb);

    gemm2_kernel<<<(NN + 63) / 64, 256, 0, stream>>>(hmidb, W2b, va2b, h2b, e_src2, e_dst2);
    agg2_kernel<<<NN / 4, 256, 0, stream>>>(h2b, e_src2, e_dst2, rowptr, deg, csr, b2, out);
}

// Round 5
// 267.072 us; speedup vs baseline: 1.1071x; 1.0395x over previous
//
#include <hip/hip_runtime.h>
#include <math.h>

#define NN 50000
#define EE 800000
#define ET (EE + NN)      // edges + self loops
#define F_IN 128
#define HEADS 8
#define HID 16
#define C1 (HEADS * HID)  // 128
#define CLASSES 40
#define NEG_SLOPE 0.2f
#define LOG2E 1.4426950408889634f

#define GB1 ((NN + 31) / 32)        // 1563 gemm1 blocks
#define CB1 ((EE / 4 + 255) / 256)  // 782 count blocks
#define NCHUNKS ((NN + 1023) / 1024)  // 49

typedef __attribute__((ext_vector_type(8))) short bf16x8;
typedef __attribute__((ext_vector_type(4))) float f32x4;
typedef __attribute__((ext_vector_type(8))) _Float16 h16x8;
typedef __attribute__((ext_vector_type(2))) _Float16 h16x2;

__device__ __forceinline__ unsigned cvtpk(float a, float b) {
    unsigned r;
    asm("v_cvt_pk_bf16_f32 %0, %1, %2" : "=v"(r) : "v"(a), "v"(b));
    return r;
}
__device__ __forceinline__ float fexp2(float x) {
    float r;
    asm("v_exp_f32 %0, %1\n\ts_nop 0" : "=v"(r) : "v"(x));
    return r;
}
__device__ __forceinline__ float bflo(unsigned u) { return __uint_as_float(u << 16); }
__device__ __forceinline__ float bfhi(unsigned u) { return __uint_as_float(u & 0xffff0000u); }
__device__ __forceinline__ float lrelu(float a) { return fmaxf(a, NEG_SLOPE * a); }
__device__ __forceinline__ unsigned short bf1(float a) { return (unsigned short)cvtpk(a, a); }
__device__ __forceinline__ float bf1f(float a) { return bflo(cvtpk(a, a)); }
__device__ __forceinline__ bf16x8 pack8(float f0, float f1, float f2, float f3,
                                        float f4, float f5, float f6, float f7) {
    union { unsigned u[4]; bf16x8 v; } U;
    U.u[0] = cvtpk(f0, f1);
    U.u[1] = cvtpk(f2, f3);
    U.u[2] = cvtpk(f4, f5);
    U.u[3] = cvtpk(f6, f7);
    return U.v;
}

// ---------------- prep ----------------
// block 0: va1 (16x128 hi/lo bf16, frag layout) + va2 (4x128 bf16)
// block 1: W1b — W1 as bf16 MFMA fragments
// block 2: W2b — W2 fragments, cols >= CLASSES zeroed
// blocks 3+: zero deg
__global__ void prep_kernel(const float* __restrict__ W1,
                            const float* __restrict__ as1, const float* __restrict__ ad1,
                            const float* __restrict__ W2,
                            const float* __restrict__ as2, const float* __restrict__ ad2,
                            unsigned short* __restrict__ va1h, unsigned short* __restrict__ va1l,
                            unsigned short* __restrict__ va2b,
                            unsigned short* __restrict__ W1b, unsigned short* __restrict__ W2b,
                            int* __restrict__ deg) {
    const int tid = threadIdx.x;
    const int b = blockIdx.x;
    if (b >= 3) {  // deg zeroing (replaces hipMemsetAsync)
        int base = ((b - 3) * 256 + tid) * 4;
        if (base < NN) *(int4*)(deg + base) = make_int4(0, 0, 0, 0);
        return;
    }
    if (b == 1) {  // W1b fragments: 2048 frags, 8 per thread
        for (int f = tid; f < 2048; f += 256) {
            const int lane = f & 63, kc = (f >> 6) & 3, ntw = f >> 8;
            const int q = lane >> 4, c = lane & 15;
            const int col = (ntw >> 1) * 32 + (ntw & 1) * 16 + c;
            const int k0 = kc * 32 + q * 8;
            const float* wp = W1 + (size_t)k0 * C1 + col;
            *(bf16x8*)(W1b + (size_t)f * 8) =
                pack8(wp[0], wp[C1], wp[2 * C1], wp[3 * C1],
                      wp[4 * C1], wp[5 * C1], wp[6 * C1], wp[7 * C1]);
        }
        return;
    }
    if (b == 2) {  // W2b fragments: 768 frags
        for (int f = tid; f < 768; f += 256) {
            const int lane = f & 63, kc = (f >> 6) & 3, nt = f >> 8;
            const int q = lane >> 4, c = lane & 15;
            const int col = nt * 16 + c;
            const int k0 = kc * 32 + q * 8;
            bf16x8 v = 0;
            if (col < CLASSES) {
                const float* wp = W2 + (size_t)k0 * CLASSES + col;
                v = pack8(wp[0], wp[CLASSES], wp[2 * CLASSES], wp[3 * CLASSES],
                          wp[4 * CLASSES], wp[5 * CLASSES], wp[6 * CLASSES], wp[7 * CLASSES]);
            }
            *(bf16x8*)(W2b + (size_t)f * 8) = v;
        }
        return;
    }
    {   // va1: thread (k, half) computes 4 heads x {src,dst}
        const int k = tid >> 1, half = tid & 1;
        const float* wrow = W1 + (size_t)k * C1 + half * 64;
        #pragma unroll
        for (int hh = 0; hh < 4; ++hh) {
            const int h = half * 4 + hh;
            float s = 0.f, d = 0.f;
            #pragma unroll
            for (int t = 0; t < 16; ++t) {
                float wv = wrow[hh * 16 + t];
                s += wv * as1[h * HID + t];
                d += wv * ad1[h * HID + t];
            }
            s *= LOG2E; d *= LOG2E;
            va1h[h * 128 + k]       = bf1(s);
            va1l[h * 128 + k]       = bf1(s - bf1f(s));
            va1h[(h + 8) * 128 + k] = bf1(d);
            va1l[(h + 8) * 128 + k] = bf1(d - bf1f(d));
        }
    }
    if (tid < C1) {  // va2: thread k dots W2 row k with a2 vectors
        const float* wrow = W2 + (size_t)tid * CLASSES;
        float s = 0.f, d = 0.f;
        #pragma unroll
        for (int c2 = 0; c2 < CLASSES; ++c2) {
            float wv = wrow[c2];
            s += wv * as2[c2];
            d += wv * ad2[c2];
        }
        s *= LOG2E; d *= LOG2E;
        va2b[0 * 128 + tid] = bf1(s);
        va2b[1 * 128 + tid] = bf1(s - bf1f(s));
        va2b[2 * 128 + tid] = bf1(d);
        va2b[3 * 128 + tid] = bf1(d - bf1f(d));
    }
}

// ---------------- GEMM1 + MFMA elogit1 + interleaved count ----------------
// h1 stored as f16 (feeds only the agg gather path; f16 = 8x better mantissa than bf16)
__global__ __launch_bounds__(256, 4)
void gemm1_count_kernel(const float* __restrict__ x,
                        const unsigned short* __restrict__ W1b,
                        const unsigned short* __restrict__ va1h,
                        const unsigned short* __restrict__ va1l,
                        const int* __restrict__ ei,
                        _Float16* __restrict__ h1h,
                        float* __restrict__ e_src, float* __restrict__ e_dst,
                        int* __restrict__ deg) {
    const int bid = blockIdx.x;
    const int tid = threadIdx.x;
    // interleave: bid<2*CB1: odd = count, even = gemm; bid>=2*CB1: gemm
    int gemmb;
    if (bid < 2 * CB1) {
        if (bid & 1) {  // -------- count (overlapped with gemm throughout) --------
            int base = ((bid >> 1) * 256 + tid) * 4;
            if (base < EE) {
                int4 d4 = *(const int4*)(ei + EE + base);
                atomicAdd(&deg[d4.x], 1);
                atomicAdd(&deg[d4.y], 1);
                atomicAdd(&deg[d4.z], 1);
                atomicAdd(&deg[d4.w], 1);
            }
            return;
        }
        gemmb = bid >> 1;
    } else {
        gemmb = bid - CB1;
    }

    const int w = tid >> 6, lane = tid & 63;
    const int q = lane >> 4, c = lane & 15;

    // hoisted A-loads for both m-tiles (16 independent 16B loads -> MLP)
    bf16x8 afrag[2][4];
    #pragma unroll
    for (int mt = 0; mt < 2; ++mt) {
        const int m0 = (gemmb * 2 + mt) * 16;
        int row = m0 + c;
        if (row > NN - 1) row = NN - 1;
        #pragma unroll
        for (int kc = 0; kc < 4; ++kc) {
            const float* xp = x + (size_t)row * F_IN + kc * 32 + q * 8;
            float4 p0 = *(const float4*)xp;
            float4 p1 = *(const float4*)(xp + 4);
            afrag[mt][kc] = pack8(p0.x, p0.y, p0.z, p0.w, p1.x, p1.y, p1.z, p1.w);
        }
    }

    // B fragments: preconverted, fully-coalesced 16B loads (L2-hot 32KB)
    bf16x8 bfrag[2][4];
    #pragma unroll
    for (int nt = 0; nt < 2; ++nt)
        #pragma unroll
        for (int kc = 0; kc < 4; ++kc)
            bfrag[nt][kc] = *(const bf16x8*)(W1b + ((size_t)(((w * 2 + nt) * 4 + kc) * 64 + lane)) * 8);
    // e-operand fragments from prep (L2-hot 8KB)
    bf16x8 beh[4], bel[4];
    #pragma unroll
    for (int kc = 0; kc < 4; ++kc) {
        const int coloff = kc * 32 + q * 8;
        beh[kc] = *(const bf16x8*)(va1h + c * 128 + coloff);
        bel[kc] = *(const bf16x8*)(va1l + c * 128 + coloff);
    }

    #pragma unroll
    for (int mt = 0; mt < 2; ++mt) {
        const int m0 = (gemmb * 2 + mt) * 16;
        f32x4 acc0 = {0.f, 0.f, 0.f, 0.f};
        f32x4 acc1 = {0.f, 0.f, 0.f, 0.f};
        #pragma unroll
        for (int kc = 0; kc < 4; ++kc) {
            acc0 = __builtin_amdgcn_mfma_f32_16x16x32_bf16(afrag[mt][kc], bfrag[0][kc], acc0, 0, 0, 0);
            acc1 = __builtin_amdgcn_mfma_f32_16x16x32_bf16(afrag[mt][kc], bfrag[1][kc], acc1, 0, 0, 0);
        }
        // e-MFMA: wave `mt` computes e_src/e_dst for this m-tile
        if (w == mt) {
            f32x4 acce = {0.f, 0.f, 0.f, 0.f};
            #pragma unroll
            for (int kc = 0; kc < 4; ++kc) {
                acce = __builtin_amdgcn_mfma_f32_16x16x32_bf16(afrag[mt][kc], beh[kc], acce, 0, 0, 0);
                acce = __builtin_amdgcn_mfma_f32_16x16x32_bf16(afrag[mt][kc], bel[kc], acce, 0, 0, 0);
            }
            float* ep = (c < 8) ? e_src : e_dst;
            const int cc = c & 7;
            #pragma unroll
            for (int r = 0; r < 4; ++r) {
                const int ro = m0 + q * 4 + r;
                if (ro < NN) ep[(size_t)ro * HEADS + cc] = acce[r];
            }
        }
        #pragma unroll
        for (int r = 0; r < 4; ++r) {
            const int ro = m0 + q * 4 + r;
            if (ro < NN) {
                h1h[(size_t)ro * C1 + w * 32 + c]      = (_Float16)acc0[r];
                h1h[(size_t)ro * C1 + w * 32 + 16 + c] = (_Float16)acc1[r];
            }
        }
    }
}

// ---------------- CSR scan ----------------
// exclusive scan over (deg[i] + 1)  [+1 = self-loop]
__global__ void scan1_kernel(const int* __restrict__ deg, int* __restrict__ rowptr,
                             int* __restrict__ bsum) {
    __shared__ int sh[256];
    const int tid = threadIdx.x;
    const int base = blockIdx.x * 1024 + tid * 4;
    int v[4], s[4];
    #pragma unroll
    for (int j = 0; j < 4; ++j) v[j] = (base + j < NN) ? (deg[base + j] + 1) : 0;
    s[0] = v[0]; s[1] = s[0] + v[1]; s[2] = s[1] + v[2]; s[3] = s[2] + v[3];
    int T = s[3];
    sh[tid] = T;
    __syncthreads();
    for (int off = 1; off < 256; off <<= 1) {
        int xv = (tid >= off) ? sh[tid - off] : 0;
        __syncthreads();
        sh[tid] += xv;
        __syncthreads();
    }
    int excl = sh[tid] - T;
    #pragma unroll
    for (int j = 0; j < 4; ++j)
        if (base + j < NN) rowptr[base + j] = excl + s[j] - v[j];
    if (tid == 255) bsum[blockIdx.x] = sh[255];
}

// finalize rowptr (scan2 fused); self-loop at slot rowptr[i]; cursor past it; deg -> total cnt
__global__ void scan3_kernel(int* __restrict__ rowptr, const int* __restrict__ bsum,
                             int* __restrict__ cursor, unsigned short* __restrict__ csr,
                             int* __restrict__ deg) {
    __shared__ int ex[64];
    const int tid = threadIdx.x;
    if (tid < 64) {
        int v = (tid < NCHUNKS) ? bsum[tid] : 0;
        int s = v;
        #pragma unroll
        for (int off = 1; off < 64; off <<= 1) {
            int xv = __shfl_up(s, off);
            if (tid >= off) s += xv;
        }
        ex[tid] = s - v;  // exclusive prefix
    }
    __syncthreads();
    int i = blockIdx.x * blockDim.x + tid;
    if (i >= NN) return;
    int rp = rowptr[i] + ex[i >> 10];
    rowptr[i] = rp;
    cursor[i] = rp + 1;
    csr[rp] = (unsigned short)i;  // self-loop first
    deg[i] += 1;                  // total incoming count incl. self-loop
}

// scatter real edges: 4 per thread, int4 loads, ushort payloads (L2-merged stores)
__global__ void fill_kernel(const int* __restrict__ ei, int* __restrict__ cursor,
                            unsigned short* __restrict__ csr) {
    int base = (blockIdx.x * blockDim.x + threadIdx.x) * 4;
    if (base >= EE) return;
    int4 s4 = *(const int4*)(ei + base);
    int4 d4 = *(const int4*)(ei + EE + base);
    int p0 = atomicAdd(&cursor[d4.x], 1);
    int p1 = atomicAdd(&cursor[d4.y], 1);
    int p2 = atomicAdd(&cursor[d4.z], 1);
    int p3 = atomicAdd(&cursor[d4.w], 1);
    csr[p0] = (unsigned short)s4.x;
    csr[p1] = (unsigned short)s4.y;
    csr[p2] = (unsigned short)s4.z;
    csr[p3] = (unsigned short)s4.w;
}

// ---------------- layer-1 aggregation (f16 gather, fma_mix; bf16 hmid out) ----------------
// block = 256 = 4 waves; wave per dst node. Wave = 4 edge-groups x 16 lanes.
// Lane l owns channels 8l..8l+7; head = l>>1. Group g: edges i = g, g+4, g+8, g+12 (stride 16).
__global__ void agg1_kernel(const _Float16* __restrict__ h1h,
                            const float* __restrict__ e_src, const float* __restrict__ e_dst,
                            const int* __restrict__ rowptr, const int* __restrict__ deg,
                            const unsigned short* __restrict__ csr,
                            const float* __restrict__ b1, unsigned short* __restrict__ hmid) {
    const int d = blockIdx.x * 4 + (threadIdx.x >> 6);
    const int lane = threadIdx.x & 63;
    const int g = lane >> 4;       // edge-group 0..3
    const int l = lane & 15;       // channel-lane: channels 8l..8l+7
    const int hd = l >> 1;
    const float ed = e_dst[(size_t)d * HEADS + hd];  // pre-scaled by log2e
    const int start = rowptr[d];
    const int cnt = deg[d];

    float denom = 0.f;
    float acc[8] = {0.f, 0.f, 0.f, 0.f, 0.f, 0.f, 0.f, 0.f};

    for (int i = g; i < cnt; i += 16) {
        const int i1 = i + 4, i2 = i + 8, i3 = i + 12;
        const bool v1 = i1 < cnt, v2 = i2 < cnt, v3 = i3 < cnt;
        int s0 = csr[start + i];
        int s1 = csr[start + (v1 ? i1 : i)];
        int s2 = csr[start + (v2 ? i2 : i)];
        int s3 = csr[start + (v3 ? i3 : i)];
        float es0 = e_src[(size_t)s0 * HEADS + hd];
        float es1 = e_src[(size_t)s1 * HEADS + hd];
        float es2 = e_src[(size_t)s2 * HEADS + hd];
        float es3 = e_src[(size_t)s3 * HEADS + hd];
        h16x8 g0 = *(const h16x8*)(h1h + (size_t)s0 * C1 + 8 * l);
        h16x8 g1 = *(const h16x8*)(h1h + (size_t)s1 * C1 + 8 * l);
        h16x8 g2 = *(const h16x8*)(h1h + (size_t)s2 * C1 + 8 * l);
        h16x8 g3 = *(const h16x8*)(h1h + (size_t)s3 * C1 + 8 * l);
        float w0 = fexp2(lrelu(es0 + ed));
        float w1 = v1 ? fexp2(lrelu(es1 + ed)) : 0.f;
        float w2 = v2 ? fexp2(lrelu(es2 + ed)) : 0.f;
        float w3 = v3 ? fexp2(lrelu(es3 + ed)) : 0.f;
        denom += (w0 + w1) + (w2 + w3);
        #pragma unroll
        for (int j = 0; j < 8; ++j) {
            // (float)f16 * f32 + f32 -> v_fma_mix_f32 (no unpack insts)
            acc[j] = fmaf((float)g0[j], w0, acc[j]);
            acc[j] = fmaf((float)g1[j], w1, acc[j]);
            acc[j] = fmaf((float)g2[j], w2, acc[j]);
            acc[j] = fmaf((float)g3[j], w3, acc[j]);
        }
    }
    // combine the 4 edge-groups (lanes l, l+16, l+32, l+48)
    denom += __shfl_xor(denom, 16);
    denom += __shfl_xor(denom, 32);
    #pragma unroll
    for (int k = 0; k < 8; ++k) {
        acc[k] += __shfl_xor(acc[k], 16);
        acc[k] += __shfl_xor(acc[k], 32);
    }
    if (g == 0) {
        const float inv = 1.f / (denom + 1e-16f);
        float o[8];
        #pragma unroll
        for (int k = 0; k < 8; ++k) {
            float t = acc[k] * inv + b1[8 * l + k];
            o[k] = (t > 0.f) ? t : expm1f(t);
        }
        uint4 st;
        st.x = cvtpk(o[0], o[1]);
        st.y = cvtpk(o[2], o[3]);
        st.z = cvtpk(o[4], o[5]);
        st.w = cvtpk(o[6], o[7]);
        *(uint4*)(hmid + (size_t)d * C1 + 8 * l) = st;  // bf16 row, 16B/lane
    }
}

// ---------------- GEMM2 (bf16 A direct, preconverted W2b) + MFMA elogit2 ----------------
__global__ __launch_bounds__(256, 4)
void gemm2_kernel(const unsigned short* __restrict__ hmid,
                  const unsigned short* __restrict__ W2b,
                  const unsigned short* __restrict__ va2b,
                  _Float16* __restrict__ h2h,
                  float* __restrict__ e_src, float* __restrict__ e_dst) {
    const int tid = threadIdx.x;
    const int w = tid >> 6, lane = tid & 63;
    const int q = lane >> 4, c = lane & 15;

    const int m0 = (blockIdx.x * 4 + w) * 16;
    if (m0 >= NN) return;
    int row = m0 + c;
    if (row > NN - 1) row = NN - 1;
    bf16x8 afrag[4];
    #pragma unroll
    for (int kc = 0; kc < 4; ++kc)
        afrag[kc] = *(const bf16x8*)(hmid + (size_t)row * C1 + kc * 32 + q * 8);  // no converts

    bf16x8 bfrag[3][4];
    #pragma unroll
    for (int nt = 0; nt < 3; ++nt)
        #pragma unroll
        for (int kc = 0; kc < 4; ++kc)
            bfrag[nt][kc] = *(const bf16x8*)(W2b + (size_t)((nt * 4 + kc) * 64 + lane) * 8);
    // e-tile cols: 0=src_hi, 1=src_lo, 2=dst_hi, 3=dst_lo (from prep, 1KB L2-hot)
    bf16x8 bfe[4];
    #pragma unroll
    for (int kc = 0; kc < 4; ++kc) {
        bf16x8 bb = 0;
        if (c < 4) bb = *(const bf16x8*)(va2b + c * 128 + kc * 32 + q * 8);
        bfe[kc] = bb;
    }

    f32x4 acc[3] = {{0.f,0.f,0.f,0.f},{0.f,0.f,0.f,0.f},{0.f,0.f,0.f,0.f}};
    f32x4 acce = {0.f, 0.f, 0.f, 0.f};
    #pragma unroll
    for (int kc = 0; kc < 4; ++kc) {
        acc[0] = __builtin_amdgcn_mfma_f32_16x16x32_bf16(afrag[kc], bfrag[0][kc], acc[0], 0, 0, 0);
        acc[1] = __builtin_amdgcn_mfma_f32_16x16x32_bf16(afrag[kc], bfrag[1][kc], acc[1], 0, 0, 0);
        acc[2] = __builtin_amdgcn_mfma_f32_16x16x32_bf16(afrag[kc], bfrag[2][kc], acc[2], 0, 0, 0);
        acce   = __builtin_amdgcn_mfma_f32_16x16x32_bf16(afrag[kc], bfe[kc],      acce,   0, 0, 0);
    }
    #pragma unroll
    for (int r = 0; r < 4; ++r) {
        const int ro = m0 + q * 4 + r;
        // combine hi+lo columns: cols (0,1) -> e_src, cols (2,3) -> e_dst
        float v = acce[r] + __shfl_xor(acce[r], 1);
        if (ro < NN) {
            #pragma unroll
            for (int nt = 0; nt < 3; ++nt) {
                const int col = nt * 16 + c;
                if (col < CLASSES)
                    h2h[(size_t)ro * CLASSES + col] = (_Float16)acc[nt][r];
            }
            if (c == 0) e_src[ro] = v;
            if (c == 2) e_dst[ro] = v;
        }
    }
}

// ---------------- layer-2 aggregation -> output ----------------
// block = 256 = 4 waves; wave per dst node. Wave = 3 edge-groups x 20 lanes (60 active).
// 4-edge unroll: group eg handles i = eg, eg+3, eg+6, eg+9 (stride 12).
__global__ void agg2_kernel(const _Float16* __restrict__ h2h,
                            const float* __restrict__ e_src, const float* __restrict__ e_dst,
                            const int* __restrict__ rowptr, const int* __restrict__ deg,
                            const unsigned short* __restrict__ csr,
                            const float* __restrict__ b2, float* __restrict__ out) {
    const int d = blockIdx.x * 4 + (threadIdx.x >> 6);
    const int lane = threadIdx.x & 63;
    const int eg = lane / 20;      // 0..2 active, 3 = idle lanes 60..63
    const int c  = lane % 20;
    const bool act = lane < 60;
    const float ed = e_dst[d];     // pre-scaled by log2e
    const int start = rowptr[d];
    const int cnt = deg[d];

    float denom = 0.f, acc0 = 0.f, acc1 = 0.f;
    for (int i = act ? eg : cnt; i < cnt; i += 12) {
        const int i1 = i + 3, i2 = i + 6, i3 = i + 9;
        const bool v1 = i1 < cnt, v2 = i2 < cnt, v3 = i3 < cnt;
        int s0 = csr[start + i];
        int s1 = csr[start + (v1 ? i1 : i)];
        int s2 = csr[start + (v2 ? i2 : i)];
        int s3 = csr[start + (v3 ? i3 : i)];
        float es0 = e_src[s0], es1 = e_src[s1], es2 = e_src[s2], es3 = e_src[s3];
        h16x2 g0 = *(const h16x2*)(h2h + (size_t)s0 * CLASSES + 2 * c);
        h16x2 g1 = *(const h16x2*)(h2h + (size_t)s1 * CLASSES + 2 * c);
        h16x2 g2 = *(const h16x2*)(h2h + (size_t)s2 * CLASSES + 2 * c);
        h16x2 g3 = *(const h16x2*)(h2h + (size_t)s3 * CLASSES + 2 * c);
        float w0 = fexp2(lrelu(es0 + ed));
        float w1 = v1 ? fexp2(lrelu(es1 + ed)) : 0.f;
        float w2 = v2 ? fexp2(lrelu(es2 + ed)) : 0.f;
        float w3 = v3 ? fexp2(lrelu(es3 + ed)) : 0.f;
        denom += (w0 + w1) + (w2 + w3);
        acc0 = fmaf((float)g0[0], w0, acc0); acc1 = fmaf((float)g0[1], w0, acc1);
        acc0 = fmaf((float)g1[0], w1, acc0); acc1 = fmaf((float)g1[1], w1, acc1);
        acc0 = fmaf((float)g2[0], w2, acc0); acc1 = fmaf((float)g2[1], w2, acc1);
        acc0 = fmaf((float)g3[0], w3, acc0); acc1 = fmaf((float)g3[1], w3, acc1);
    }
    // combine 3 edge-groups: lanes c, c+20, c+40
    float dA = __shfl(denom, c + 20), dB = __shfl(denom, c + 40);
    float aA = __shfl(acc0,  c + 20), aB = __shfl(acc0,  c + 40);
    float bA = __shfl(acc1,  c + 20), bB = __shfl(acc1,  c + 40);
    if (lane < 20) {
        denom += dA + dB;
        acc0  += aA + aB;
        acc1  += bA + bB;
        const float inv = 1.f / (denom + 1e-16f);
        float2 o;
        o.x = acc0 * inv + b2[2 * c];
        o.y = acc1 * inv + b2[2 * c + 1];
        *(float2*)(out + (size_t)d * CLASSES + 2 * c) = o;
    }
}

extern "C" void kernel_launch(void* const* d_in, const int* in_sizes, int n_in,
                              void* d_out, int out_size, void* d_ws, size_t ws_size,
                              hipStream_t stream) {
    const float* x      = (const float*)d_in[0];
    const int*   ei     = (const int*)d_in[1];
    const float* W1     = (const float*)d_in[2];
    const float* a_src1 = (const float*)d_in[3];
    const float* a_dst1 = (const float*)d_in[4];
    const float* b1     = (const float*)d_in[5];
    const float* W2     = (const float*)d_in[6];
    const float* a_src2 = (const float*)d_in[7];
    const float* a_dst2 = (const float*)d_in[8];
    const float* b2     = (const float*)d_in[9];
    float* out = (float*)d_out;

    char* ws = (char*)d_ws;
    size_t off = 0;
    auto alloc = [&](size_t bytes) { char* p = ws + off; off += (bytes + 255) & ~(size_t)255; return p; };
    _Float16* h1h = (_Float16*)alloc((size_t)NN * C1 * 2);
    _Float16* h2h = (_Float16*)alloc((size_t)NN * CLASSES * 2);
    unsigned short* hmidb = (unsigned short*)alloc((size_t)NN * C1 * 2);
    float* e_src1 = (float*)alloc((size_t)NN * HEADS * 4);
    float* e_dst1 = (float*)alloc((size_t)NN * HEADS * 4);
    float* e_src2 = (float*)alloc((size_t)NN * 4);
    float* e_dst2 = (float*)alloc((size_t)NN * 4);
    int*   deg    = (int*)alloc((size_t)NN * 4);
    int*   rowptr = (int*)alloc((size_t)NN * 4);
    int*   cursor = (int*)alloc((size_t)NN * 4);
    unsigned short* csr  = (unsigned short*)alloc((size_t)ET * 2);
    int*   bsum   = (int*)alloc(256 * 4);
    unsigned short* va1h = (unsigned short*)alloc(16 * 128 * 2);
    unsigned short* va1l = (unsigned short*)alloc(16 * 128 * 2);
    unsigned short* va2b = (unsigned short*)alloc(4 * 128 * 2);
    unsigned short* W1b  = (unsigned short*)alloc(2048 * 8 * 2);
    unsigned short* W2b  = (unsigned short*)alloc(768 * 8 * 2);

    prep_kernel<<<3 + NCHUNKS, 256, 0, stream>>>(W1, a_src1, a_dst1, W2, a_src2, a_dst2,
                                                 va1h, va1l, va2b, W1b, W2b, deg);
    gemm1_count_kernel<<<GB1 + CB1, 256, 0, stream>>>(x, W1b, va1h, va1l, ei,
                                                      h1h, e_src1, e_dst1, deg);
    scan1_kernel<<<NCHUNKS, 256, 0, stream>>>(deg, rowptr, bsum);
    scan3_kernel<<<(NN + 255) / 256, 256, 0, stream>>>(rowptr, bsum, cursor, csr, deg);
    fill_kernel<<<(EE / 4 + 255) / 256, 256, 0, stream>>>(ei, cursor, csr);

    agg1_kernel<<<NN / 4, 256, 0, stream>>>(h1h, e_src1, e_dst1, rowptr, deg, csr, b1, hmidb);

    gemm2_kernel<<<(NN + 63) / 64, 256, 0, stream>>>(hmidb, W2b, va2b, h2h, e_src2, e_dst2);
    agg2_kernel<<<NN / 4, 256, 0, stream>>>(h2h, e_src2, e_dst2, rowptr, deg, csr, b2, out);
}

// Round 6
// 258.808 us; speedup vs baseline: 1.1425x; 1.0319x over previous
//
#include <hip/hip_runtime.h>
#include <math.h>

#define NN 50000
#define EE 800000
#define ET (EE + NN)      // edges + self loops
#define F_IN 128
#define HEADS 8
#define HID 16
#define C1 (HEADS * HID)  // 128
#define CLASSES 40
#define NEG_SLOPE 0.2f
#define LOG2E 1.4426950408889634f

#define GB1 ((NN + 31) / 32)        // 1563 gemm1 blocks
#define CB1 ((EE / 4 + 255) / 256)  // 782 count blocks
#define NCHUNKS ((NN + 1023) / 1024)  // 49

typedef __attribute__((ext_vector_type(8))) short bf16x8;
typedef __attribute__((ext_vector_type(4))) float f32x4;
typedef __attribute__((ext_vector_type(8))) _Float16 h16x8;
typedef __attribute__((ext_vector_type(2))) _Float16 h16x2;

__device__ __forceinline__ unsigned cvtpk(float a, float b) {
    unsigned r;
    asm("v_cvt_pk_bf16_f32 %0, %1, %2" : "=v"(r) : "v"(a), "v"(b));
    return r;
}
__device__ __forceinline__ float fexp2(float x) {
    float r;
    asm("v_exp_f32 %0, %1\n\ts_nop 0" : "=v"(r) : "v"(x));
    return r;
}
__device__ __forceinline__ float bflo(unsigned u) { return __uint_as_float(u << 16); }
__device__ __forceinline__ float bfhi(unsigned u) { return __uint_as_float(u & 0xffff0000u); }
__device__ __forceinline__ float lrelu(float a) { return fmaxf(a, NEG_SLOPE * a); }
__device__ __forceinline__ unsigned short bf1(float a) { return (unsigned short)cvtpk(a, a); }
__device__ __forceinline__ float bf1f(float a) { return bflo(cvtpk(a, a)); }
__device__ __forceinline__ bf16x8 pack8(float f0, float f1, float f2, float f3,
                                        float f4, float f5, float f6, float f7) {
    union { unsigned u[4]; bf16x8 v; } U;
    U.u[0] = cvtpk(f0, f1);
    U.u[1] = cvtpk(f2, f3);
    U.u[2] = cvtpk(f4, f5);
    U.u[3] = cvtpk(f6, f7);
    return U.v;
}

// ---------------- prep ----------------
// block 0: va1 (16x128 hi/lo bf16, frag layout) + va2 (4x128 bf16)
// block 1: W1b — W1 as bf16 MFMA fragments
// block 2: W2b — W2 fragments, cols >= CLASSES zeroed
// blocks 3+: zero deg
__global__ void prep_kernel(const float* __restrict__ W1,
                            const float* __restrict__ as1, const float* __restrict__ ad1,
                            const float* __restrict__ W2,
                            const float* __restrict__ as2, const float* __restrict__ ad2,
                            unsigned short* __restrict__ va1h, unsigned short* __restrict__ va1l,
                            unsigned short* __restrict__ va2b,
                            unsigned short* __restrict__ W1b, unsigned short* __restrict__ W2b,
                            int* __restrict__ deg) {
    const int tid = threadIdx.x;
    const int b = blockIdx.x;
    if (b >= 3) {  // deg zeroing (replaces hipMemsetAsync)
        int base = ((b - 3) * 256 + tid) * 4;
        if (base < NN) *(int4*)(deg + base) = make_int4(0, 0, 0, 0);
        return;
    }
    if (b == 1) {  // W1b fragments: 2048 frags, 8 per thread
        for (int f = tid; f < 2048; f += 256) {
            const int lane = f & 63, kc = (f >> 6) & 3, ntw = f >> 8;
            const int q = lane >> 4, c = lane & 15;
            const int col = (ntw >> 1) * 32 + (ntw & 1) * 16 + c;
            const int k0 = kc * 32 + q * 8;
            const float* wp = W1 + (size_t)k0 * C1 + col;
            *(bf16x8*)(W1b + (size_t)f * 8) =
                pack8(wp[0], wp[C1], wp[2 * C1], wp[3 * C1],
                      wp[4 * C1], wp[5 * C1], wp[6 * C1], wp[7 * C1]);
        }
        return;
    }
    if (b == 2) {  // W2b fragments: 768 frags
        for (int f = tid; f < 768; f += 256) {
            const int lane = f & 63, kc = (f >> 6) & 3, nt = f >> 8;
            const int q = lane >> 4, c = lane & 15;
            const int col = nt * 16 + c;
            const int k0 = kc * 32 + q * 8;
            bf16x8 v = 0;
            if (col < CLASSES) {
                const float* wp = W2 + (size_t)k0 * CLASSES + col;
                v = pack8(wp[0], wp[CLASSES], wp[2 * CLASSES], wp[3 * CLASSES],
                          wp[4 * CLASSES], wp[5 * CLASSES], wp[6 * CLASSES], wp[7 * CLASSES]);
            }
            *(bf16x8*)(W2b + (size_t)f * 8) = v;
        }
        return;
    }
    {   // va1: thread (k, half) computes 4 heads x {src,dst}
        const int k = tid >> 1, half = tid & 1;
        const float* wrow = W1 + (size_t)k * C1 + half * 64;
        #pragma unroll
        for (int hh = 0; hh < 4; ++hh) {
            const int h = half * 4 + hh;
            float s = 0.f, d = 0.f;
            #pragma unroll
            for (int t = 0; t < 16; ++t) {
                float wv = wrow[hh * 16 + t];
                s += wv * as1[h * HID + t];
                d += wv * ad1[h * HID + t];
            }
            s *= LOG2E; d *= LOG2E;
            va1h[h * 128 + k]       = bf1(s);
            va1l[h * 128 + k]       = bf1(s - bf1f(s));
            va1h[(h + 8) * 128 + k] = bf1(d);
            va1l[(h + 8) * 128 + k] = bf1(d - bf1f(d));
        }
    }
    if (tid < C1) {  // va2: thread k dots W2 row k with a2 vectors
        const float* wrow = W2 + (size_t)tid * CLASSES;
        float s = 0.f, d = 0.f;
        #pragma unroll
        for (int c2 = 0; c2 < CLASSES; ++c2) {
            float wv = wrow[c2];
            s += wv * as2[c2];
            d += wv * ad2[c2];
        }
        s *= LOG2E; d *= LOG2E;
        va2b[0 * 128 + tid] = bf1(s);
        va2b[1 * 128 + tid] = bf1(s - bf1f(s));
        va2b[2 * 128 + tid] = bf1(d);
        va2b[3 * 128 + tid] = bf1(d - bf1f(d));
    }
}

// ---------------- GEMM1 + MFMA elogit1 + interleaved count ----------------
// h1 stored as f16 (feeds only the agg gather path; f16 = 8x better mantissa than bf16)
__global__ __launch_bounds__(256, 4)
void gemm1_count_kernel(const float* __restrict__ x,
                        const unsigned short* __restrict__ W1b,
                        const unsigned short* __restrict__ va1h,
                        const unsigned short* __restrict__ va1l,
                        const int* __restrict__ ei,
                        _Float16* __restrict__ h1h,
                        float* __restrict__ e_src, float* __restrict__ e_dst,
                        int* __restrict__ deg) {
    const int bid = blockIdx.x;
    const int tid = threadIdx.x;
    // interleave: bid<2*CB1: odd = count, even = gemm; bid>=2*CB1: gemm
    int gemmb;
    if (bid < 2 * CB1) {
        if (bid & 1) {  // -------- count (overlapped with gemm throughout) --------
            int base = ((bid >> 1) * 256 + tid) * 4;
            if (base < EE) {
                int4 d4 = *(const int4*)(ei + EE + base);
                atomicAdd(&deg[d4.x], 1);
                atomicAdd(&deg[d4.y], 1);
                atomicAdd(&deg[d4.z], 1);
                atomicAdd(&deg[d4.w], 1);
            }
            return;
        }
        gemmb = bid >> 1;
    } else {
        gemmb = bid - CB1;
    }

    const int w = tid >> 6, lane = tid & 63;
    const int q = lane >> 4, c = lane & 15;

    // hoisted A-loads for both m-tiles (16 independent 16B loads -> MLP)
    bf16x8 afrag[2][4];
    #pragma unroll
    for (int mt = 0; mt < 2; ++mt) {
        const int m0 = (gemmb * 2 + mt) * 16;
        int row = m0 + c;
        if (row > NN - 1) row = NN - 1;
        #pragma unroll
        for (int kc = 0; kc < 4; ++kc) {
            const float* xp = x + (size_t)row * F_IN + kc * 32 + q * 8;
            float4 p0 = *(const float4*)xp;
            float4 p1 = *(const float4*)(xp + 4);
            afrag[mt][kc] = pack8(p0.x, p0.y, p0.z, p0.w, p1.x, p1.y, p1.z, p1.w);
        }
    }

    // B fragments: preconverted, fully-coalesced 16B loads (L2-hot 32KB)
    bf16x8 bfrag[2][4];
    #pragma unroll
    for (int nt = 0; nt < 2; ++nt)
        #pragma unroll
        for (int kc = 0; kc < 4; ++kc)
            bfrag[nt][kc] = *(const bf16x8*)(W1b + ((size_t)(((w * 2 + nt) * 4 + kc) * 64 + lane)) * 8);
    // e-operand fragments from prep (L2-hot 8KB)
    bf16x8 beh[4], bel[4];
    #pragma unroll
    for (int kc = 0; kc < 4; ++kc) {
        const int coloff = kc * 32 + q * 8;
        beh[kc] = *(const bf16x8*)(va1h + c * 128 + coloff);
        bel[kc] = *(const bf16x8*)(va1l + c * 128 + coloff);
    }

    #pragma unroll
    for (int mt = 0; mt < 2; ++mt) {
        const int m0 = (gemmb * 2 + mt) * 16;
        f32x4 acc0 = {0.f, 0.f, 0.f, 0.f};
        f32x4 acc1 = {0.f, 0.f, 0.f, 0.f};
        #pragma unroll
        for (int kc = 0; kc < 4; ++kc) {
            acc0 = __builtin_amdgcn_mfma_f32_16x16x32_bf16(afrag[mt][kc], bfrag[0][kc], acc0, 0, 0, 0);
            acc1 = __builtin_amdgcn_mfma_f32_16x16x32_bf16(afrag[mt][kc], bfrag[1][kc], acc1, 0, 0, 0);
        }
        // e-MFMA: wave `mt` computes e_src/e_dst for this m-tile
        if (w == mt) {
            f32x4 acce = {0.f, 0.f, 0.f, 0.f};
            #pragma unroll
            for (int kc = 0; kc < 4; ++kc) {
                acce = __builtin_amdgcn_mfma_f32_16x16x32_bf16(afrag[mt][kc], beh[kc], acce, 0, 0, 0);
                acce = __builtin_amdgcn_mfma_f32_16x16x32_bf16(afrag[mt][kc], bel[kc], acce, 0, 0, 0);
            }
            float* ep = (c < 8) ? e_src : e_dst;
            const int cc = c & 7;
            #pragma unroll
            for (int r = 0; r < 4; ++r) {
                const int ro = m0 + q * 4 + r;
                if (ro < NN) ep[(size_t)ro * HEADS + cc] = acce[r];
            }
        }
        #pragma unroll
        for (int r = 0; r < 4; ++r) {
            const int ro = m0 + q * 4 + r;
            if (ro < NN) {
                h1h[(size_t)ro * C1 + w * 32 + c]      = (_Float16)acc0[r];
                h1h[(size_t)ro * C1 + w * 32 + 16 + c] = (_Float16)acc1[r];
            }
        }
    }
}

// ---------------- CSR scan ----------------
// exclusive scan over (deg[i] + 1)  [+1 = self-loop]
__global__ void scan1_kernel(const int* __restrict__ deg, int* __restrict__ rowptr,
                             int* __restrict__ bsum) {
    __shared__ int sh[256];
    const int tid = threadIdx.x;
    const int base = blockIdx.x * 1024 + tid * 4;
    int v[4], s[4];
    #pragma unroll
    for (int j = 0; j < 4; ++j) v[j] = (base + j < NN) ? (deg[base + j] + 1) : 0;
    s[0] = v[0]; s[1] = s[0] + v[1]; s[2] = s[1] + v[2]; s[3] = s[2] + v[3];
    int T = s[3];
    sh[tid] = T;
    __syncthreads();
    for (int off = 1; off < 256; off <<= 1) {
        int xv = (tid >= off) ? sh[tid - off] : 0;
        __syncthreads();
        sh[tid] += xv;
        __syncthreads();
    }
    int excl = sh[tid] - T;
    #pragma unroll
    for (int j = 0; j < 4; ++j)
        if (base + j < NN) rowptr[base + j] = excl + s[j] - v[j];
    if (tid == 255) bsum[blockIdx.x] = sh[255];
}

// finalize rowptr (scan2 fused); self-loop at slot rowptr[i]; cursor past it; deg -> total cnt
__global__ void scan3_kernel(int* __restrict__ rowptr, const int* __restrict__ bsum,
                             int* __restrict__ cursor, unsigned short* __restrict__ csr,
                             int* __restrict__ deg) {
    __shared__ int ex[64];
    const int tid = threadIdx.x;
    if (tid < 64) {
        int v = (tid < NCHUNKS) ? bsum[tid] : 0;
        int s = v;
        #pragma unroll
        for (int off = 1; off < 64; off <<= 1) {
            int xv = __shfl_up(s, off);
            if (tid >= off) s += xv;
        }
        ex[tid] = s - v;  // exclusive prefix
    }
    __syncthreads();
    int i = blockIdx.x * blockDim.x + tid;
    if (i >= NN) return;
    int rp = rowptr[i] + ex[i >> 10];
    rowptr[i] = rp;
    cursor[i] = rp + 1;
    csr[rp] = (unsigned short)i;  // self-loop first
    deg[i] += 1;                  // total incoming count incl. self-loop
}

// scatter real edges: 4 per thread, int4 loads, ushort payloads (L2-merged stores)
__global__ void fill_kernel(const int* __restrict__ ei, int* __restrict__ cursor,
                            unsigned short* __restrict__ csr) {
    int base = (blockIdx.x * blockDim.x + threadIdx.x) * 4;
    if (base >= EE) return;
    int4 s4 = *(const int4*)(ei + base);
    int4 d4 = *(const int4*)(ei + EE + base);
    int p0 = atomicAdd(&cursor[d4.x], 1);
    int p1 = atomicAdd(&cursor[d4.y], 1);
    int p2 = atomicAdd(&cursor[d4.z], 1);
    int p3 = atomicAdd(&cursor[d4.w], 1);
    csr[p0] = (unsigned short)s4.x;
    csr[p1] = (unsigned short)s4.y;
    csr[p2] = (unsigned short)s4.z;
    csr[p3] = (unsigned short)s4.w;
}

// ---------------- layer-1 aggregation: dst-per-group ----------------
// block = 256 = 4 waves = 16 groups of 16 lanes; each group owns one dst node.
// Lane l owns channels 8l..8l+7; head = l>>1. Group processes its dst's edges
// 4 at a time (contiguous). No cross-lane reduction needed: each lane's
// denom/acc are complete for its head. Epilogue retires 4 dst per wave.
__global__ void agg1_kernel(const _Float16* __restrict__ h1h,
                            const float* __restrict__ e_src, const float* __restrict__ e_dst,
                            const int* __restrict__ rowptr, const int* __restrict__ deg,
                            const unsigned short* __restrict__ csr,
                            const float* __restrict__ b1, unsigned short* __restrict__ hmid) {
    const int tid = threadIdx.x;
    const int lane = tid & 63;
    const int l = lane & 15;           // channel-lane: channels 8l..8l+7
    const int d = blockIdx.x * 16 + (tid >> 4);  // group index = dst (grid*16 == NN exactly)
    const int hd = l >> 1;
    const float ed = e_dst[(size_t)d * HEADS + hd];  // pre-scaled by log2e
    const int start = rowptr[d];
    const int cnt = deg[d];

    float denom = 0.f;
    float acc[8] = {0.f, 0.f, 0.f, 0.f, 0.f, 0.f, 0.f, 0.f};

    for (int i = 0; i < cnt; i += 4) {
        const bool v1 = i + 1 < cnt, v2 = i + 2 < cnt, v3 = i + 3 < cnt;
        int s0 = csr[start + i];
        int s1 = csr[start + (v1 ? i + 1 : i)];
        int s2 = csr[start + (v2 ? i + 2 : i)];
        int s3 = csr[start + (v3 ? i + 3 : i)];
        float es0 = e_src[(size_t)s0 * HEADS + hd];
        float es1 = e_src[(size_t)s1 * HEADS + hd];
        float es2 = e_src[(size_t)s2 * HEADS + hd];
        float es3 = e_src[(size_t)s3 * HEADS + hd];
        h16x8 g0 = *(const h16x8*)(h1h + (size_t)s0 * C1 + 8 * l);
        h16x8 g1 = *(const h16x8*)(h1h + (size_t)s1 * C1 + 8 * l);
        h16x8 g2 = *(const h16x8*)(h1h + (size_t)s2 * C1 + 8 * l);
        h16x8 g3 = *(const h16x8*)(h1h + (size_t)s3 * C1 + 8 * l);
        float w0 = fexp2(lrelu(es0 + ed));
        float w1 = v1 ? fexp2(lrelu(es1 + ed)) : 0.f;
        float w2 = v2 ? fexp2(lrelu(es2 + ed)) : 0.f;
        float w3 = v3 ? fexp2(lrelu(es3 + ed)) : 0.f;
        denom += (w0 + w1) + (w2 + w3);
        #pragma unroll
        for (int j = 0; j < 8; ++j) {
            // (float)f16 * f32 + f32 -> v_fma_mix_f32 (no unpack insts)
            acc[j] = fmaf((float)g0[j], w0, acc[j]);
            acc[j] = fmaf((float)g1[j], w1, acc[j]);
            acc[j] = fmaf((float)g2[j], w2, acc[j]);
            acc[j] = fmaf((float)g3[j], w3, acc[j]);
        }
    }
    // no cross-lane combine: denom/acc complete per lane.
    const float inv = 1.f / (denom + 1e-16f);
    float o[8];
    #pragma unroll
    for (int k = 0; k < 8; ++k) {
        float t = acc[k] * inv + b1[8 * l + k];
        // elu via exp2 (output is rounded to bf16 right after; expm1 precision is overkill)
        o[k] = (t > 0.f) ? t : fexp2(t * LOG2E) - 1.f;
    }
    uint4 st;
    st.x = cvtpk(o[0], o[1]);
    st.y = cvtpk(o[2], o[3]);
    st.z = cvtpk(o[4], o[5]);
    st.w = cvtpk(o[6], o[7]);
    *(uint4*)(hmid + (size_t)d * C1 + 8 * l) = st;  // bf16 row, 16B/lane
}

// ---------------- GEMM2 (bf16 A direct, preconverted W2b) + MFMA elogit2 ----------------
__global__ __launch_bounds__(256, 4)
void gemm2_kernel(const unsigned short* __restrict__ hmid,
                  const unsigned short* __restrict__ W2b,
                  const unsigned short* __restrict__ va2b,
                  _Float16* __restrict__ h2h,
                  float* __restrict__ e_src, float* __restrict__ e_dst) {
    const int tid = threadIdx.x;
    const int w = tid >> 6, lane = tid & 63;
    const int q = lane >> 4, c = lane & 15;

    const int m0 = (blockIdx.x * 4 + w) * 16;
    if (m0 >= NN) return;
    int row = m0 + c;
    if (row > NN - 1) row = NN - 1;
    bf16x8 afrag[4];
    #pragma unroll
    for (int kc = 0; kc < 4; ++kc)
        afrag[kc] = *(const bf16x8*)(hmid + (size_t)row * C1 + kc * 32 + q * 8);  // no converts

    bf16x8 bfrag[3][4];
    #pragma unroll
    for (int nt = 0; nt < 3; ++nt)
        #pragma unroll
        for (int kc = 0; kc < 4; ++kc)
            bfrag[nt][kc] = *(const bf16x8*)(W2b + (size_t)((nt * 4 + kc) * 64 + lane) * 8);
    // e-tile cols: 0=src_hi, 1=src_lo, 2=dst_hi, 3=dst_lo (from prep, 1KB L2-hot)
    bf16x8 bfe[4];
    #pragma unroll
    for (int kc = 0; kc < 4; ++kc) {
        bf16x8 bb = 0;
        if (c < 4) bb = *(const bf16x8*)(va2b + c * 128 + kc * 32 + q * 8);
        bfe[kc] = bb;
    }

    f32x4 acc[3] = {{0.f,0.f,0.f,0.f},{0.f,0.f,0.f,0.f},{0.f,0.f,0.f,0.f}};
    f32x4 acce = {0.f, 0.f, 0.f, 0.f};
    #pragma unroll
    for (int kc = 0; kc < 4; ++kc) {
        acc[0] = __builtin_amdgcn_mfma_f32_16x16x32_bf16(afrag[kc], bfrag[0][kc], acc[0], 0, 0, 0);
        acc[1] = __builtin_amdgcn_mfma_f32_16x16x32_bf16(afrag[kc], bfrag[1][kc], acc[1], 0, 0, 0);
        acc[2] = __builtin_amdgcn_mfma_f32_16x16x32_bf16(afrag[kc], bfrag[2][kc], acc[2], 0, 0, 0);
        acce   = __builtin_amdgcn_mfma_f32_16x16x32_bf16(afrag[kc], bfe[kc],      acce,   0, 0, 0);
    }
    #pragma unroll
    for (int r = 0; r < 4; ++r) {
        const int ro = m0 + q * 4 + r;
        // combine hi+lo columns: cols (0,1) -> e_src, cols (2,3) -> e_dst
        float v = acce[r] + __shfl_xor(acce[r], 1);
        if (ro < NN) {
            #pragma unroll
            for (int nt = 0; nt < 3; ++nt) {
                const int col = nt * 16 + c;
                if (col < CLASSES)
                    h2h[(size_t)ro * CLASSES + col] = (_Float16)acc[nt][r];
            }
            if (c == 0) e_src[ro] = v;
            if (c == 2) e_dst[ro] = v;
        }
    }
}

// ---------------- layer-2 aggregation: dst-per-group -> output ----------------
// block = 256 = 4 waves; wave = 3 groups of 20 lanes (lanes 60..63 idle).
// Each group owns one dst; lane c owns channels 2c,2c+1. No cross-lane combine.
__global__ void agg2_kernel(const _Float16* __restrict__ h2h,
                            const float* __restrict__ e_src, const float* __restrict__ e_dst,
                            const int* __restrict__ rowptr, const int* __restrict__ deg,
                            const unsigned short* __restrict__ csr,
                            const float* __restrict__ b2, float* __restrict__ out) {
    const int tid = threadIdx.x;
    const int wv = tid >> 6, lane = tid & 63;
    const int eg = lane / 20;      // 0..2 active groups, 3 = idle lanes 60..63
    const int c  = lane % 20;
    const int d = blockIdx.x * 12 + wv * 3 + eg;
    const bool live = (eg < 3) && (d < NN);
    const int dcl = live ? d : 0;
    const float ed = e_dst[dcl];   // pre-scaled by log2e
    const int start = rowptr[dcl];
    const int cnt = live ? deg[dcl] : 0;

    float denom = 0.f, acc0 = 0.f, acc1 = 0.f;
    for (int i = 0; i < cnt; i += 4) {
        const bool v1 = i + 1 < cnt, v2 = i + 2 < cnt, v3 = i + 3 < cnt;
        int s0 = csr[start + i];
        int s1 = csr[start + (v1 ? i + 1 : i)];
        int s2 = csr[start + (v2 ? i + 2 : i)];
        int s3 = csr[start + (v3 ? i + 3 : i)];
        float es0 = e_src[s0], es1 = e_src[s1], es2 = e_src[s2], es3 = e_src[s3];
        h16x2 g0 = *(const h16x2*)(h2h + (size_t)s0 * CLASSES + 2 * c);
        h16x2 g1 = *(const h16x2*)(h2h + (size_t)s1 * CLASSES + 2 * c);
        h16x2 g2 = *(const h16x2*)(h2h + (size_t)s2 * CLASSES + 2 * c);
        h16x2 g3 = *(const h16x2*)(h2h + (size_t)s3 * CLASSES + 2 * c);
        float w0 = fexp2(lrelu(es0 + ed));
        float w1 = v1 ? fexp2(lrelu(es1 + ed)) : 0.f;
        float w2 = v2 ? fexp2(lrelu(es2 + ed)) : 0.f;
        float w3 = v3 ? fexp2(lrelu(es3 + ed)) : 0.f;
        denom += (w0 + w1) + (w2 + w3);
        acc0 = fmaf((float)g0[0], w0, acc0); acc1 = fmaf((float)g0[1], w0, acc1);
        acc0 = fmaf((float)g1[0], w1, acc0); acc1 = fmaf((float)g1[1], w1, acc1);
        acc0 = fmaf((float)g2[0], w2, acc0); acc1 = fmaf((float)g2[1], w2, acc1);
        acc0 = fmaf((float)g3[0], w3, acc0); acc1 = fmaf((float)g3[1], w3, acc1);
    }
    if (live) {
        const float inv = 1.f / (denom + 1e-16f);
        float2 o;
        o.x = acc0 * inv + b2[2 * c];
        o.y = acc1 * inv + b2[2 * c + 1];
        *(float2*)(out + (size_t)d * CLASSES + 2 * c) = o;
    }
}

extern "C" void kernel_launch(void* const* d_in, const int* in_sizes, int n_in,
                              void* d_out, int out_size, void* d_ws, size_t ws_size,
                              hipStream_t stream) {
    const float* x      = (const float*)d_in[0];
    const int*   ei     = (const int*)d_in[1];
    const float* W1     = (const float*)d_in[2];
    const float* a_src1 = (const float*)d_in[3];
    const float* a_dst1 = (const float*)d_in[4];
    const float* b1     = (const float*)d_in[5];
    const float* W2     = (const float*)d_in[6];
    const float* a_src2 = (const float*)d_in[7];
    const float* a_dst2 = (const float*)d_in[8];
    const float* b2     = (const float*)d_in[9];
    float* out = (float*)d_out;

    char* ws = (char*)d_ws;
    size_t off = 0;
    auto alloc = [&](size_t bytes) { char* p = ws + off; off += (bytes + 255) & ~(size_t)255; return p; };
    _Float16* h1h = (_Float16*)alloc((size_t)NN * C1 * 2);
    _Float16* h2h = (_Float16*)alloc((size_t)NN * CLASSES * 2);
    unsigned short* hmidb = (unsigned short*)alloc((size_t)NN * C1 * 2);
    float* e_src1 = (float*)alloc((size_t)NN * HEADS * 4);
    float* e_dst1 = (float*)alloc((size_t)NN * HEADS * 4);
    float* e_src2 = (float*)alloc((size_t)NN * 4);
    float* e_dst2 = (float*)alloc((size_t)NN * 4);
    int*   deg    = (int*)alloc((size_t)NN * 4);
    int*   rowptr = (int*)alloc((size_t)NN * 4);
    int*   cursor = (int*)alloc((size_t)NN * 4);
    unsigned short* csr  = (unsigned short*)alloc((size_t)ET * 2);
    int*   bsum   = (int*)alloc(256 * 4);
    unsigned short* va1h = (unsigned short*)alloc(16 * 128 * 2);
    unsigned short* va1l = (unsigned short*)alloc(16 * 128 * 2);
    unsigned short* va2b = (unsigned short*)alloc(4 * 128 * 2);
    unsigned short* W1b  = (unsigned short*)alloc(2048 * 8 * 2);
    unsigned short* W2b  = (unsigned short*)alloc(768 * 8 * 2);

    prep_kernel<<<3 + NCHUNKS, 256, 0, stream>>>(W1, a_src1, a_dst1, W2, a_src2, a_dst2,
                                                 va1h, va1l, va2b, W1b, W2b, deg);
    gemm1_count_kernel<<<GB1 + CB1, 256, 0, stream>>>(x, W1b, va1h, va1l, ei,
                                                      h1h, e_src1, e_dst1, deg);
    scan1_kernel<<<NCHUNKS, 256, 0, stream>>>(deg, rowptr, bsum);
    scan3_kernel<<<(NN + 255) / 256, 256, 0, stream>>>(rowptr, bsum, cursor, csr, deg);
    fill_kernel<<<(EE / 4 + 255) / 256, 256, 0, stream>>>(ei, cursor, csr);

    agg1_kernel<<<NN / 16, 256, 0, stream>>>(h1h, e_src1, e_dst1, rowptr, deg, csr, b1, hmidb);

    gemm2_kernel<<<(NN + 63) / 64, 256, 0, stream>>>(hmidb, W2b, va2b, h2h, e_src2, e_dst2);
    agg2_kernel<<<(NN + 11) / 12, 256, 0, stream>>>(h2h, e_src2, e_dst2, rowptr, deg, csr, b2, out);
}

// Round 7
// 241.287 us; speedup vs baseline: 1.2254x; 1.0726x over previous
//
#include <hip/hip_runtime.h>
#include <math.h>

#define NN 50000
#define EE 800000
#define ET (EE + NN)      // edges + self loops
#define F_IN 128
#define HEADS 8
#define HID 16
#define C1 (HEADS * HID)  // 128
#define CLASSES 40
#define NEG_SLOPE 0.2f
#define LOG2E 1.4426950408889634f

#define NCHUNKS ((NN + 1023) / 1024)  // 49
#define NHIST 64                      // histogram blocks
#define EPB (EE / NHIST)              // 12500 edges per hist block
#define LHN 25088                     // padded u32 histogram words (>= 50176 u16 >= NCHUNKS*1024)

typedef __attribute__((ext_vector_type(8))) short bf16x8;
typedef __attribute__((ext_vector_type(4))) float f32x4;
typedef __attribute__((ext_vector_type(8))) _Float16 h16x8;
typedef __attribute__((ext_vector_type(2))) _Float16 h16x2;

__device__ __forceinline__ unsigned cvtpk(float a, float b) {
    unsigned r;
    asm("v_cvt_pk_bf16_f32 %0, %1, %2" : "=v"(r) : "v"(a), "v"(b));
    return r;
}
__device__ __forceinline__ float fexp2(float x) {
    float r;
    asm("v_exp_f32 %0, %1\n\ts_nop 0" : "=v"(r) : "v"(x));
    return r;
}
__device__ __forceinline__ float bflo(unsigned u) { return __uint_as_float(u << 16); }
__device__ __forceinline__ float bfhi(unsigned u) { return __uint_as_float(u & 0xffff0000u); }
__device__ __forceinline__ float lrelu(float a) { return fmaxf(a, NEG_SLOPE * a); }
__device__ __forceinline__ unsigned short bf1(float a) { return (unsigned short)cvtpk(a, a); }
__device__ __forceinline__ float bf1f(float a) { return bflo(cvtpk(a, a)); }
__device__ __forceinline__ bf16x8 pack8(float f0, float f1, float f2, float f3,
                                        float f4, float f5, float f6, float f7) {
    union { unsigned u[4]; bf16x8 v; } U;
    U.u[0] = cvtpk(f0, f1);
    U.u[1] = cvtpk(f2, f3);
    U.u[2] = cvtpk(f4, f5);
    U.u[3] = cvtpk(f6, f7);
    return U.v;
}

// ---------------- prep ----------------
// block 0: va1 (16x128 hi/lo bf16, frag layout) + va2 (4x128 bf16)
// block 1: W1b — W1 as bf16 MFMA fragments
// block 2: W2b — W2 fragments, cols >= CLASSES zeroed
// blocks 3..3+NHIST: LDS-histogram degree count (u16-packed; NO global atomics)
__global__ void prep_kernel(const float* __restrict__ W1,
                            const float* __restrict__ as1, const float* __restrict__ ad1,
                            const float* __restrict__ W2,
                            const float* __restrict__ as2, const float* __restrict__ ad2,
                            const int* __restrict__ ei,
                            unsigned short* __restrict__ va1h, unsigned short* __restrict__ va1l,
                            unsigned short* __restrict__ va2b,
                            unsigned short* __restrict__ W1b, unsigned short* __restrict__ W2b,
                            unsigned* __restrict__ partial) {
    const int tid = threadIdx.x;
    const int b = blockIdx.x;
    if (b >= 3) {  // -------- histogram count, pure LDS atomics --------
        __shared__ unsigned lhist[LHN];
        for (int i = tid; i < LHN; i += 256) lhist[i] = 0;
        __syncthreads();
        const int hb = b - 3;
        const int* dp = ei + EE + hb * EPB;
        for (int e0 = tid * 4; e0 < EPB; e0 += 1024) {
            int4 d4 = *(const int4*)(dp + e0);
            atomicAdd(&lhist[(unsigned)d4.x >> 1], 1u << ((d4.x & 1) << 4));
            atomicAdd(&lhist[(unsigned)d4.y >> 1], 1u << ((d4.y & 1) << 4));
            atomicAdd(&lhist[(unsigned)d4.z >> 1], 1u << ((d4.z & 1) << 4));
            atomicAdd(&lhist[(unsigned)d4.w >> 1], 1u << ((d4.w & 1) << 4));
        }
        __syncthreads();
        unsigned* pb = partial + (size_t)hb * LHN;
        for (int i = tid; i < LHN; i += 256) pb[i] = lhist[i];
        return;
    }
    if (b == 1) {  // W1b fragments: 2048 frags, 8 per thread
        for (int f = tid; f < 2048; f += 256) {
            const int lane = f & 63, kc = (f >> 6) & 3, ntw = f >> 8;
            const int q = lane >> 4, c = lane & 15;
            const int col = ntw * 16 + c;
            const int k0 = kc * 32 + q * 8;
            const float* wp = W1 + (size_t)k0 * C1 + col;
            *(bf16x8*)(W1b + (size_t)f * 8) =
                pack8(wp[0], wp[C1], wp[2 * C1], wp[3 * C1],
                      wp[4 * C1], wp[5 * C1], wp[6 * C1], wp[7 * C1]);
        }
        return;
    }
    if (b == 2) {  // W2b fragments: 768 frags
        for (int f = tid; f < 768; f += 256) {
            const int lane = f & 63, kc = (f >> 6) & 3, nt = f >> 8;
            const int q = lane >> 4, c = lane & 15;
            const int col = nt * 16 + c;
            const int k0 = kc * 32 + q * 8;
            bf16x8 v = 0;
            if (col < CLASSES) {
                const float* wp = W2 + (size_t)k0 * CLASSES + col;
                v = pack8(wp[0], wp[CLASSES], wp[2 * CLASSES], wp[3 * CLASSES],
                          wp[4 * CLASSES], wp[5 * CLASSES], wp[6 * CLASSES], wp[7 * CLASSES]);
            }
            *(bf16x8*)(W2b + (size_t)f * 8) = v;
        }
        return;
    }
    {   // va1: thread (k, half) computes 4 heads x {src,dst}
        const int k = tid >> 1, half = tid & 1;
        const float* wrow = W1 + (size_t)k * C1 + half * 64;
        #pragma unroll
        for (int hh = 0; hh < 4; ++hh) {
            const int h = half * 4 + hh;
            float s = 0.f, d = 0.f;
            #pragma unroll
            for (int t = 0; t < 16; ++t) {
                float wv = wrow[hh * 16 + t];
                s += wv * as1[h * HID + t];
                d += wv * ad1[h * HID + t];
            }
            s *= LOG2E; d *= LOG2E;
            va1h[h * 128 + k]       = bf1(s);
            va1l[h * 128 + k]       = bf1(s - bf1f(s));
            va1h[(h + 8) * 128 + k] = bf1(d);
            va1l[(h + 8) * 128 + k] = bf1(d - bf1f(d));
        }
    }
    if (tid < C1) {  // va2: thread k dots W2 row k with a2 vectors
        const float* wrow = W2 + (size_t)tid * CLASSES;
        float s = 0.f, d = 0.f;
        #pragma unroll
        for (int c2 = 0; c2 < CLASSES; ++c2) {
            float wv = wrow[c2];
            s += wv * as2[c2];
            d += wv * ad2[c2];
        }
        s *= LOG2E; d *= LOG2E;
        va2b[0 * 128 + tid] = bf1(s);
        va2b[1 * 128 + tid] = bf1(s - bf1f(s));
        va2b[2 * 128 + tid] = bf1(d);
        va2b[3 * 128 + tid] = bf1(d - bf1f(d));
    }
}

// ---------------- GEMM1 (pure, wave-per-mtile) + MFMA elogit1 ----------------
// Each wave owns 16 rows x all 128 cols: no redundant A-loads. h1 stored f16.
__global__ __launch_bounds__(256, 4)
void gemm1_kernel(const float* __restrict__ x,
                  const unsigned short* __restrict__ W1b,
                  const unsigned short* __restrict__ va1h,
                  const unsigned short* __restrict__ va1l,
                  _Float16* __restrict__ h1h,
                  float* __restrict__ e_src, float* __restrict__ e_dst) {
    const int tid = threadIdx.x;
    const int w = tid >> 6, lane = tid & 63;
    const int q = lane >> 4, c = lane & 15;
    const int m0 = (blockIdx.x * 4 + w) * 16;

    int row = m0 + c;
    if (row > NN - 1) row = NN - 1;
    bf16x8 afrag[4];
    #pragma unroll
    for (int kc = 0; kc < 4; ++kc) {
        const float* xp = x + (size_t)row * F_IN + kc * 32 + q * 8;
        float4 p0 = *(const float4*)xp;
        float4 p1 = *(const float4*)(xp + 4);
        afrag[kc] = pack8(p0.x, p0.y, p0.z, p0.w, p1.x, p1.y, p1.z, p1.w);
    }

    // e-operand fragments from prep (L2-hot 8KB) and e-MFMA
    {
        f32x4 acce = {0.f, 0.f, 0.f, 0.f};
        #pragma unroll
        for (int kc = 0; kc < 4; ++kc) {
            const int coloff = kc * 32 + q * 8;
            bf16x8 beh = *(const bf16x8*)(va1h + c * 128 + coloff);
            bf16x8 bel = *(const bf16x8*)(va1l + c * 128 + coloff);
            acce = __builtin_amdgcn_mfma_f32_16x16x32_bf16(afrag[kc], beh, acce, 0, 0, 0);
            acce = __builtin_amdgcn_mfma_f32_16x16x32_bf16(afrag[kc], bel, acce, 0, 0, 0);
        }
        float* ep = (c < 8) ? e_src : e_dst;
        const int cc = c & 7;
        #pragma unroll
        for (int r = 0; r < 4; ++r) {
            const int ro = m0 + q * 4 + r;
            if (ro < NN) ep[(size_t)ro * HEADS + cc] = acce[r];
        }
    }

    // main GEMM: 8 n-tiles, B frags from preconverted L2-hot W1b
    #pragma unroll 2
    for (int nt = 0; nt < 8; ++nt) {
        bf16x8 bf0 = *(const bf16x8*)(W1b + (size_t)((nt * 4 + 0) * 64 + lane) * 8);
        bf16x8 bf1_ = *(const bf16x8*)(W1b + (size_t)((nt * 4 + 1) * 64 + lane) * 8);
        bf16x8 bf2 = *(const bf16x8*)(W1b + (size_t)((nt * 4 + 2) * 64 + lane) * 8);
        bf16x8 bf3 = *(const bf16x8*)(W1b + (size_t)((nt * 4 + 3) * 64 + lane) * 8);
        f32x4 a = {0.f, 0.f, 0.f, 0.f};
        a = __builtin_amdgcn_mfma_f32_16x16x32_bf16(afrag[0], bf0, a, 0, 0, 0);
        a = __builtin_amdgcn_mfma_f32_16x16x32_bf16(afrag[1], bf1_, a, 0, 0, 0);
        a = __builtin_amdgcn_mfma_f32_16x16x32_bf16(afrag[2], bf2, a, 0, 0, 0);
        a = __builtin_amdgcn_mfma_f32_16x16x32_bf16(afrag[3], bf3, a, 0, 0, 0);
        #pragma unroll
        for (int r = 0; r < 4; ++r) {
            const int ro = m0 + q * 4 + r;
            if (ro < NN) h1h[(size_t)ro * C1 + nt * 16 + c] = (_Float16)a[r];
        }
    }
}

// ---------------- CSR scan ----------------
// scan1: deg totals from histogram partials (coalesced), then exclusive scan over
// (deg_real[i] + 1)  [+1 = self-loop]. Writes deg[i] = total incl self-loop.
__global__ void scan1_kernel(const unsigned* __restrict__ partial, int* __restrict__ deg,
                             int* __restrict__ rowptr, int* __restrict__ bsum) {
    __shared__ int sh[256];
    const int tid = threadIdx.x;
    const int base = blockIdx.x * 1024 + tid * 4;
    const unsigned short* pu = (const unsigned short*)partial;
    int t0 = 0, t1 = 0, t2 = 0, t3 = 0;
    #pragma unroll 8
    for (int b = 0; b < NHIST; ++b) {
        ushort4 p = *(const ushort4*)(pu + (size_t)b * (LHN * 2) + base);
        t0 += p.x; t1 += p.y; t2 += p.z; t3 += p.w;
    }
    int v[4], s[4];
    v[0] = (base + 0 < NN) ? t0 + 1 : 0;
    v[1] = (base + 1 < NN) ? t1 + 1 : 0;
    v[2] = (base + 2 < NN) ? t2 + 1 : 0;
    v[3] = (base + 3 < NN) ? t3 + 1 : 0;
    #pragma unroll
    for (int j = 0; j < 4; ++j)
        if (base + j < NN) deg[base + j] = v[j];  // total incl self-loop
    s[0] = v[0]; s[1] = s[0] + v[1]; s[2] = s[1] + v[2]; s[3] = s[2] + v[3];
    int T = s[3];
    sh[tid] = T;
    __syncthreads();
    for (int off = 1; off < 256; off <<= 1) {
        int xv = (tid >= off) ? sh[tid - off] : 0;
        __syncthreads();
        sh[tid] += xv;
        __syncthreads();
    }
    int excl = sh[tid] - T;
    #pragma unroll
    for (int j = 0; j < 4; ++j)
        if (base + j < NN) rowptr[base + j] = excl + s[j] - v[j];
    if (tid == 255) bsum[blockIdx.x] = sh[255];
}

// finalize rowptr (scan2 fused); self-loop at slot rowptr[i]; cursor past it
__global__ void scan3_kernel(int* __restrict__ rowptr, const int* __restrict__ bsum,
                             int* __restrict__ cursor, unsigned short* __restrict__ csr) {
    __shared__ int ex[64];
    const int tid = threadIdx.x;
    if (tid < 64) {
        int v = (tid < NCHUNKS) ? bsum[tid] : 0;
        int s = v;
        #pragma unroll
        for (int off = 1; off < 64; off <<= 1) {
            int xv = __shfl_up(s, off);
            if (tid >= off) s += xv;
        }
        ex[tid] = s - v;  // exclusive prefix
    }
    __syncthreads();
    int i = blockIdx.x * blockDim.x + tid;
    if (i >= NN) return;
    int rp = rowptr[i] + ex[i >> 10];
    rowptr[i] = rp;
    cursor[i] = rp + 1;
    csr[rp] = (unsigned short)i;  // self-loop first
}

// scatter real edges: 4 per thread, int4 loads, ushort payloads (L2-merged stores)
__global__ void fill_kernel(const int* __restrict__ ei, int* __restrict__ cursor,
                            unsigned short* __restrict__ csr) {
    int base = (blockIdx.x * blockDim.x + threadIdx.x) * 4;
    if (base >= EE) return;
    int4 s4 = *(const int4*)(ei + base);
    int4 d4 = *(const int4*)(ei + EE + base);
    int p0 = atomicAdd(&cursor[d4.x], 1);
    int p1 = atomicAdd(&cursor[d4.y], 1);
    int p2 = atomicAdd(&cursor[d4.z], 1);
    int p3 = atomicAdd(&cursor[d4.w], 1);
    csr[p0] = (unsigned short)s4.x;
    csr[p1] = (unsigned short)s4.y;
    csr[p2] = (unsigned short)s4.z;
    csr[p3] = (unsigned short)s4.w;
}

// ---------------- layer-1 aggregation: dst-per-group ----------------
// block = 256 = 16 groups of 16 lanes; each group owns one dst node.
// Lane l owns channels 8l..8l+7; head = l>>1. No cross-lane reduction needed.
__global__ void agg1_kernel(const _Float16* __restrict__ h1h,
                            const float* __restrict__ e_src, const float* __restrict__ e_dst,
                            const int* __restrict__ rowptr, const int* __restrict__ deg,
                            const unsigned short* __restrict__ csr,
                            const float* __restrict__ b1, unsigned short* __restrict__ hmid) {
    const int tid = threadIdx.x;
    const int lane = tid & 63;
    const int l = lane & 15;           // channel-lane: channels 8l..8l+7
    const int d = blockIdx.x * 16 + (tid >> 4);  // group index = dst (grid*16 == NN exactly)
    const int hd = l >> 1;
    const float ed = e_dst[(size_t)d * HEADS + hd];  // pre-scaled by log2e
    const int start = rowptr[d];
    const int cnt = deg[d];

    float denom = 0.f;
    float acc[8] = {0.f, 0.f, 0.f, 0.f, 0.f, 0.f, 0.f, 0.f};

    for (int i = 0; i < cnt; i += 4) {
        const bool v1 = i + 1 < cnt, v2 = i + 2 < cnt, v3 = i + 3 < cnt;
        int s0 = csr[start + i];
        int s1 = csr[start + (v1 ? i + 1 : i)];
        int s2 = csr[start + (v2 ? i + 2 : i)];
        int s3 = csr[start + (v3 ? i + 3 : i)];
        float es0 = e_src[(size_t)s0 * HEADS + hd];
        float es1 = e_src[(size_t)s1 * HEADS + hd];
        float es2 = e_src[(size_t)s2 * HEADS + hd];
        float es3 = e_src[(size_t)s3 * HEADS + hd];
        h16x8 g0 = *(const h16x8*)(h1h + (size_t)s0 * C1 + 8 * l);
        h16x8 g1 = *(const h16x8*)(h1h + (size_t)s1 * C1 + 8 * l);
        h16x8 g2 = *(const h16x8*)(h1h + (size_t)s2 * C1 + 8 * l);
        h16x8 g3 = *(const h16x8*)(h1h + (size_t)s3 * C1 + 8 * l);
        float w0 = fexp2(lrelu(es0 + ed));
        float w1 = v1 ? fexp2(lrelu(es1 + ed)) : 0.f;
        float w2 = v2 ? fexp2(lrelu(es2 + ed)) : 0.f;
        float w3 = v3 ? fexp2(lrelu(es3 + ed)) : 0.f;
        denom += (w0 + w1) + (w2 + w3);
        #pragma unroll
        for (int j = 0; j < 8; ++j) {
            // (float)f16 * f32 + f32 -> v_fma_mix_f32 (no unpack insts)
            acc[j] = fmaf((float)g0[j], w0, acc[j]);
            acc[j] = fmaf((float)g1[j], w1, acc[j]);
            acc[j] = fmaf((float)g2[j], w2, acc[j]);
            acc[j] = fmaf((float)g3[j], w3, acc[j]);
        }
    }
    const float inv = 1.f / (denom + 1e-16f);
    float o[8];
    #pragma unroll
    for (int k = 0; k < 8; ++k) {
        float t = acc[k] * inv + b1[8 * l + k];
        // elu via exp2 (output is rounded to bf16 right after; expm1 precision is overkill)
        o[k] = (t > 0.f) ? t : fexp2(t * LOG2E) - 1.f;
    }
    uint4 st;
    st.x = cvtpk(o[0], o[1]);
    st.y = cvtpk(o[2], o[3]);
    st.z = cvtpk(o[4], o[5]);
    st.w = cvtpk(o[6], o[7]);
    *(uint4*)(hmid + (size_t)d * C1 + 8 * l) = st;  // bf16 row, 16B/lane
}

// ---------------- GEMM2 (bf16 A direct, preconverted W2b) + MFMA elogit2 ----------------
__global__ __launch_bounds__(256, 4)
void gemm2_kernel(const unsigned short* __restrict__ hmid,
                  const unsigned short* __restrict__ W2b,
                  const unsigned short* __restrict__ va2b,
                  _Float16* __restrict__ h2h,
                  float* __restrict__ e_src, float* __restrict__ e_dst) {
    const int tid = threadIdx.x;
    const int w = tid >> 6, lane = tid & 63;
    const int q = lane >> 4, c = lane & 15;

    const int m0 = (blockIdx.x * 4 + w) * 16;
    if (m0 >= NN) return;
    int row = m0 + c;
    if (row > NN - 1) row = NN - 1;
    bf16x8 afrag[4];
    #pragma unroll
    for (int kc = 0; kc < 4; ++kc)
        afrag[kc] = *(const bf16x8*)(hmid + (size_t)row * C1 + kc * 32 + q * 8);  // no converts

    bf16x8 bfrag[3][4];
    #pragma unroll
    for (int nt = 0; nt < 3; ++nt)
        #pragma unroll
        for (int kc = 0; kc < 4; ++kc)
            bfrag[nt][kc] = *(const bf16x8*)(W2b + (size_t)((nt * 4 + kc) * 64 + lane) * 8);
    // e-tile cols: 0=src_hi, 1=src_lo, 2=dst_hi, 3=dst_lo (from prep, 1KB L2-hot)
    bf16x8 bfe[4];
    #pragma unroll
    for (int kc = 0; kc < 4; ++kc) {
        bf16x8 bb = 0;
        if (c < 4) bb = *(const bf16x8*)(va2b + c * 128 + kc * 32 + q * 8);
        bfe[kc] = bb;
    }

    f32x4 acc[3] = {{0.f,0.f,0.f,0.f},{0.f,0.f,0.f,0.f},{0.f,0.f,0.f,0.f}};
    f32x4 acce = {0.f, 0.f, 0.f, 0.f};
    #pragma unroll
    for (int kc = 0; kc < 4; ++kc) {
        acc[0] = __builtin_amdgcn_mfma_f32_16x16x32_bf16(afrag[kc], bfrag[0][kc], acc[0], 0, 0, 0);
        acc[1] = __builtin_amdgcn_mfma_f32_16x16x32_bf16(afrag[kc], bfrag[1][kc], acc[1], 0, 0, 0);
        acc[2] = __builtin_amdgcn_mfma_f32_16x16x32_bf16(afrag[kc], bfrag[2][kc], acc[2], 0, 0, 0);
        acce   = __builtin_amdgcn_mfma_f32_16x16x32_bf16(afrag[kc], bfe[kc],      acce,   0, 0, 0);
    }
    #pragma unroll
    for (int r = 0; r < 4; ++r) {
        const int ro = m0 + q * 4 + r;
        // combine hi+lo columns: cols (0,1) -> e_src, cols (2,3) -> e_dst
        float v = acce[r] + __shfl_xor(acce[r], 1);
        if (ro < NN) {
            #pragma unroll
            for (int nt = 0; nt < 3; ++nt) {
                const int col = nt * 16 + c;
                if (col < CLASSES)
                    h2h[(size_t)ro * CLASSES + col] = (_Float16)acc[nt][r];
            }
            if (c == 0) e_src[ro] = v;
            if (c == 2) e_dst[ro] = v;
        }
    }
}

// ---------------- layer-2 aggregation: dst-per-group -> output ----------------
__global__ void agg2_kernel(const _Float16* __restrict__ h2h,
                            const float* __restrict__ e_src, const float* __restrict__ e_dst,
                            const int* __restrict__ rowptr, const int* __restrict__ deg,
                            const unsigned short* __restrict__ csr,
                            const float* __restrict__ b2, float* __restrict__ out) {
    const int tid = threadIdx.x;
    const int wv = tid >> 6, lane = tid & 63;
    const int eg = lane / 20;      // 0..2 active groups, 3 = idle lanes 60..63
    const int c  = lane % 20;
    const int d = blockIdx.x * 12 + wv * 3 + eg;
    const bool live = (eg < 3) && (d < NN);
    const int dcl = live ? d : 0;
    const float ed = e_dst[dcl];   // pre-scaled by log2e
    const int start = rowptr[dcl];
    const int cnt = live ? deg[dcl] : 0;

    float denom = 0.f, acc0 = 0.f, acc1 = 0.f;
    for (int i = 0; i < cnt; i += 4) {
        const bool v1 = i + 1 < cnt, v2 = i + 2 < cnt, v3 = i + 3 < cnt;
        int s0 = csr[start + i];
        int s1 = csr[start + (v1 ? i + 1 : i)];
        int s2 = csr[start + (v2 ? i + 2 : i)];
        int s3 = csr[start + (v3 ? i + 3 : i)];
        float es0 = e_src[s0], es1 = e_src[s1], es2 = e_src[s2], es3 = e_src[s3];
        h16x2 g0 = *(const h16x2*)(h2h + (size_t)s0 * CLASSES + 2 * c);
        h16x2 g1 = *(const h16x2*)(h2h + (size_t)s1 * CLASSES + 2 * c);
        h16x2 g2 = *(const h16x2*)(h2h + (size_t)s2 * CLASSES + 2 * c);
        h16x2 g3 = *(const h16x2*)(h2h + (size_t)s3 * CLASSES + 2 * c);
        float w0 = fexp2(lrelu(es0 + ed));
        float w1 = v1 ? fexp2(lrelu(es1 + ed)) : 0.f;
        float w2 = v2 ? fexp2(lrelu(es2 + ed)) : 0.f;
        float w3 = v3 ? fexp2(lrelu(es3 + ed)) : 0.f;
        denom += (w0 + w1) + (w2 + w3);
        acc0 = fmaf((float)g0[0], w0, acc0); acc1 = fmaf((float)g0[1], w0, acc1);
        acc0 = fmaf((float)g1[0], w1, acc0); acc1 = fmaf((float)g1[1], w1, acc1);
        acc0 = fmaf((float)g2[0], w2, acc0); acc1 = fmaf((float)g2[1], w2, acc1);
        acc0 = fmaf((float)g3[0], w3, acc0); acc1 = fmaf((float)g3[1], w3, acc1);
    }
    if (live) {
        const float inv = 1.f / (denom + 1e-16f);
        float2 o;
        o.x = acc0 * inv + b2[2 * c];
        o.y = acc1 * inv + b2[2 * c + 1];
        *(float2*)(out + (size_t)d * CLASSES + 2 * c) = o;
    }
}

extern "C" void kernel_launch(void* const* d_in, const int* in_sizes, int n_in,
                              void* d_out, int out_size, void* d_ws, size_t ws_size,
                              hipStream_t stream) {
    const float* x      = (const float*)d_in[0];
    const int*   ei     = (const int*)d_in[1];
    const float* W1     = (const float*)d_in[2];
    const float* a_src1 = (const float*)d_in[3];
    const float* a_dst1 = (const float*)d_in[4];
    const float* b1     = (const float*)d_in[5];
    const float* W2     = (const float*)d_in[6];
    const float* a_src2 = (const float*)d_in[7];
    const float* a_dst2 = (const float*)d_in[8];
    const float* b2     = (const float*)d_in[9];
    float* out = (float*)d_out;

    char* ws = (char*)d_ws;
    size_t off = 0;
    auto alloc = [&](size_t bytes) { char* p = ws + off; off += (bytes + 255) & ~(size_t)255; return p; };
    _Float16* h1h = (_Float16*)alloc((size_t)NN * C1 * 2);
    _Float16* h2h = (_Float16*)alloc((size_t)NN * CLASSES * 2);
    unsigned short* hmidb = (unsigned short*)alloc((size_t)NN * C1 * 2);
    float* e_src1 = (float*)alloc((size_t)NN * HEADS * 4);
    float* e_dst1 = (float*)alloc((size_t)NN * HEADS * 4);
    float* e_src2 = (float*)alloc((size_t)NN * 4);
    float* e_dst2 = (float*)alloc((size_t)NN * 4);
    int*   deg    = (int*)alloc((size_t)NN * 4);
    int*   rowptr = (int*)alloc((size_t)NN * 4);
    int*   cursor = (int*)alloc((size_t)NN * 4);
    unsigned short* csr  = (unsigned short*)alloc((size_t)ET * 2);
    int*   bsum   = (int*)alloc(256 * 4);
    unsigned short* va1h = (unsigned short*)alloc(16 * 128 * 2);
    unsigned short* va1l = (unsigned short*)alloc(16 * 128 * 2);
    unsigned short* va2b = (unsigned short*)alloc(4 * 128 * 2);
    unsigned short* W1b  = (unsigned short*)alloc(2048 * 8 * 2);
    unsigned short* W2b  = (unsigned short*)alloc(768 * 8 * 2);
    unsigned* partial    = (unsigned*)alloc((size_t)NHIST * LHN * 4);

    prep_kernel<<<3 + NHIST, 256, 0, stream>>>(W1, a_src1, a_dst1, W2, a_src2, a_dst2, ei,
                                               va1h, va1l, va2b, W1b, W2b, partial);
    gemm1_kernel<<<(NN + 63) / 64, 256, 0, stream>>>(x, W1b, va1h, va1l,
                                                     h1h, e_src1, e_dst1);
    scan1_kernel<<<NCHUNKS, 256, 0, stream>>>(partial, deg, rowptr, bsum);
    scan3_kernel<<<(NN + 255) / 256, 256, 0, stream>>>(rowptr, bsum, cursor, csr);
    fill_kernel<<<(EE / 4 + 255) / 256, 256, 0, stream>>>(ei, cursor, csr);

    agg1_kernel<<<NN / 16, 256, 0, stream>>>(h1h, e_src1, e_dst1, rowptr, deg, csr, b1, hmidb);

    gemm2_kernel<<<(NN + 63) / 64, 256, 0, stream>>>(hmidb, W2b, va2b, h2h, e_src2, e_dst2);
    agg2_kernel<<<(NN + 11) / 12, 256, 0, stream>>>(h2h, e_src2, e_dst2, rowptr, deg, csr, b2, out);
}

// Round 8
// 217.416 us; speedup vs baseline: 1.3600x; 1.1098x over previous
//
#include <hip/hip_runtime.h>
#include <math.h>

#define NN 50000
#define EE 800000
#define ET (EE + NN)      // edges + self loops
#define F_IN 128
#define HEADS 8
#define HID 16
#define C1 (HEADS * HID)  // 128
#define CLASSES 40
#define NEG_SLOPE 0.2f
#define LOG2E 1.4426950408889634f

#define NCHUNKS ((NN + 1023) / 1024)  // 49
#define NHIST 64                      // histogram blocks
#define EPB (EE / NHIST)              // 12500 edges per hist block
#define LHN 25088                     // padded u32 histogram words (>= 50176 u16)
#define GB ((NN + 63) / 64)           // 782 gemm1 blocks (64 rows each)

typedef __attribute__((ext_vector_type(8))) short bf16x8;
typedef __attribute__((ext_vector_type(4))) float f32x4;
typedef __attribute__((ext_vector_type(8))) _Float16 h16x8;
typedef __attribute__((ext_vector_type(2))) _Float16 h16x2;

__device__ __forceinline__ unsigned cvtpk(float a, float b) {
    unsigned r;
    asm("v_cvt_pk_bf16_f32 %0, %1, %2" : "=v"(r) : "v"(a), "v"(b));
    return r;
}
__device__ __forceinline__ float fexp2(float x) {
    float r;
    asm("v_exp_f32 %0, %1\n\ts_nop 0" : "=v"(r) : "v"(x));
    return r;
}
__device__ __forceinline__ float bflo(unsigned u) { return __uint_as_float(u << 16); }
__device__ __forceinline__ float bfhi(unsigned u) { return __uint_as_float(u & 0xffff0000u); }
__device__ __forceinline__ float lrelu(float a) { return fmaxf(a, NEG_SLOPE * a); }
__device__ __forceinline__ unsigned short bf1(float a) { return (unsigned short)cvtpk(a, a); }
__device__ __forceinline__ float bf1f(float a) { return bflo(cvtpk(a, a)); }
__device__ __forceinline__ bf16x8 pack8(float f0, float f1, float f2, float f3,
                                        float f4, float f5, float f6, float f7) {
    union { unsigned u[4]; bf16x8 v; } U;
    U.u[0] = cvtpk(f0, f1);
    U.u[1] = cvtpk(f2, f3);
    U.u[2] = cvtpk(f4, f5);
    U.u[3] = cvtpk(f6, f7);
    return U.v;
}

// ---------------- prep ----------------
// block 0: va1 (16x128 hi/lo bf16, frag layout) + va2 (4x128 bf16)
// block 1: W1b — W1 as bf16 MFMA fragments
// block 2: W2b — W2 fragments, cols >= CLASSES zeroed
// blocks 3..3+NHIST: LDS-histogram degree count (u16-packed; NO global atomics)
__global__ void prep_kernel(const float* __restrict__ W1,
                            const float* __restrict__ as1, const float* __restrict__ ad1,
                            const float* __restrict__ W2,
                            const float* __restrict__ as2, const float* __restrict__ ad2,
                            const int* __restrict__ ei,
                            unsigned short* __restrict__ va1h, unsigned short* __restrict__ va1l,
                            unsigned short* __restrict__ va2b,
                            unsigned short* __restrict__ W1b, unsigned short* __restrict__ W2b,
                            unsigned* __restrict__ partial) {
    const int tid = threadIdx.x;
    const int b = blockIdx.x;
    if (b >= 3) {  // -------- histogram count, pure LDS atomics --------
        __shared__ unsigned lhist[LHN];
        for (int i = tid; i < LHN; i += 256) lhist[i] = 0;
        __syncthreads();
        const int hb = b - 3;
        const int* dp = ei + EE + hb * EPB;
        for (int e0 = tid * 4; e0 < EPB; e0 += 1024) {
            int4 d4 = *(const int4*)(dp + e0);
            atomicAdd(&lhist[(unsigned)d4.x >> 1], 1u << ((d4.x & 1) << 4));
            atomicAdd(&lhist[(unsigned)d4.y >> 1], 1u << ((d4.y & 1) << 4));
            atomicAdd(&lhist[(unsigned)d4.z >> 1], 1u << ((d4.z & 1) << 4));
            atomicAdd(&lhist[(unsigned)d4.w >> 1], 1u << ((d4.w & 1) << 4));
        }
        __syncthreads();
        unsigned* pb = partial + (size_t)hb * LHN;
        for (int i = tid; i < LHN; i += 256) pb[i] = lhist[i];
        return;
    }
    if (b == 1) {  // W1b fragments: 2048 frags, 8 per thread
        for (int f = tid; f < 2048; f += 256) {
            const int lane = f & 63, kc = (f >> 6) & 3, ntw = f >> 8;
            const int q = lane >> 4, c = lane & 15;
            const int col = ntw * 16 + c;
            const int k0 = kc * 32 + q * 8;
            const float* wp = W1 + (size_t)k0 * C1 + col;
            *(bf16x8*)(W1b + (size_t)f * 8) =
                pack8(wp[0], wp[C1], wp[2 * C1], wp[3 * C1],
                      wp[4 * C1], wp[5 * C1], wp[6 * C1], wp[7 * C1]);
        }
        return;
    }
    if (b == 2) {  // W2b fragments: 768 frags
        for (int f = tid; f < 768; f += 256) {
            const int lane = f & 63, kc = (f >> 6) & 3, nt = f >> 8;
            const int q = lane >> 4, c = lane & 15;
            const int col = nt * 16 + c;
            const int k0 = kc * 32 + q * 8;
            bf16x8 v = 0;
            if (col < CLASSES) {
                const float* wp = W2 + (size_t)k0 * CLASSES + col;
                v = pack8(wp[0], wp[CLASSES], wp[2 * CLASSES], wp[3 * CLASSES],
                          wp[4 * CLASSES], wp[5 * CLASSES], wp[6 * CLASSES], wp[7 * CLASSES]);
            }
            *(bf16x8*)(W2b + (size_t)f * 8) = v;
        }
        return;
    }
    {   // va1: thread (k, half) computes 4 heads x {src,dst}
        const int k = tid >> 1, half = tid & 1;
        const float* wrow = W1 + (size_t)k * C1 + half * 64;
        #pragma unroll
        for (int hh = 0; hh < 4; ++hh) {
            const int h = half * 4 + hh;
            float s = 0.f, d = 0.f;
            #pragma unroll
            for (int t = 0; t < 16; ++t) {
                float wv = wrow[hh * 16 + t];
                s += wv * as1[h * HID + t];
                d += wv * ad1[h * HID + t];
            }
            s *= LOG2E; d *= LOG2E;
            va1h[h * 128 + k]       = bf1(s);
            va1l[h * 128 + k]       = bf1(s - bf1f(s));
            va1h[(h + 8) * 128 + k] = bf1(d);
            va1l[(h + 8) * 128 + k] = bf1(d - bf1f(d));
        }
    }
    if (tid < C1) {  // va2: thread k dots W2 row k with a2 vectors
        const float* wrow = W2 + (size_t)tid * CLASSES;
        float s = 0.f, d = 0.f;
        #pragma unroll
        for (int c2 = 0; c2 < CLASSES; ++c2) {
            float wv = wrow[c2];
            s += wv * as2[c2];
            d += wv * ad2[c2];
        }
        s *= LOG2E; d *= LOG2E;
        va2b[0 * 128 + tid] = bf1(s);
        va2b[1 * 128 + tid] = bf1(s - bf1f(s));
        va2b[2 * 128 + tid] = bf1(d);
        va2b[3 * 128 + tid] = bf1(d - bf1f(d));
    }
}

// ---------------- CSR scan ----------------
// scan1: deg totals from histogram partials (coalesced), then exclusive scan over
// (deg_real[i] + 1)  [+1 = self-loop]. Writes deg[i] = total incl self-loop.
__global__ void scan1_kernel(const unsigned* __restrict__ partial, int* __restrict__ deg,
                             int* __restrict__ rowptr, int* __restrict__ bsum) {
    __shared__ int sh[256];
    const int tid = threadIdx.x;
    const int base = blockIdx.x * 1024 + tid * 4;
    const unsigned short* pu = (const unsigned short*)partial;
    int t0 = 0, t1 = 0, t2 = 0, t3 = 0;
    #pragma unroll 8
    for (int b = 0; b < NHIST; ++b) {
        ushort4 p = *(const ushort4*)(pu + (size_t)b * (LHN * 2) + base);
        t0 += p.x; t1 += p.y; t2 += p.z; t3 += p.w;
    }
    int v[4], s[4];
    v[0] = (base + 0 < NN) ? t0 + 1 : 0;
    v[1] = (base + 1 < NN) ? t1 + 1 : 0;
    v[2] = (base + 2 < NN) ? t2 + 1 : 0;
    v[3] = (base + 3 < NN) ? t3 + 1 : 0;
    #pragma unroll
    for (int j = 0; j < 4; ++j)
        if (base + j < NN) deg[base + j] = v[j];  // total incl self-loop
    s[0] = v[0]; s[1] = s[0] + v[1]; s[2] = s[1] + v[2]; s[3] = s[2] + v[3];
    int T = s[3];
    sh[tid] = T;
    __syncthreads();
    for (int off = 1; off < 256; off <<= 1) {
        int xv = (tid >= off) ? sh[tid - off] : 0;
        __syncthreads();
        sh[tid] += xv;
        __syncthreads();
    }
    int excl = sh[tid] - T;
    #pragma unroll
    for (int j = 0; j < 4; ++j)
        if (base + j < NN) rowptr[base + j] = excl + s[j] - v[j];
    if (tid == 255) bsum[blockIdx.x] = sh[255];
}

// finalize rowptr (scan2 fused); self-loop at slot rowptr[i]; cursor past it
__global__ void scan3_kernel(int* __restrict__ rowptr, const int* __restrict__ bsum,
                             int* __restrict__ cursor, unsigned short* __restrict__ csr) {
    __shared__ int ex[64];
    const int tid = threadIdx.x;
    if (tid < 64) {
        int v = (tid < NCHUNKS) ? bsum[tid] : 0;
        int s = v;
        #pragma unroll
        for (int off = 1; off < 64; off <<= 1) {
            int xv = __shfl_up(s, off);
            if (tid >= off) s += xv;
        }
        ex[tid] = s - v;  // exclusive prefix
    }
    __syncthreads();
    int i = blockIdx.x * blockDim.x + tid;
    if (i >= NN) return;
    int rp = rowptr[i] + ex[i >> 10];
    rowptr[i] = rp;
    cursor[i] = rp + 1;
    csr[rp] = (unsigned short)i;  // self-loop first
}

// ---------------- GEMM1 (wave-per-mtile) + MFMA elogit1, FUSED with fill ----------------
// even bid: gemm block (bid>>1); odd bid: fill block (bid>>1).
// fill's 800K random cursor-atomics overlap gemm's MFMA/L2 work.
__global__ __launch_bounds__(256, 4)
void gemm1_fill_kernel(const float* __restrict__ x,
                       const unsigned short* __restrict__ W1b,
                       const unsigned short* __restrict__ va1h,
                       const unsigned short* __restrict__ va1l,
                       const int* __restrict__ ei,
                       int* __restrict__ cursor, unsigned short* __restrict__ csr,
                       _Float16* __restrict__ h1h,
                       float* __restrict__ e_src, float* __restrict__ e_dst) {
    const int bid = blockIdx.x;
    const int tid = threadIdx.x;
    if (bid & 1) {  // -------- fill: scatter real edges --------
        int base = ((bid >> 1) * 256 + tid) * 4;
        if (base < EE) {
            int4 s4 = *(const int4*)(ei + base);
            int4 d4 = *(const int4*)(ei + EE + base);
            int p0 = atomicAdd(&cursor[d4.x], 1);
            int p1 = atomicAdd(&cursor[d4.y], 1);
            int p2 = atomicAdd(&cursor[d4.z], 1);
            int p3 = atomicAdd(&cursor[d4.w], 1);
            csr[p0] = (unsigned short)s4.x;
            csr[p1] = (unsigned short)s4.y;
            csr[p2] = (unsigned short)s4.z;
            csr[p3] = (unsigned short)s4.w;
        }
        return;
    }
    const int gemmb = bid >> 1;
    const int w = tid >> 6, lane = tid & 63;
    const int q = lane >> 4, c = lane & 15;
    const int m0 = (gemmb * 4 + w) * 16;

    int row = m0 + c;
    if (row > NN - 1) row = NN - 1;
    bf16x8 afrag[4];
    #pragma unroll
    for (int kc = 0; kc < 4; ++kc) {
        const float* xp = x + (size_t)row * F_IN + kc * 32 + q * 8;
        float4 p0 = *(const float4*)xp;
        float4 p1 = *(const float4*)(xp + 4);
        afrag[kc] = pack8(p0.x, p0.y, p0.z, p0.w, p1.x, p1.y, p1.z, p1.w);
    }

    // e-operand fragments from prep (L2-hot 8KB) and e-MFMA
    {
        f32x4 acce = {0.f, 0.f, 0.f, 0.f};
        #pragma unroll
        for (int kc = 0; kc < 4; ++kc) {
            const int coloff = kc * 32 + q * 8;
            bf16x8 beh = *(const bf16x8*)(va1h + c * 128 + coloff);
            bf16x8 bel = *(const bf16x8*)(va1l + c * 128 + coloff);
            acce = __builtin_amdgcn_mfma_f32_16x16x32_bf16(afrag[kc], beh, acce, 0, 0, 0);
            acce = __builtin_amdgcn_mfma_f32_16x16x32_bf16(afrag[kc], bel, acce, 0, 0, 0);
        }
        float* ep = (c < 8) ? e_src : e_dst;
        const int cc = c & 7;
        #pragma unroll
        for (int r = 0; r < 4; ++r) {
            const int ro = m0 + q * 4 + r;
            if (ro < NN) ep[(size_t)ro * HEADS + cc] = acce[r];
        }
    }

    // main GEMM: 8 n-tiles, B frags from preconverted L2-hot W1b
    #pragma unroll 2
    for (int nt = 0; nt < 8; ++nt) {
        bf16x8 bf0 = *(const bf16x8*)(W1b + (size_t)((nt * 4 + 0) * 64 + lane) * 8);
        bf16x8 bf1_ = *(const bf16x8*)(W1b + (size_t)((nt * 4 + 1) * 64 + lane) * 8);
        bf16x8 bf2 = *(const bf16x8*)(W1b + (size_t)((nt * 4 + 2) * 64 + lane) * 8);
        bf16x8 bf3 = *(const bf16x8*)(W1b + (size_t)((nt * 4 + 3) * 64 + lane) * 8);
        f32x4 a = {0.f, 0.f, 0.f, 0.f};
        a = __builtin_amdgcn_mfma_f32_16x16x32_bf16(afrag[0], bf0, a, 0, 0, 0);
        a = __builtin_amdgcn_mfma_f32_16x16x32_bf16(afrag[1], bf1_, a, 0, 0, 0);
        a = __builtin_amdgcn_mfma_f32_16x16x32_bf16(afrag[2], bf2, a, 0, 0, 0);
        a = __builtin_amdgcn_mfma_f32_16x16x32_bf16(afrag[3], bf3, a, 0, 0, 0);
        #pragma unroll
        for (int r = 0; r < 4; ++r) {
            const int ro = m0 + q * 4 + r;
            if (ro < NN) h1h[(size_t)ro * C1 + nt * 16 + c] = (_Float16)a[r];
        }
    }
}

// ---------------- layer-1 aggregation: dst-per-group, 8-edge pipeline ----------------
// block = 64 = 1 wave = 4 groups of 16 lanes; each group owns one dst node.
// Lane l owns channels 8l..8l+7; head = l>>1. 8 independent gather chains in flight.
__global__ __launch_bounds__(64)
void agg1_kernel(const _Float16* __restrict__ h1h,
                 const float* __restrict__ e_src, const float* __restrict__ e_dst,
                 const int* __restrict__ rowptr, const int* __restrict__ deg,
                 const unsigned short* __restrict__ csr,
                 const float* __restrict__ b1, unsigned short* __restrict__ hmid) {
    const int tid = threadIdx.x;
    const int l = tid & 15;                      // channel-lane: channels 8l..8l+7
    const int d = blockIdx.x * 4 + (tid >> 4);   // group = dst (grid*4 == NN exactly)
    const int hd = l >> 1;
    const float ed = e_dst[(size_t)d * HEADS + hd];  // pre-scaled by log2e
    const int start = rowptr[d];
    const int cnt = deg[d];

    float denom = 0.f;
    float acc[8] = {0.f, 0.f, 0.f, 0.f, 0.f, 0.f, 0.f, 0.f};

    for (int i = 0; i < cnt; i += 8) {
        int s[8];
        #pragma unroll
        for (int e = 0; e < 8; ++e)
            s[e] = csr[start + ((i + e < cnt) ? i + e : i)];
        float es[8];
        #pragma unroll
        for (int e = 0; e < 8; ++e)
            es[e] = e_src[(size_t)s[e] * HEADS + hd];
        h16x8 g[8];
        #pragma unroll
        for (int e = 0; e < 8; ++e)
            g[e] = *(const h16x8*)(h1h + (size_t)s[e] * C1 + 8 * l);
        float w[8];
        #pragma unroll
        for (int e = 0; e < 8; ++e) {
            float we = fexp2(lrelu(es[e] + ed));
            w[e] = (i + e < cnt) ? we : 0.f;
            denom += w[e];
        }
        #pragma unroll
        for (int e = 0; e < 8; ++e) {
            #pragma unroll
            for (int j = 0; j < 8; ++j)   // v_fma_mix_f32: (float)f16 * f32 + f32
                acc[j] = fmaf((float)g[e][j], w[e], acc[j]);
        }
    }
    const float inv = 1.f / (denom + 1e-16f);
    float o[8];
    #pragma unroll
    for (int k = 0; k < 8; ++k) {
        float t = acc[k] * inv + b1[8 * l + k];
        o[k] = (t > 0.f) ? t : fexp2(t * LOG2E) - 1.f;  // elu (bf16-rounded after)
    }
    uint4 st;
    st.x = cvtpk(o[0], o[1]);
    st.y = cvtpk(o[2], o[3]);
    st.z = cvtpk(o[4], o[5]);
    st.w = cvtpk(o[6], o[7]);
    *(uint4*)(hmid + (size_t)d * C1 + 8 * l) = st;  // bf16 row, 16B/lane
}

// ---------------- GEMM2 (bf16 A direct, preconverted W2b) + MFMA elogit2 ----------------
__global__ __launch_bounds__(256, 4)
void gemm2_kernel(const unsigned short* __restrict__ hmid,
                  const unsigned short* __restrict__ W2b,
                  const unsigned short* __restrict__ va2b,
                  _Float16* __restrict__ h2h,
                  float* __restrict__ e_src, float* __restrict__ e_dst) {
    const int tid = threadIdx.x;
    const int w = tid >> 6, lane = tid & 63;
    const int q = lane >> 4, c = lane & 15;

    const int m0 = (blockIdx.x * 4 + w) * 16;
    if (m0 >= NN) return;
    int row = m0 + c;
    if (row > NN - 1) row = NN - 1;
    bf16x8 afrag[4];
    #pragma unroll
    for (int kc = 0; kc < 4; ++kc)
        afrag[kc] = *(const bf16x8*)(hmid + (size_t)row * C1 + kc * 32 + q * 8);  // no converts

    bf16x8 bfrag[3][4];
    #pragma unroll
    for (int nt = 0; nt < 3; ++nt)
        #pragma unroll
        for (int kc = 0; kc < 4; ++kc)
            bfrag[nt][kc] = *(const bf16x8*)(W2b + (size_t)((nt * 4 + kc) * 64 + lane) * 8);
    // e-tile cols: 0=src_hi, 1=src_lo, 2=dst_hi, 3=dst_lo (from prep, 1KB L2-hot)
    bf16x8 bfe[4];
    #pragma unroll
    for (int kc = 0; kc < 4; ++kc) {
        bf16x8 bb = 0;
        if (c < 4) bb = *(const bf16x8*)(va2b + c * 128 + kc * 32 + q * 8);
        bfe[kc] = bb;
    }

    f32x4 acc[3] = {{0.f,0.f,0.f,0.f},{0.f,0.f,0.f,0.f},{0.f,0.f,0.f,0.f}};
    f32x4 acce = {0.f, 0.f, 0.f, 0.f};
    #pragma unroll
    for (int kc = 0; kc < 4; ++kc) {
        acc[0] = __builtin_amdgcn_mfma_f32_16x16x32_bf16(afrag[kc], bfrag[0][kc], acc[0], 0, 0, 0);
        acc[1] = __builtin_amdgcn_mfma_f32_16x16x32_bf16(afrag[kc], bfrag[1][kc], acc[1], 0, 0, 0);
        acc[2] = __builtin_amdgcn_mfma_f32_16x16x32_bf16(afrag[kc], bfrag[2][kc], acc[2], 0, 0, 0);
        acce   = __builtin_amdgcn_mfma_f32_16x16x32_bf16(afrag[kc], bfe[kc],      acce,   0, 0, 0);
    }
    #pragma unroll
    for (int r = 0; r < 4; ++r) {
        const int ro = m0 + q * 4 + r;
        // combine hi+lo columns: cols (0,1) -> e_src, cols (2,3) -> e_dst
        float v = acce[r] + __shfl_xor(acce[r], 1);
        if (ro < NN) {
            #pragma unroll
            for (int nt = 0; nt < 3; ++nt) {
                const int col = nt * 16 + c;
                if (col < CLASSES)
                    h2h[(size_t)ro * CLASSES + col] = (_Float16)acc[nt][r];
            }
            if (c == 0) e_src[ro] = v;
            if (c == 2) e_dst[ro] = v;
        }
    }
}

// ---------------- layer-2 aggregation: dst-per-group, 8-edge pipeline ----------------
// block = 64 = 1 wave = 3 groups of 20 lanes (lanes 60..63 idle); 3 dst/block.
__global__ __launch_bounds__(64)
void agg2_kernel(const _Float16* __restrict__ h2h,
                 const float* __restrict__ e_src, const float* __restrict__ e_dst,
                 const int* __restrict__ rowptr, const int* __restrict__ deg,
                 const unsigned short* __restrict__ csr,
                 const float* __restrict__ b2, float* __restrict__ out) {
    const int tid = threadIdx.x;
    const int eg = tid / 20;      // 0..2 active groups, 3 = idle lanes 60..63
    const int c  = tid % 20;
    const int d = blockIdx.x * 3 + eg;
    const bool live = (eg < 3) && (d < NN);
    const int dcl = live ? d : 0;
    const float ed = e_dst[dcl];   // pre-scaled by log2e
    const int start = rowptr[dcl];
    const int cnt = live ? deg[dcl] : 0;

    float denom = 0.f, acc0 = 0.f, acc1 = 0.f;
    for (int i = 0; i < cnt; i += 8) {
        int s[8];
        #pragma unroll
        for (int e = 0; e < 8; ++e)
            s[e] = csr[start + ((i + e < cnt) ? i + e : i)];
        float es[8];
        #pragma unroll
        for (int e = 0; e < 8; ++e)
            es[e] = e_src[s[e]];
        h16x2 g[8];
        #pragma unroll
        for (int e = 0; e < 8; ++e)
            g[e] = *(const h16x2*)(h2h + (size_t)s[e] * CLASSES + 2 * c);
        float w[8];
        #pragma unroll
        for (int e = 0; e < 8; ++e) {
            float we = fexp2(lrelu(es[e] + ed));
            w[e] = (i + e < cnt) ? we : 0.f;
            denom += w[e];
        }
        #pragma unroll
        for (int e = 0; e < 8; ++e) {
            acc0 = fmaf((float)g[e][0], w[e], acc0);
            acc1 = fmaf((float)g[e][1], w[e], acc1);
        }
    }
    if (live) {
        const float inv = 1.f / (denom + 1e-16f);
        float2 o;
        o.x = acc0 * inv + b2[2 * c];
        o.y = acc1 * inv + b2[2 * c + 1];
        *(float2*)(out + (size_t)d * CLASSES + 2 * c) = o;
    }
}

extern "C" void kernel_launch(void* const* d_in, const int* in_sizes, int n_in,
                              void* d_out, int out_size, void* d_ws, size_t ws_size,
                              hipStream_t stream) {
    const float* x      = (const float*)d_in[0];
    const int*   ei     = (const int*)d_in[1];
    const float* W1     = (const float*)d_in[2];
    const float* a_src1 = (const float*)d_in[3];
    const float* a_dst1 = (const float*)d_in[4];
    const float* b1     = (const float*)d_in[5];
    const float* W2     = (const float*)d_in[6];
    const float* a_src2 = (const float*)d_in[7];
    const float* a_dst2 = (const float*)d_in[8];
    const float* b2     = (const float*)d_in[9];
    float* out = (float*)d_out;

    char* ws = (char*)d_ws;
    size_t off = 0;
    auto alloc = [&](size_t bytes) { char* p = ws + off; off += (bytes + 255) & ~(size_t)255; return p; };
    _Float16* h1h = (_Float16*)alloc((size_t)NN * C1 * 2);
    _Float16* h2h = (_Float16*)alloc((size_t)NN * CLASSES * 2);
    unsigned short* hmidb = (unsigned short*)alloc((size_t)NN * C1 * 2);
    float* e_src1 = (float*)alloc((size_t)NN * HEADS * 4);
    float* e_dst1 = (float*)alloc((size_t)NN * HEADS * 4);
    float* e_src2 = (float*)alloc((size_t)NN * 4);
    float* e_dst2 = (float*)alloc((size_t)NN * 4);
    int*   deg    = (int*)alloc((size_t)NN * 4);
    int*   rowptr = (int*)alloc((size_t)NN * 4);
    int*   cursor = (int*)alloc((size_t)NN * 4);
    unsigned short* csr  = (unsigned short*)alloc((size_t)ET * 2);
    int*   bsum   = (int*)alloc(256 * 4);
    unsigned short* va1h = (unsigned short*)alloc(16 * 128 * 2);
    unsigned short* va1l = (unsigned short*)alloc(16 * 128 * 2);
    unsigned short* va2b = (unsigned short*)alloc(4 * 128 * 2);
    unsigned short* W1b  = (unsigned short*)alloc(2048 * 8 * 2);
    unsigned short* W2b  = (unsigned short*)alloc(768 * 8 * 2);
    unsigned* partial    = (unsigned*)alloc((size_t)NHIST * LHN * 4);

    prep_kernel<<<3 + NHIST, 256, 0, stream>>>(W1, a_src1, a_dst1, W2, a_src2, a_dst2, ei,
                                               va1h, va1l, va2b, W1b, W2b, partial);
    scan1_kernel<<<NCHUNKS, 256, 0, stream>>>(partial, deg, rowptr, bsum);
    scan3_kernel<<<(NN + 255) / 256, 256, 0, stream>>>(rowptr, bsum, cursor, csr);
    gemm1_fill_kernel<<<2 * GB, 256, 0, stream>>>(x, W1b, va1h, va1l, ei, cursor, csr,
                                                  h1h, e_src1, e_dst1);

    agg1_kernel<<<NN / 4, 64, 0, stream>>>(h1h, e_src1, e_dst1, rowptr, deg, csr, b1, hmidb);

    gemm2_kernel<<<(NN + 63) / 64, 256, 0, stream>>>(hmidb, W2b, va2b, h2h, e_src2, e_dst2);
    agg2_kernel<<<(NN + 2) / 3, 64, 0, stream>>>(h2h, e_src2, e_dst2, rowptr, deg, csr, b2, out);
}

// Round 9
// 206.073 us; speedup vs baseline: 1.4348x; 1.0550x over previous
//
#include <hip/hip_runtime.h>
#include <math.h>

#define NN 50000
#define EE 800000
#define ET (EE + NN)      // edges + self loops
#define F_IN 128
#define HEADS 8
#define HID 16
#define C1 (HEADS * HID)  // 128
#define CLASSES 40
#define NEG_SLOPE 0.2f
#define LOG2E 1.4426950408889634f

#define NCHUNKS ((NN + 1023) / 1024)  // 49
#define NHIST 64                      // edge partitions (hist + fill)
#define EPB (EE / NHIST)              // 12500 edges per partition
#define PADN (NCHUNKS * 1024)         // 50176 padded dst slots
#define LDSW (PADN / 4)               // 12544 u32 words of packed-u8 counters
#define GB ((NN + 63) / 64)           // 782 gemm1 blocks (64 rows each)

typedef __attribute__((ext_vector_type(8))) short bf16x8;
typedef __attribute__((ext_vector_type(4))) float f32x4;
typedef __attribute__((ext_vector_type(8))) _Float16 h16x8;
typedef __attribute__((ext_vector_type(2))) _Float16 h16x2;

__device__ __forceinline__ unsigned cvtpk(float a, float b) {
    unsigned r;
    asm("v_cvt_pk_bf16_f32 %0, %1, %2" : "=v"(r) : "v"(a), "v"(b));
    return r;
}
__device__ __forceinline__ float fexp2(float x) {
    float r;
    asm("v_exp_f32 %0, %1\n\ts_nop 0" : "=v"(r) : "v"(x));
    return r;
}
__device__ __forceinline__ float bflo(unsigned u) { return __uint_as_float(u << 16); }
__device__ __forceinline__ float bfhi(unsigned u) { return __uint_as_float(u & 0xffff0000u); }
__device__ __forceinline__ float lrelu(float a) { return fmaxf(a, NEG_SLOPE * a); }
__device__ __forceinline__ unsigned short bf1(float a) { return (unsigned short)cvtpk(a, a); }
__device__ __forceinline__ float bf1f(float a) { return bflo(cvtpk(a, a)); }
__device__ __forceinline__ bf16x8 pack8(float f0, float f1, float f2, float f3,
                                        float f4, float f5, float f6, float f7) {
    union { unsigned u[4]; bf16x8 v; } U;
    U.u[0] = cvtpk(f0, f1);
    U.u[1] = cvtpk(f2, f3);
    U.u[2] = cvtpk(f4, f5);
    U.u[3] = cvtpk(f6, f7);
    return U.v;
}

// ---------------- prep ----------------
// block 0: va1 (16x128 hi/lo bf16, frag layout) + va2 (4x128 bf16)
// block 1: W1b — W1 as bf16 MFMA fragments
// block 2: W2b — W2 fragments, cols >= CLASSES zeroed
// blocks 3..3+NHIST: LDS-histogram degree count, u8-packed (NO global atomics)
__global__ void prep_kernel(const float* __restrict__ W1,
                            const float* __restrict__ as1, const float* __restrict__ ad1,
                            const float* __restrict__ W2,
                            const float* __restrict__ as2, const float* __restrict__ ad2,
                            const int* __restrict__ ei,
                            unsigned short* __restrict__ va1h, unsigned short* __restrict__ va1l,
                            unsigned short* __restrict__ va2b,
                            unsigned short* __restrict__ W1b, unsigned short* __restrict__ W2b,
                            unsigned char* __restrict__ partial8) {
    const int tid = threadIdx.x;
    const int b = blockIdx.x;
    if (b >= 3) {  // -------- histogram count, u8-packed LDS atomics --------
        __shared__ unsigned lhist[LDSW];
        for (int i = tid; i < LDSW; i += 256) lhist[i] = 0;
        __syncthreads();
        const int hb = b - 3;
        const int* dp = ei + EE + hb * EPB;
        for (int e0 = tid * 4; e0 < EPB; e0 += 1024) {
            int4 d4 = *(const int4*)(dp + e0);
            atomicAdd(&lhist[(unsigned)d4.x >> 2], 1u << (((unsigned)d4.x & 3) << 3));
            atomicAdd(&lhist[(unsigned)d4.y >> 2], 1u << (((unsigned)d4.y & 3) << 3));
            atomicAdd(&lhist[(unsigned)d4.z >> 2], 1u << (((unsigned)d4.z & 3) << 3));
            atomicAdd(&lhist[(unsigned)d4.w >> 2], 1u << (((unsigned)d4.w & 3) << 3));
        }
        __syncthreads();
        unsigned* pb = (unsigned*)(partial8 + (size_t)hb * PADN);
        for (int i = tid; i < LDSW; i += 256) pb[i] = lhist[i];
        return;
    }
    if (b == 1) {  // W1b fragments: 2048 frags, 8 per thread
        for (int f = tid; f < 2048; f += 256) {
            const int lane = f & 63, kc = (f >> 6) & 3, ntw = f >> 8;
            const int q = lane >> 4, c = lane & 15;
            const int col = ntw * 16 + c;
            const int k0 = kc * 32 + q * 8;
            const float* wp = W1 + (size_t)k0 * C1 + col;
            *(bf16x8*)(W1b + (size_t)f * 8) =
                pack8(wp[0], wp[C1], wp[2 * C1], wp[3 * C1],
                      wp[4 * C1], wp[5 * C1], wp[6 * C1], wp[7 * C1]);
        }
        return;
    }
    if (b == 2) {  // W2b fragments: 768 frags
        for (int f = tid; f < 768; f += 256) {
            const int lane = f & 63, kc = (f >> 6) & 3, nt = f >> 8;
            const int q = lane >> 4, c = lane & 15;
            const int col = nt * 16 + c;
            const int k0 = kc * 32 + q * 8;
            bf16x8 v = 0;
            if (col < CLASSES) {
                const float* wp = W2 + (size_t)k0 * CLASSES + col;
                v = pack8(wp[0], wp[CLASSES], wp[2 * CLASSES], wp[3 * CLASSES],
                          wp[4 * CLASSES], wp[5 * CLASSES], wp[6 * CLASSES], wp[7 * CLASSES]);
            }
            *(bf16x8*)(W2b + (size_t)f * 8) = v;
        }
        return;
    }
    {   // va1: thread (k, half) computes 4 heads x {src,dst}
        const int k = tid >> 1, half = tid & 1;
        const float* wrow = W1 + (size_t)k * C1 + half * 64;
        #pragma unroll
        for (int hh = 0; hh < 4; ++hh) {
            const int h = half * 4 + hh;
            float s = 0.f, d = 0.f;
            #pragma unroll
            for (int t = 0; t < 16; ++t) {
                float wv = wrow[hh * 16 + t];
                s += wv * as1[h * HID + t];
                d += wv * ad1[h * HID + t];
            }
            s *= LOG2E; d *= LOG2E;
            va1h[h * 128 + k]       = bf1(s);
            va1l[h * 128 + k]       = bf1(s - bf1f(s));
            va1h[(h + 8) * 128 + k] = bf1(d);
            va1l[(h + 8) * 128 + k] = bf1(d - bf1f(d));
        }
    }
    if (tid < C1) {  // va2: thread k dots W2 row k with a2 vectors
        const float* wrow = W2 + (size_t)tid * CLASSES;
        float s = 0.f, d = 0.f;
        #pragma unroll
        for (int c2 = 0; c2 < CLASSES; ++c2) {
            float wv = wrow[c2];
            s += wv * as2[c2];
            d += wv * ad2[c2];
        }
        s *= LOG2E; d *= LOG2E;
        va2b[0 * 128 + tid] = bf1(s);
        va2b[1 * 128 + tid] = bf1(s - bf1f(s));
        va2b[2 * 128 + tid] = bf1(d);
        va2b[3 * 128 + tid] = bf1(d - bf1f(d));
    }
}

// ---------------- CSR scan ----------------
// scan1: deg totals from u8 partials; ALSO writes pfx8[b][d] = running prefix of
// dst-d counts over partitions < b. Then exclusive scan over (deg_real + 1).
__global__ void scan1_kernel(const unsigned char* __restrict__ partial8,
                             unsigned char* __restrict__ pfx8,
                             int* __restrict__ deg,
                             int* __restrict__ rowptr, int* __restrict__ bsum) {
    __shared__ int sh[256];
    const int tid = threadIdx.x;
    const int base = blockIdx.x * 1024 + tid * 4;  // < PADN always
    int t0 = 0, t1 = 0, t2 = 0, t3 = 0;
    #pragma unroll 8
    for (int b = 0; b < NHIST; ++b) {
        uchar4 pf;
        pf.x = (unsigned char)t0; pf.y = (unsigned char)t1;
        pf.z = (unsigned char)t2; pf.w = (unsigned char)t3;
        *(uchar4*)(pfx8 + (size_t)b * PADN + base) = pf;   // prefix BEFORE block b
        uchar4 p = *(const uchar4*)(partial8 + (size_t)b * PADN + base);
        t0 += p.x; t1 += p.y; t2 += p.z; t3 += p.w;
    }
    int v[4], s[4];
    v[0] = (base + 0 < NN) ? t0 + 1 : 0;
    v[1] = (base + 1 < NN) ? t1 + 1 : 0;
    v[2] = (base + 2 < NN) ? t2 + 1 : 0;
    v[3] = (base + 3 < NN) ? t3 + 1 : 0;
    #pragma unroll
    for (int j = 0; j < 4; ++j)
        if (base + j < NN) deg[base + j] = v[j];  // total incl self-loop
    s[0] = v[0]; s[1] = s[0] + v[1]; s[2] = s[1] + v[2]; s[3] = s[2] + v[3];
    int T = s[3];
    sh[tid] = T;
    __syncthreads();
    for (int off = 1; off < 256; off <<= 1) {
        int xv = (tid >= off) ? sh[tid - off] : 0;
        __syncthreads();
        sh[tid] += xv;
        __syncthreads();
    }
    int excl = sh[tid] - T;
    #pragma unroll
    for (int j = 0; j < 4; ++j)
        if (base + j < NN) rowptr[base + j] = excl + s[j] - v[j];
    if (tid == 255) bsum[blockIdx.x] = sh[255];
}

// finalize rowptr (scan2 fused); self-loop at slot rowptr[i]
__global__ void scan3_kernel(int* __restrict__ rowptr, const int* __restrict__ bsum,
                             unsigned short* __restrict__ csr) {
    __shared__ int ex[64];
    const int tid = threadIdx.x;
    if (tid < 64) {
        int v = (tid < NCHUNKS) ? bsum[tid] : 0;
        int s = v;
        #pragma unroll
        for (int off = 1; off < 64; off <<= 1) {
            int xv = __shfl_up(s, off);
            if (tid >= off) s += xv;
        }
        ex[tid] = s - v;  // exclusive prefix
    }
    __syncthreads();
    int i = blockIdx.x * blockDim.x + tid;
    if (i >= NN) return;
    int rp = rowptr[i] + ex[i >> 10];
    rowptr[i] = rp;
    csr[rp] = (unsigned short)i;  // self-loop first
}

// ---------------- GEMM1 (wave-per-mtile) + MFMA elogit1, FUSED with atomic-free fill --
// bids 0..NHIST-1: fill partition (LDS rank counters + pfx8; NO global atomics).
// bids NHIST..: gemm blocks.
__global__ __launch_bounds__(256, 3)
void gemm1_fill_kernel(const float* __restrict__ x,
                       const unsigned short* __restrict__ W1b,
                       const unsigned short* __restrict__ va1h,
                       const unsigned short* __restrict__ va1l,
                       const int* __restrict__ ei,
                       const int* __restrict__ rowptr,
                       const unsigned char* __restrict__ pfx8,
                       unsigned short* __restrict__ csr,
                       _Float16* __restrict__ h1h,
                       float* __restrict__ e_src, float* __restrict__ e_dst) {
    const int bid = blockIdx.x;
    const int tid = threadIdx.x;
    __shared__ unsigned lrank[LDSW];  // only fill blocks touch it (50KB -> 3 blocks/CU)
    if (bid < NHIST) {  // -------- fill: rank via LDS, slot via rowptr+pfx8 --------
        for (int i = tid; i < LDSW; i += 256) lrank[i] = 0;
        __syncthreads();
        const int fb = bid;
        const int* sp = ei + fb * EPB;
        const int* dp = ei + EE + fb * EPB;
        const unsigned char* pf = pfx8 + (size_t)fb * PADN;
        for (int e0 = tid * 4; e0 < EPB; e0 += 1024) {
            int4 s4 = *(const int4*)(sp + e0);
            int4 d4 = *(const int4*)(dp + e0);
            {
                const unsigned d = (unsigned)d4.x, sh8 = (d & 3) << 3;
                unsigned old = atomicAdd(&lrank[d >> 2], 1u << sh8);
                csr[rowptr[d] + 1 + pf[d] + ((old >> sh8) & 0xff)] = (unsigned short)s4.x;
            }
            {
                const unsigned d = (unsigned)d4.y, sh8 = (d & 3) << 3;
                unsigned old = atomicAdd(&lrank[d >> 2], 1u << sh8);
                csr[rowptr[d] + 1 + pf[d] + ((old >> sh8) & 0xff)] = (unsigned short)s4.y;
            }
            {
                const unsigned d = (unsigned)d4.z, sh8 = (d & 3) << 3;
                unsigned old = atomicAdd(&lrank[d >> 2], 1u << sh8);
                csr[rowptr[d] + 1 + pf[d] + ((old >> sh8) & 0xff)] = (unsigned short)s4.z;
            }
            {
                const unsigned d = (unsigned)d4.w, sh8 = (d & 3) << 3;
                unsigned old = atomicAdd(&lrank[d >> 2], 1u << sh8);
                csr[rowptr[d] + 1 + pf[d] + ((old >> sh8) & 0xff)] = (unsigned short)s4.w;
            }
        }
        return;
    }
    const int gemmb = bid - NHIST;
    const int w = tid >> 6, lane = tid & 63;
    const int q = lane >> 4, c = lane & 15;
    const int m0 = (gemmb * 4 + w) * 16;

    int row = m0 + c;
    if (row > NN - 1) row = NN - 1;
    bf16x8 afrag[4];
    #pragma unroll
    for (int kc = 0; kc < 4; ++kc) {
        const float* xp = x + (size_t)row * F_IN + kc * 32 + q * 8;
        float4 p0 = *(const float4*)xp;
        float4 p1 = *(const float4*)(xp + 4);
        afrag[kc] = pack8(p0.x, p0.y, p0.z, p0.w, p1.x, p1.y, p1.z, p1.w);
    }

    // e-operand fragments from prep (L2-hot 8KB) and e-MFMA
    {
        f32x4 acce = {0.f, 0.f, 0.f, 0.f};
        #pragma unroll
        for (int kc = 0; kc < 4; ++kc) {
            const int coloff = kc * 32 + q * 8;
            bf16x8 beh = *(const bf16x8*)(va1h + c * 128 + coloff);
            bf16x8 bel = *(const bf16x8*)(va1l + c * 128 + coloff);
            acce = __builtin_amdgcn_mfma_f32_16x16x32_bf16(afrag[kc], beh, acce, 0, 0, 0);
            acce = __builtin_amdgcn_mfma_f32_16x16x32_bf16(afrag[kc], bel, acce, 0, 0, 0);
        }
        float* ep = (c < 8) ? e_src : e_dst;
        const int cc = c & 7;
        #pragma unroll
        for (int r = 0; r < 4; ++r) {
            const int ro = m0 + q * 4 + r;
            if (ro < NN) ep[(size_t)ro * HEADS + cc] = acce[r];
        }
    }

    // main GEMM: 8 n-tiles, B frags from preconverted L2-hot W1b
    #pragma unroll 2
    for (int nt = 0; nt < 8; ++nt) {
        bf16x8 bf0 = *(const bf16x8*)(W1b + (size_t)((nt * 4 + 0) * 64 + lane) * 8);
        bf16x8 bf1_ = *(const bf16x8*)(W1b + (size_t)((nt * 4 + 1) * 64 + lane) * 8);
        bf16x8 bf2 = *(const bf16x8*)(W1b + (size_t)((nt * 4 + 2) * 64 + lane) * 8);
        bf16x8 bf3 = *(const bf16x8*)(W1b + (size_t)((nt * 4 + 3) * 64 + lane) * 8);
        f32x4 a = {0.f, 0.f, 0.f, 0.f};
        a = __builtin_amdgcn_mfma_f32_16x16x32_bf16(afrag[0], bf0, a, 0, 0, 0);
        a = __builtin_amdgcn_mfma_f32_16x16x32_bf16(afrag[1], bf1_, a, 0, 0, 0);
        a = __builtin_amdgcn_mfma_f32_16x16x32_bf16(afrag[2], bf2, a, 0, 0, 0);
        a = __builtin_amdgcn_mfma_f32_16x16x32_bf16(afrag[3], bf3, a, 0, 0, 0);
        #pragma unroll
        for (int r = 0; r < 4; ++r) {
            const int ro = m0 + q * 4 + r;
            if (ro < NN) h1h[(size_t)ro * C1 + nt * 16 + c] = (_Float16)a[r];
        }
    }
}

// ---------------- layer-1 aggregation: dst-per-group, 8-edge pipeline ----------------
// block = 64 = 1 wave = 4 groups of 16 lanes; each group owns one dst node.
__global__ __launch_bounds__(64)
void agg1_kernel(const _Float16* __restrict__ h1h,
                 const float* __restrict__ e_src, const float* __restrict__ e_dst,
                 const int* __restrict__ rowptr, const int* __restrict__ deg,
                 const unsigned short* __restrict__ csr,
                 const float* __restrict__ b1, unsigned short* __restrict__ hmid) {
    const int tid = threadIdx.x;
    const int l = tid & 15;                      // channel-lane: channels 8l..8l+7
    const int d = blockIdx.x * 4 + (tid >> 4);   // group = dst (grid*4 == NN exactly)
    const int hd = l >> 1;
    const float ed = e_dst[(size_t)d * HEADS + hd];  // pre-scaled by log2e
    const int start = rowptr[d];
    const int cnt = deg[d];

    float denom = 0.f;
    float acc[8] = {0.f, 0.f, 0.f, 0.f, 0.f, 0.f, 0.f, 0.f};

    for (int i = 0; i < cnt; i += 8) {
        int s[8];
        #pragma unroll
        for (int e = 0; e < 8; ++e)
            s[e] = csr[start + ((i + e < cnt) ? i + e : i)];
        float es[8];
        #pragma unroll
        for (int e = 0; e < 8; ++e)
            es[e] = e_src[(size_t)s[e] * HEADS + hd];
        h16x8 g[8];
        #pragma unroll
        for (int e = 0; e < 8; ++e)
            g[e] = *(const h16x8*)(h1h + (size_t)s[e] * C1 + 8 * l);
        float w[8];
        #pragma unroll
        for (int e = 0; e < 8; ++e) {
            float we = fexp2(lrelu(es[e] + ed));
            w[e] = (i + e < cnt) ? we : 0.f;
            denom += w[e];
        }
        #pragma unroll
        for (int e = 0; e < 8; ++e) {
            #pragma unroll
            for (int j = 0; j < 8; ++j)   // v_fma_mix_f32: (float)f16 * f32 + f32
                acc[j] = fmaf((float)g[e][j], w[e], acc[j]);
        }
    }
    const float inv = 1.f / (denom + 1e-16f);
    float o[8];
    #pragma unroll
    for (int k = 0; k < 8; ++k) {
        float t = acc[k] * inv + b1[8 * l + k];
        o[k] = (t > 0.f) ? t : fexp2(t * LOG2E) - 1.f;  // elu (bf16-rounded after)
    }
    uint4 st;
    st.x = cvtpk(o[0], o[1]);
    st.y = cvtpk(o[2], o[3]);
    st.z = cvtpk(o[4], o[5]);
    st.w = cvtpk(o[6], o[7]);
    *(uint4*)(hmid + (size_t)d * C1 + 8 * l) = st;  // bf16 row, 16B/lane
}

// ---------------- GEMM2 (bf16 A direct, preconverted W2b) + MFMA elogit2 ----------------
__global__ __launch_bounds__(256, 4)
void gemm2_kernel(const unsigned short* __restrict__ hmid,
                  const unsigned short* __restrict__ W2b,
                  const unsigned short* __restrict__ va2b,
                  _Float16* __restrict__ h2h,
                  float* __restrict__ e_src, float* __restrict__ e_dst) {
    const int tid = threadIdx.x;
    const int w = tid >> 6, lane = tid & 63;
    const int q = lane >> 4, c = lane & 15;

    const int m0 = (blockIdx.x * 4 + w) * 16;
    if (m0 >= NN) return;
    int row = m0 + c;
    if (row > NN - 1) row = NN - 1;
    bf16x8 afrag[4];
    #pragma unroll
    for (int kc = 0; kc < 4; ++kc)
        afrag[kc] = *(const bf16x8*)(hmid + (size_t)row * C1 + kc * 32 + q * 8);  // no converts

    bf16x8 bfrag[3][4];
    #pragma unroll
    for (int nt = 0; nt < 3; ++nt)
        #pragma unroll
        for (int kc = 0; kc < 4; ++kc)
            bfrag[nt][kc] = *(const bf16x8*)(W2b + (size_t)((nt * 4 + kc) * 64 + lane) * 8);
    // e-tile cols: 0=src_hi, 1=src_lo, 2=dst_hi, 3=dst_lo (from prep, 1KB L2-hot)
    bf16x8 bfe[4];
    #pragma unroll
    for (int kc = 0; kc < 4; ++kc) {
        bf16x8 bb = 0;
        if (c < 4) bb = *(const bf16x8*)(va2b + c * 128 + kc * 32 + q * 8);
        bfe[kc] = bb;
    }

    f32x4 acc[3] = {{0.f,0.f,0.f,0.f},{0.f,0.f,0.f,0.f},{0.f,0.f,0.f,0.f}};
    f32x4 acce = {0.f, 0.f, 0.f, 0.f};
    #pragma unroll
    for (int kc = 0; kc < 4; ++kc) {
        acc[0] = __builtin_amdgcn_mfma_f32_16x16x32_bf16(afrag[kc], bfrag[0][kc], acc[0], 0, 0, 0);
        acc[1] = __builtin_amdgcn_mfma_f32_16x16x32_bf16(afrag[kc], bfrag[1][kc], acc[1], 0, 0, 0);
        acc[2] = __builtin_amdgcn_mfma_f32_16x16x32_bf16(afrag[kc], bfrag[2][kc], acc[2], 0, 0, 0);
        acce   = __builtin_amdgcn_mfma_f32_16x16x32_bf16(afrag[kc], bfe[kc],      acce,   0, 0, 0);
    }
    #pragma unroll
    for (int r = 0; r < 4; ++r) {
        const int ro = m0 + q * 4 + r;
        // combine hi+lo columns: cols (0,1) -> e_src, cols (2,3) -> e_dst
        float v = acce[r] + __shfl_xor(acce[r], 1);
        if (ro < NN) {
            #pragma unroll
            for (int nt = 0; nt < 3; ++nt) {
                const int col = nt * 16 + c;
                if (col < CLASSES)
                    h2h[(size_t)ro * CLASSES + col] = (_Float16)acc[nt][r];
            }
            if (c == 0) e_src[ro] = v;
            if (c == 2) e_dst[ro] = v;
        }
    }
}

// ---------------- layer-2 aggregation: dst-per-group, 8-edge pipeline ----------------
// block = 64 = 1 wave = 3 groups of 20 lanes (lanes 60..63 idle); 3 dst/block.
__global__ __launch_bounds__(64)
void agg2_kernel(const _Float16* __restrict__ h2h,
                 const float* __restrict__ e_src, const float* __restrict__ e_dst,
                 const int* __restrict__ rowptr, const int* __restrict__ deg,
                 const unsigned short* __restrict__ csr,
                 const float* __restrict__ b2, float* __restrict__ out) {
    const int tid = threadIdx.x;
    const int eg = tid / 20;      // 0..2 active groups, 3 = idle lanes 60..63
    const int c  = tid % 20;
    const int d = blockIdx.x * 3 + eg;
    const bool live = (eg < 3) && (d < NN);
    const int dcl = live ? d : 0;
    const float ed = e_dst[dcl];   // pre-scaled by log2e
    const int start = rowptr[dcl];
    const int cnt = live ? deg[dcl] : 0;

    float denom = 0.f, acc0 = 0.f, acc1 = 0.f;
    for (int i = 0; i < cnt; i += 8) {
        int s[8];
        #pragma unroll
        for (int e = 0; e < 8; ++e)
            s[e] = csr[start + ((i + e < cnt) ? i + e : i)];
        float es[8];
        #pragma unroll
        for (int e = 0; e < 8; ++e)
            es[e] = e_src[s[e]];
        h16x2 g[8];
        #pragma unroll
        for (int e = 0; e < 8; ++e)
            g[e] = *(const h16x2*)(h2h + (size_t)s[e] * CLASSES + 2 * c);
        float w[8];
        #pragma unroll
        for (int e = 0; e < 8; ++e) {
            float we = fexp2(lrelu(es[e] + ed));
            w[e] = (i + e < cnt) ? we : 0.f;
            denom += w[e];
        }
        #pragma unroll
        for (int e = 0; e < 8; ++e) {
            acc0 = fmaf((float)g[e][0], w[e], acc0);
            acc1 = fmaf((float)g[e][1], w[e], acc1);
        }
    }
    if (live) {
        const float inv = 1.f / (denom + 1e-16f);
        float2 o;
        o.x = acc0 * inv + b2[2 * c];
        o.y = acc1 * inv + b2[2 * c + 1];
        *(float2*)(out + (size_t)d * CLASSES + 2 * c) = o;
    }
}

extern "C" void kernel_launch(void* const* d_in, const int* in_sizes, int n_in,
                              void* d_out, int out_size, void* d_ws, size_t ws_size,
                              hipStream_t stream) {
    const float* x      = (const float*)d_in[0];
    const int*   ei     = (const int*)d_in[1];
    const float* W1     = (const float*)d_in[2];
    const float* a_src1 = (const float*)d_in[3];
    const float* a_dst1 = (const float*)d_in[4];
    const float* b1     = (const float*)d_in[5];
    const float* W2     = (const float*)d_in[6];
    const float* a_src2 = (const float*)d_in[7];
    const float* a_dst2 = (const float*)d_in[8];
    const float* b2     = (const float*)d_in[9];
    float* out = (float*)d_out;

    char* ws = (char*)d_ws;
    size_t off = 0;
    auto alloc = [&](size_t bytes) { char* p = ws + off; off += (bytes + 255) & ~(size_t)255; return p; };
    _Float16* h1h = (_Float16*)alloc((size_t)NN * C1 * 2);
    _Float16* h2h = (_Float16*)alloc((size_t)NN * CLASSES * 2);
    unsigned short* hmidb = (unsigned short*)alloc((size_t)NN * C1 * 2);
    float* e_src1 = (float*)alloc((size_t)NN * HEADS * 4);
    float* e_dst1 = (float*)alloc((size_t)NN * HEADS * 4);
    float* e_src2 = (float*)alloc((size_t)NN * 4);
    float* e_dst2 = (float*)alloc((size_t)NN * 4);
    int*   deg    = (int*)alloc((size_t)NN * 4);
    int*   rowptr = (int*)alloc((size_t)NN * 4);
    unsigned short* csr  = (unsigned short*)alloc((size_t)ET * 2);
    int*   bsum   = (int*)alloc(256 * 4);
    unsigned short* va1h = (unsigned short*)alloc(16 * 128 * 2);
    unsigned short* va1l = (unsigned short*)alloc(16 * 128 * 2);
    unsigned short* va2b = (unsigned short*)alloc(4 * 128 * 2);
    unsigned short* W1b  = (unsigned short*)alloc(2048 * 8 * 2);
    unsigned short* W2b  = (unsigned short*)alloc(768 * 8 * 2);
    unsigned char* partial8 = (unsigned char*)alloc((size_t)NHIST * PADN);
    unsigned char* pfx8     = (unsigned char*)alloc((size_t)NHIST * PADN);

    prep_kernel<<<3 + NHIST, 256, 0, stream>>>(W1, a_src1, a_dst1, W2, a_src2, a_dst2, ei,
                                               va1h, va1l, va2b, W1b, W2b, partial8);
    scan1_kernel<<<NCHUNKS, 256, 0, stream>>>(partial8, pfx8, deg, rowptr, bsum);
    scan3_kernel<<<(NN + 255) / 256, 256, 0, stream>>>(rowptr, bsum, csr);
    gemm1_fill_kernel<<<NHIST + GB, 256, 0, stream>>>(x, W1b, va1h, va1l, ei, rowptr, pfx8,
                                                      csr, h1h, e_src1, e_dst1);

    agg1_kernel<<<NN / 4, 64, 0, stream>>>(h1h, e_src1, e_dst1, rowptr, deg, csr, b1, hmidb);

    gemm2_kernel<<<(NN + 63) / 64, 256, 0, stream>>>(hmidb, W2b, va2b, h2h, e_src2, e_dst2);
    agg2_kernel<<<(NN + 2) / 3, 64, 0, stream>>>(h2h, e_src2, e_dst2, rowptr, deg, csr, b2, out);
}